// Round 1
// baseline (3037.299 us; speedup 1.0000x reference)
//
#include <hip/hip_runtime.h>
#include <hip/hip_bf16.h>

#define DN 100000     // N entities
#define DD 128        // D
#define DR 12         // R relations
#define DNB 8         // bases
#define DE 1000000    // edges
#define DP 400000     // hyperedge incidences
#define DHE 20000     // hyperedges
#define DB 64         // batch
#define DLR 64
#define DLC 32
#define DNH 8
#define DHD 16

// ---------------------------------------------------------------- GEMM (K=128, Nout=128)
// C[m,n] = sum_k A[m,k] * W(k,n) + bias[n];  W(k,n) = trans ? W[n*128+k] : W[k*128+n]
__global__ __launch_bounds__(256) void k_gemm128(
    const float* __restrict__ A, const float* __restrict__ W,
    const float* __restrict__ bias, float* __restrict__ C, int M, int trans)
{
    __shared__ float Wl[64 * 128];   // 32KB  (k-chunk of 64)
    __shared__ float Al[64 * 68];    // 17.4KB (64 rows x 64 cols, +4 pad)
    int tid = threadIdx.x;
    int row0 = blockIdx.x * 64;
    int tr = (tid >> 5) * 8;         // 8 rows per thread
    int tc = (tid & 31) * 4;         // 4 cols per thread
    float acc[8][4] = {};
    for (int kc = 0; kc < 2; ++kc) {
        __syncthreads();
        if (!trans) {
            for (int i = tid; i < 64 * 32; i += 256)
                ((float4*)Wl)[i] = ((const float4*)(W + kc * 64 * 128))[i];
        } else {
            for (int i = tid; i < 64 * 128; i += 256) {
                int n = i >> 6, k = i & 63;
                Wl[k * 128 + n] = W[(size_t)n * 128 + kc * 64 + k];
            }
        }
        for (int i = tid; i < 64 * 16; i += 256) {
            int r = i >> 4, c4 = i & 15;
            int gr = row0 + r;
            float4 v = make_float4(0.f, 0.f, 0.f, 0.f);
            if (gr < M) v = *((const float4*)(A + (size_t)gr * 128 + kc * 64) + c4);
            *(float4*)&Al[r * 68 + c4 * 4] = v;
        }
        __syncthreads();
        for (int k = 0; k < 64; ++k) {
            float4 wv = *(const float4*)&Wl[k * 128 + tc];
            #pragma unroll
            for (int r = 0; r < 8; ++r) {
                float av = Al[(tr + r) * 68 + k];
                acc[r][0] += av * wv.x; acc[r][1] += av * wv.y;
                acc[r][2] += av * wv.z; acc[r][3] += av * wv.w;
            }
        }
    }
    float4 bv = make_float4(0.f, 0.f, 0.f, 0.f);
    if (bias) bv = *(const float4*)&bias[tc];
    #pragma unroll
    for (int r = 0; r < 8; ++r) {
        int gr = row0 + tr + r;
        if (gr < M) {
            float4 o = make_float4(acc[r][0] + bv.x, acc[r][1] + bv.y,
                                   acc[r][2] + bv.z, acc[r][3] + bv.w);
            *(float4*)(C + (size_t)gr * 128 + tc) = o;
        }
    }
}

// ---------------------------------------------------------------- RGCN helpers
__global__ void k_edge_count(const int* __restrict__ dst, const int* __restrict__ et,
                             float* cnt, int E)
{
    int i = blockIdx.x * blockDim.x + threadIdx.x;
    if (i < E) atomicAdd(&cnt[(size_t)dst[i] * DR + et[i]], 1.0f);
}

__global__ void k_wcomp(const float* __restrict__ comp, const float* __restrict__ bases,
                        float* __restrict__ w_all)
{
    int i = blockIdx.x * blockDim.x + threadIdx.x;
    if (i >= DR * DD * DD) return;
    int r = i / (DD * DD), io = i % (DD * DD);
    float s = 0.f;
    #pragma unroll
    for (int b = 0; b < DNB; ++b) s += comp[r * DNB + b] * bases[(size_t)b * DD * DD + io];
    w_all[i] = s;
}

__global__ void k_type_hist(const int* __restrict__ et, int* thist, int E)
{
    __shared__ int lh[DR];
    if (threadIdx.x < DR) lh[threadIdx.x] = 0;
    __syncthreads();
    int i = blockIdx.x * blockDim.x + threadIdx.x;
    if (i < E) atomicAdd(&lh[et[i]], 1);
    __syncthreads();
    if (threadIdx.x < DR) atomicAdd(&thist[threadIdx.x], lh[threadIdx.x]);
}

__global__ void k_prefix(const int* __restrict__ thist, int* base, int* cursor)
{
    int s = 0;
    for (int r = 0; r < DR; ++r) { base[r] = s; cursor[r] = s; s += thist[r]; }
    base[DR] = s;
}

__global__ void k_bucket(const int* __restrict__ et, int* cursor, int* eorder, int E)
{
    __shared__ int lh[DR], lbase[DR];
    if (threadIdx.x < DR) lh[threadIdx.x] = 0;
    __syncthreads();
    int i = blockIdx.x * blockDim.x + threadIdx.x;
    int t = 0, p = 0;
    bool act = (i < E);
    if (act) { t = et[i]; p = atomicAdd(&lh[t], 1); }
    __syncthreads();
    if (threadIdx.x < DR) lbase[threadIdx.x] = atomicAdd(&cursor[threadIdx.x], lh[threadIdx.x]);
    __syncthreads();
    if (act) eorder[lbase[t] + p] = i;
}

// wave per edge of bucket r: kg[dst] += h[src] / cnt[dst,r]
__global__ void k_rgcn_scatter(const float* __restrict__ h, const int* __restrict__ eorder,
                               const int* __restrict__ src, const int* __restrict__ dst,
                               const float* __restrict__ cnt, float* kg,
                               const int* __restrict__ base, int r)
{
    int lane = threadIdx.x & 63;
    int wid = (blockIdx.x * blockDim.x + threadIdx.x) >> 6;
    int nw = (gridDim.x * blockDim.x) >> 6;
    int lo = base[r], hi = base[r + 1];
    for (int i = lo + wid; i < hi; i += nw) {
        int e = eorder[i];
        int s = src[e], d = dst[e];
        float norm = 1.0f / fmaxf(cnt[(size_t)d * DR + r], 1.0f);
        float2 hv = *(const float2*)&h[(size_t)s * 128 + lane * 2];
        atomicAdd(&kg[(size_t)d * 128 + lane * 2],     hv.x * norm);
        atomicAdd(&kg[(size_t)d * 128 + lane * 2 + 1], hv.y * norm);
    }
}

// ---------------------------------------------------------------- hypergraph conv
__global__ void k_slot_assign(const int* __restrict__ idx, int* slot, int* counter, int n)
{
    int i = blockIdx.x * blockDim.x + threadIdx.x;
    if (i >= n) return;
    int node = idx[i];
    if (atomicCAS(&slot[node], -1, -2) == -1) {
        int s = atomicAdd(counter, 1);
        slot[node] = s;
    }
}

// wave per incidence: edge_feat[he] += xt[node]; b_deg[he]++; sdeg[slot[node]]++
__global__ void k_hyper_edge(const float* __restrict__ xt, const int* __restrict__ nodes,
                             const int* __restrict__ edges, float* efeat, float* bdeg,
                             const int* __restrict__ slot, float* sdeg, int P)
{
    int lane = threadIdx.x & 63;
    int wid = (blockIdx.x * blockDim.x + threadIdx.x) >> 6;
    int nw = (gridDim.x * blockDim.x) >> 6;
    for (int p = wid; p < P; p += nw) {
        int node = nodes[p], he = edges[p];
        float2 v = *(const float2*)&xt[(size_t)node * 128 + lane * 2];
        atomicAdd(&efeat[(size_t)he * 128 + lane * 2],     v.x);
        atomicAdd(&efeat[(size_t)he * 128 + lane * 2 + 1], v.y);
        if (lane == 0) {
            atomicAdd(&bdeg[he], 1.0f);
            int s = slot[node];
            if (s >= 0) atomicAdd(&sdeg[s], 1.0f);
        }
    }
}

__global__ void k_edge_norm(float* efeat, const float* __restrict__ bdeg, int total)
{
    int i = blockIdx.x * blockDim.x + threadIdx.x;
    if (i < total) {
        float d = bdeg[i >> 7];
        efeat[i] *= (d > 0.f) ? 1.0f / d : 0.f;
    }
}

// wave per incidence: if node needed -> slotacc[slot] += edge_feat[he]
__global__ void k_hyper_node(const float* __restrict__ efeat, const int* __restrict__ nodes,
                             const int* __restrict__ edges, const int* __restrict__ slot,
                             float* sacc, int P)
{
    int lane = threadIdx.x & 63;
    int wid = (blockIdx.x * blockDim.x + threadIdx.x) >> 6;
    int nw = (gridDim.x * blockDim.x) >> 6;
    for (int p = wid; p < P; p += nw) {
        int s = slot[nodes[p]];
        if (s < 0) continue;
        int he = edges[p];
        float2 v = *(const float2*)&efeat[(size_t)he * 128 + lane * 2];
        atomicAdd(&sacc[(size_t)s * 128 + lane * 2],     v.x);
        atomicAdd(&sacc[(size_t)s * 128 + lane * 2 + 1], v.y);
    }
}

// related[b, colOff+l, :] = sacc[slot[idx]] / sdeg + bias
__global__ void k_hyper_gather(const float* __restrict__ sacc, const float* __restrict__ sdeg,
                               const int* __restrict__ slot, const int* __restrict__ rel_idx,
                               const float* __restrict__ bias, float* related,
                               int nIdx, int colOff)
{
    int gid = blockIdx.x * blockDim.x + threadIdx.x;
    int i = gid >> 6, lane = gid & 63;
    if (i >= nIdx) return;
    int node = rel_idx[i];
    int s = slot[node];
    float dd = sdeg[s];
    float inv = (dd > 0.f) ? 1.0f / dd : 0.f;
    int b = i / DLR, l = i % DLR;
    float2 v = *(const float2*)&sacc[(size_t)s * 128 + lane * 2];
    float2 o = make_float2(v.x * inv + bias[lane * 2], v.y * inv + bias[lane * 2 + 1]);
    *(float2*)&related[((size_t)b * 128 + colOff + l) * 128 + lane * 2] = o;
}

// ---------------------------------------------------------------- gathers / misc
__global__ void k_gather_rows(const float* __restrict__ src, const int* __restrict__ idx,
                              float* dst, int nRows)
{
    int i = blockIdx.x * blockDim.x + threadIdx.x;
    if (i >= nRows * 128) return;
    int row = i >> 7, d = i & 127;
    dst[i] = src[(size_t)idx[row] * 128 + d];
}

__global__ void k_build_ucat(const float* __restrict__ ctx, const float* __restrict__ his,
                             float* ucat)
{
    int i = blockIdx.x * blockDim.x + threadIdx.x;
    if (i >= DB * 33 * 128) return;
    int d = i & 127, l = (i >> 7) % 33, b = i / (33 * 128);
    ucat[i] = (l < 32) ? ctx[((size_t)b * 32 + l) * 128 + d] : his[(size_t)b * 128 + d];
}

// ---------------------------------------------------------------- MHA core: one block per (b,h)
__global__ __launch_bounds__(256) void k_mha(const float* __restrict__ qb,
                                             const float* __restrict__ kb,
                                             const float* __restrict__ vb,
                                             float* __restrict__ ob)
{
    int b = blockIdx.x >> 3, h = blockIdx.x & 7;
    __shared__ float Ks[128][16], Vs[128][16], Qs[32][16];
    int tid = threadIdx.x;
    for (int i = tid; i < 128 * 16; i += 256) {
        int j = i >> 4, d = i & 15;
        Ks[j][d] = kb[((size_t)b * 128 + j) * 128 + h * 16 + d];
        Vs[j][d] = vb[((size_t)b * 128 + j) * 128 + h * 16 + d];
    }
    for (int i = tid; i < 32 * 16; i += 256) {
        int q = i >> 4, d = i & 15;
        Qs[q][d] = qb[((size_t)b * 32 + q) * 128 + h * 16 + d] * 0.25f;  // 1/sqrt(16)
    }
    __syncthreads();
    int q = tid >> 3;    // 0..31
    int jg = tid & 7;    // covers keys jg*16..+15
    float lg[16];
    float m = -1e30f;
    #pragma unroll
    for (int jj = 0; jj < 16; ++jj) {
        int j = jg * 16 + jj;
        float s = 0.f;
        #pragma unroll
        for (int d = 0; d < 16; ++d) s += Qs[q][d] * Ks[j][d];
        lg[jj] = s;
        m = fmaxf(m, s);
    }
    #pragma unroll
    for (int o = 1; o < 8; o <<= 1) m = fmaxf(m, __shfl_xor(m, o));
    float sum = 0.f;
    float acc[16] = {};
    #pragma unroll
    for (int jj = 0; jj < 16; ++jj) {
        float p = __expf(lg[jj] - m);
        sum += p;
        int j = jg * 16 + jj;
        #pragma unroll
        for (int d = 0; d < 16; ++d) acc[d] += p * Vs[j][d];
    }
    #pragma unroll
    for (int o = 1; o < 8; o <<= 1) {
        sum += __shfl_xor(sum, o);
        #pragma unroll
        for (int d = 0; d < 16; ++d) acc[d] += __shfl_xor(acc[d], o);
    }
    if (jg == 0) {
        float inv = 1.0f / sum;
        #pragma unroll
        for (int d = 0; d < 16; ++d)
            ob[((size_t)b * 32 + q) * 128 + h * 16 + d] = acc[d] * inv;
    }
}

// ---------------------------------------------------------------- tanh-attention pooling, block per b
template <int L>
__global__ __launch_bounds__(128) void k_selfattn(const float* __restrict__ h,
                                                  const float* __restrict__ a,
                                                  const float* __restrict__ bvec,
                                                  float* __restrict__ out)
{
    __shared__ float As[64 * 128];   // 32KB, reused as Tm
    __shared__ float Hs[33 * 128];
    __shared__ float Ts[33];
    __shared__ float Ws[33];
    int b = blockIdx.x, tid = threadIdx.x;
    const float* hb = h + (size_t)b * L * 128;
    for (int i = tid; i < L * 32; i += 128) ((float4*)Hs)[i] = ((const float4*)hb)[i];
    float sacc[L];
    #pragma unroll
    for (int l = 0; l < L; ++l) sacc[l] = 0.f;
    for (int kc = 0; kc < 2; ++kc) {
        __syncthreads();
        for (int i = tid; i < 64 * 32; i += 128)
            ((float4*)As)[i] = ((const float4*)(a + kc * 64 * 128))[i];
        __syncthreads();
        #pragma unroll
        for (int l = 0; l < L; ++l) {
            float s = 0.f;
            for (int k = 0; k < 64; ++k) s += Hs[l * 128 + kc * 64 + k] * As[k * 128 + tid];
            sacc[l] += s;
        }
    }
    float bv = bvec[tid];
    __syncthreads();
    #pragma unroll
    for (int l = 0; l < L; ++l) As[l * 128 + tid] = tanhf(sacc[l]) * bv;  // Tm
    __syncthreads();
    if (tid < L) {
        float e = 0.f;
        for (int d = 0; d < 128; ++d) e += As[tid * 128 + d];
        Ts[tid] = e;
    }
    __syncthreads();
    if (tid == 0) {
        float m = -1e30f;
        for (int l = 0; l < L; ++l) m = fmaxf(m, Ts[l]);
        float s = 0.f;
        for (int l = 0; l < L; ++l) { float w = __expf(Ts[l] - m); Ws[l] = w; s += w; }
        float inv = 1.0f / s;
        for (int l = 0; l < L; ++l) Ws[l] *= inv;
    }
    __syncthreads();
    float o = 0.f;
    #pragma unroll
    for (int l = 0; l < L; ++l) o += Ws[l] * Hs[l * 128 + tid];
    out[(size_t)b * 128 + tid] = o;
}

// ---------------------------------------------------------------- final scoring: out[b,n] = user[b]·kg[n] + rec_bias[n]
__global__ __launch_bounds__(256) void k_score(const float* __restrict__ user,
                                               const float* __restrict__ kg,
                                               const float* __restrict__ rb,
                                               float* __restrict__ out, int Ntot)
{
    __shared__ float Us[64 * 128];
    for (int i = threadIdx.x; i < 64 * 32; i += 256)
        ((float4*)Us)[i] = ((const float4*)user)[i];
    __syncthreads();
    int n = blockIdx.x * blockDim.x + threadIdx.x;
    if (n >= Ntot) return;
    float acc[64] = {};
    const float* kr = kg + (size_t)n * 128;
    for (int d = 0; d < 128; d += 4) {
        float4 kv = *(const float4*)(kr + d);
        #pragma unroll
        for (int b = 0; b < 64; ++b) {
            acc[b] += kv.x * Us[b * 128 + d] + kv.y * Us[b * 128 + d + 1]
                    + kv.z * Us[b * 128 + d + 2] + kv.w * Us[b * 128 + d + 3];
        }
    }
    float rbn = rb[n];
    #pragma unroll
    for (int b = 0; b < 64; ++b) out[(size_t)b * Ntot + n] = acc[b] + rbn;
}

// ---------------------------------------------------------------- launch
extern "C" void kernel_launch(void* const* d_in, const int* in_sizes, int n_in,
                              void* d_out, int out_size, void* d_ws, size_t ws_size,
                              hipStream_t stream)
{
    const float* emb        = (const float*)d_in[0];
    const float* bases      = (const float*)d_in[1];
    const float* comp       = (const float*)d_in[2];
    const float* root       = (const float*)d_in[3];
    const float* rgcn_bias  = (const float*)d_in[4];
    const float* sess_theta = (const float*)d_in[5];
    const float* sess_bias  = (const float*)d_in[6];
    const float* know_theta = (const float*)d_in[7];
    const float* know_bias  = (const float*)d_in[8];
    const float* in_proj_w  = (const float*)d_in[9];
    const float* in_proj_b  = (const float*)d_in[10];
    const float* out_proj_w = (const float*)d_in[11];
    const float* out_proj_b = (const float*)d_in[12];
    const float* attn_his_a = (const float*)d_in[13];
    const float* attn_his_b = (const float*)d_in[14];
    const float* attn_a     = (const float*)d_in[15];
    const float* attn_b     = (const float*)d_in[16];
    const float* rec_bias   = (const float*)d_in[17];
    const int* edge_src     = (const int*)d_in[18];
    const int* edge_dst     = (const int*)d_in[19];
    const int* edge_type    = (const int*)d_in[20];
    const int* sess_nodes   = (const int*)d_in[21];
    const int* sess_edges   = (const int*)d_in[22];
    const int* know_nodes   = (const int*)d_in[23];
    const int* know_edges   = (const int*)d_in[24];
    const int* sess_rel_idx = (const int*)d_in[25];
    const int* know_rel_idx = (const int*)d_in[26];
    const int* context_idx  = (const int*)d_in[27];
    float* out = (float*)d_out;

    // ---- workspace layout (floats), 256-elt aligned blocks
    float* wsf = (float*)d_ws;
    size_t off = 0;
    auto alloc = [&](size_t n) { size_t r = off; off += (n + 255) & ~(size_t)255; return r; };
    float* kg     = wsf + alloc(12800000);           // N*D
    float* tmp    = wsf + alloc(12800000);           // h_r / xt
    float* cntf   = wsf + alloc(1200000);            // N*R
    float* w_all  = wsf + alloc(196608);             // R*D*D
    int*   eorder = (int*)(wsf + alloc(1000000));
    int*   thist  = (int*)(wsf + alloc(16));
    int*   tbase  = (int*)(wsf + alloc(16));
    int*   tcur   = (int*)(wsf + alloc(16));
    int*   slot_s = (int*)(wsf + alloc(100000));
    int*   slot_k = (int*)(wsf + alloc(100000));
    int*   scnt   = (int*)(wsf + alloc(16));
    float* efeat  = wsf + alloc(2560000);            // HE*D
    float* bdeg   = wsf + alloc(20000);
    float* saccb  = wsf + alloc(524288);             // 4096*128
    float* sdeg   = wsf + alloc(4096);
    float* related= wsf + alloc(1048576);            // B*128*D
    float* ctx    = wsf + alloc(262144);             // B*32*D
    float* qb     = wsf + alloc(262144);
    float* kb     = wsf + alloc(1048576);
    float* vb     = wsf + alloc(1048576);
    float* obuf   = wsf + alloc(262144);
    float* attrel = wsf + alloc(262144);
    float* his    = wsf + alloc(8192);
    float* ucat   = wsf + alloc(270336);             // B*33*D
    float* userb  = wsf + alloc(8192);
    (void)ws_size; (void)in_sizes; (void)n_in; (void)out_size;

    // ---- zero / init
    hipMemsetAsync(cntf, 0, 1200000 * 4, stream);
    hipMemsetAsync(thist, 0, 3 * 256 * 4, stream);            // thist+tbase+tcur contiguous
    hipMemsetAsync(slot_s, 0xFF, 100000 * 4, stream);
    hipMemsetAsync(slot_k, 0xFF, 100000 * 4, stream);
    hipMemsetAsync(scnt, 0, 16 * 4, stream);

    // ---- RGCN
    k_edge_count<<<(DE + 255) / 256, 256, 0, stream>>>(edge_dst, edge_type, cntf, DE);
    k_type_hist<<<(DE + 255) / 256, 256, 0, stream>>>(edge_type, thist, DE);
    k_prefix<<<1, 1, 0, stream>>>(thist, tbase, tcur);
    k_bucket<<<(DE + 255) / 256, 256, 0, stream>>>(edge_type, tcur, eorder, DE);
    k_wcomp<<<(DR * DD * DD + 255) / 256, 256, 0, stream>>>(comp, bases, w_all);

    int gemmN = (DN + 63) / 64;
    k_gemm128<<<gemmN, 256, 0, stream>>>(emb, root, rgcn_bias, kg, DN, 0);
    for (int r = 0; r < DR; ++r) {
        k_gemm128<<<gemmN, 256, 0, stream>>>(emb, w_all + (size_t)r * DD * DD, nullptr, tmp, DN, 0);
        k_rgcn_scatter<<<1024, 256, 0, stream>>>(tmp, eorder, edge_src, edge_dst, cntf, kg, tbase, r);
    }

    // ---- sess hypergraph conv
    k_slot_assign<<<16, 256, 0, stream>>>(sess_rel_idx, slot_s, scnt, DB * DLR);
    hipMemsetAsync(efeat, 0, 2560000 * 4, stream);
    hipMemsetAsync(bdeg, 0, 20000 * 4, stream);
    hipMemsetAsync(saccb, 0, 524288 * 4, stream);
    hipMemsetAsync(sdeg, 0, 4096 * 4, stream);
    k_gemm128<<<gemmN, 256, 0, stream>>>(kg, sess_theta, nullptr, tmp, DN, 0);
    k_hyper_edge<<<4096, 256, 0, stream>>>(tmp, sess_nodes, sess_edges, efeat, bdeg, slot_s, sdeg, DP);
    k_edge_norm<<<(DHE * 128 + 255) / 256, 256, 0, stream>>>(efeat, bdeg, DHE * 128);
    k_hyper_node<<<2048, 256, 0, stream>>>(efeat, sess_nodes, sess_edges, slot_s, saccb, DP);
    k_hyper_gather<<<(DB * DLR * 64 + 255) / 256, 256, 0, stream>>>(
        saccb, sdeg, slot_s, sess_rel_idx, sess_bias, related, DB * DLR, 0);

    // ---- know hypergraph conv
    k_slot_assign<<<16, 256, 0, stream>>>(know_rel_idx, slot_k, scnt + 1, DB * DLR);
    hipMemsetAsync(efeat, 0, 2560000 * 4, stream);
    hipMemsetAsync(bdeg, 0, 20000 * 4, stream);
    hipMemsetAsync(saccb, 0, 524288 * 4, stream);
    hipMemsetAsync(sdeg, 0, 4096 * 4, stream);
    k_gemm128<<<gemmN, 256, 0, stream>>>(kg, know_theta, nullptr, tmp, DN, 0);
    k_hyper_edge<<<4096, 256, 0, stream>>>(tmp, know_nodes, know_edges, efeat, bdeg, slot_k, sdeg, DP);
    k_edge_norm<<<(DHE * 128 + 255) / 256, 256, 0, stream>>>(efeat, bdeg, DHE * 128);
    k_hyper_node<<<2048, 256, 0, stream>>>(efeat, know_nodes, know_edges, slot_k, saccb, DP);
    k_hyper_gather<<<(DB * DLR * 64 + 255) / 256, 256, 0, stream>>>(
        saccb, sdeg, slot_k, know_rel_idx, know_bias, related, DB * DLR, 64);

    // ---- context + MHA
    k_gather_rows<<<(DB * DLC * 128 + 255) / 256, 256, 0, stream>>>(kg, context_idx, ctx, DB * DLC);
    k_gemm128<<<(DB * DLC + 63) / 64, 256, 0, stream>>>(ctx, in_proj_w, in_proj_b, qb, DB * DLC, 1);
    k_gemm128<<<(DB * 128 + 63) / 64, 256, 0, stream>>>(related, in_proj_w + DD * DD,
                                                        in_proj_b + DD, kb, DB * 128, 1);
    k_gemm128<<<(DB * 128 + 63) / 64, 256, 0, stream>>>(related, in_proj_w + 2 * DD * DD,
                                                        in_proj_b + 2 * DD, vb, DB * 128, 1);
    k_mha<<<DB * DNH, 256, 0, stream>>>(qb, kb, vb, obuf);
    k_gemm128<<<(DB * DLC + 63) / 64, 256, 0, stream>>>(obuf, out_proj_w, out_proj_b, attrel, DB * DLC, 1);

    // ---- pooling
    k_selfattn<32><<<DB, 128, 0, stream>>>(attrel, attn_his_a, attn_his_b, his);
    k_build_ucat<<<(DB * 33 * 128 + 255) / 256, 256, 0, stream>>>(ctx, his, ucat);
    k_selfattn<33><<<DB, 128, 0, stream>>>(ucat, attn_a, attn_b, userb);

    // ---- score
    k_score<<<(DN + 255) / 256, 256, 0, stream>>>(userb, kg, rec_bias, out, DN);
}

// Round 2
// 1898.602 us; speedup vs baseline: 1.5998x; 1.5998x over previous
//
#include <hip/hip_runtime.h>
#include <hip/hip_bf16.h>

#define DN 100000     // N entities
#define DD 128        // D
#define DR 12         // R relations
#define DNB 8         // bases
#define DE 1000000    // edges
#define DP 400000     // hyperedge incidences
#define DHE 20000     // hyperedges
#define DB 64         // batch
#define DLR 64
#define DLC 32
#define DNH 8
#define DHD 16
#define NRBINS (DR * DN)   // 1.2M
#define SCAN_CHUNK 1024
#define MCAP 65536

// ---------------------------------------------------------------- GEMM (K=128, Nout=128)
__global__ __launch_bounds__(256) void k_gemm128(
    const float* __restrict__ A, const float* __restrict__ W,
    const float* __restrict__ bias, float* __restrict__ C, int M, int trans)
{
    __shared__ float Wl[64 * 128];
    __shared__ float Al[64 * 68];
    int tid = threadIdx.x;
    int row0 = blockIdx.x * 64;
    int tr = (tid >> 5) * 8;
    int tc = (tid & 31) * 4;
    float acc[8][4] = {};
    for (int kc = 0; kc < 2; ++kc) {
        __syncthreads();
        if (!trans) {
            for (int i = tid; i < 64 * 32; i += 256)
                ((float4*)Wl)[i] = ((const float4*)(W + kc * 64 * 128))[i];
        } else {
            for (int i = tid; i < 64 * 128; i += 256) {
                int n = i >> 6, k = i & 63;
                Wl[k * 128 + n] = W[(size_t)n * 128 + kc * 64 + k];
            }
        }
        for (int i = tid; i < 64 * 16; i += 256) {
            int r = i >> 4, c4 = i & 15;
            int gr = row0 + r;
            float4 v = make_float4(0.f, 0.f, 0.f, 0.f);
            if (gr < M) v = *((const float4*)(A + (size_t)gr * 128 + kc * 64) + c4);
            *(float4*)&Al[r * 68 + c4 * 4] = v;
        }
        __syncthreads();
        for (int k = 0; k < 64; ++k) {
            float4 wv = *(const float4*)&Wl[k * 128 + tc];
            #pragma unroll
            for (int r = 0; r < 8; ++r) {
                float av = Al[(tr + r) * 68 + k];
                acc[r][0] += av * wv.x; acc[r][1] += av * wv.y;
                acc[r][2] += av * wv.z; acc[r][3] += av * wv.w;
            }
        }
    }
    float4 bv = make_float4(0.f, 0.f, 0.f, 0.f);
    if (bias) bv = *(const float4*)&bias[tc];
    #pragma unroll
    for (int r = 0; r < 8; ++r) {
        int gr = row0 + tr + r;
        if (gr < M) {
            float4 o = make_float4(acc[r][0] + bv.x, acc[r][1] + bv.y,
                                   acc[r][2] + bv.z, acc[r][3] + bv.w);
            *(float4*)(C + (size_t)gr * 128 + tc) = o;
        }
    }
}

// ---------------------------------------------------------------- generic exclusive scan (int)
// mode 0: scan values; mode 1: scan predicate (v>0)
__global__ void k_scan_pass1(const int* __restrict__ in, int n, int* __restrict__ bsum, int mode)
{
    __shared__ int red[256];
    int b = blockIdx.x, t = threadIdx.x;
    int i0 = b * SCAN_CHUNK + t * 4;
    int s = 0;
    #pragma unroll
    for (int j = 0; j < 4; ++j) {
        int i = i0 + j;
        if (i < n) { int v = in[i]; s += mode ? (v > 0) : v; }
    }
    red[t] = s;
    __syncthreads();
    for (int o = 128; o > 0; o >>= 1) {
        if (t < o) red[t] += red[t + o];
        __syncthreads();
    }
    if (t == 0) bsum[b] = red[0];
}

__global__ void k_scan_pass2(int* bsum, int nb, int* total)
{
    if (threadIdx.x == 0 && blockIdx.x == 0) {
        int acc = 0;
        for (int i = 0; i < nb; ++i) { int v = bsum[i]; bsum[i] = acc; acc += v; }
        if (total) *total = acc;
    }
}

__global__ void k_scan_pass3(const int* __restrict__ in, int n, const int* __restrict__ bsum,
                             int* __restrict__ out, int mode)
{
    __shared__ int lds[256];
    int b = blockIdx.x, t = threadIdx.x;
    int i0 = b * SCAN_CHUNK + t * 4;
    int v[4]; int s = 0;
    #pragma unroll
    for (int j = 0; j < 4; ++j) {
        int i = i0 + j;
        int x = 0;
        if (i < n) { int raw = in[i]; x = mode ? (raw > 0) : raw; }
        v[j] = x; s += x;
    }
    lds[t] = s;
    __syncthreads();
    for (int o = 1; o < 256; o <<= 1) {
        int add = (t >= o) ? lds[t - o] : 0;
        __syncthreads();
        lds[t] += add;
        __syncthreads();
    }
    int run = lds[t] - s + bsum[b];
    #pragma unroll
    for (int j = 0; j < 4; ++j) {
        int i = i0 + j;
        if (i < n) { out[i] = run; run += v[j]; }
    }
}

// ---------------------------------------------------------------- RGCN sort
__global__ void k_hist_rgcn(const int* __restrict__ dst, const int* __restrict__ et,
                            int* hist, int E)
{
    int i = blockIdx.x * blockDim.x + threadIdx.x;
    if (i < E) atomicAdd(&hist[(size_t)et[i] * DN + dst[i]], 1);
}

__global__ void k_seglist(const int* __restrict__ hist, const int* __restrict__ segpos,
                          int* __restrict__ seglist, int n)
{
    int i = blockIdx.x * blockDim.x + threadIdx.x;
    if (i < n && hist[i] > 0) seglist[segpos[i]] = i;
}

__global__ void k_stypebase(const int* __restrict__ segpos, int* stypebase)
{
    int t = threadIdx.x;
    if (t < DR) stypebase[t] = segpos[(size_t)t * DN];
    // stypebase[DR] written by scan_pass2 total
}

__global__ void k_bucket_rgcn(const int* __restrict__ src, const int* __restrict__ dst,
                              const int* __restrict__ et, const int* __restrict__ off,
                              int* cur, int* ssrc, int E)
{
    int i = blockIdx.x * blockDim.x + threadIdx.x;
    if (i >= E) return;
    int key = et[i] * DN + dst[i];
    int pos = off[key] + atomicAdd(&cur[key], 1);
    ssrc[pos] = src[i];
}

// per-type fused (segment-mean @ w[r]) scatter-accumulated into kg. Exclusive per dst within pass.
__global__ __launch_bounds__(256) void k_rgcn_gemm_scatter(
    const float* __restrict__ x, const float* __restrict__ w,
    const int* __restrict__ seglist, const int* __restrict__ soff,
    const int* __restrict__ slen, const int* __restrict__ ssrc,
    const int* __restrict__ stypebase, float* __restrict__ kg, int r)
{
    __shared__ float Al[64 * 132];
    __shared__ float Wl[64 * 128];
    int s0 = stypebase[r], s1 = stypebase[r + 1];
    int base = s0 + blockIdx.x * 64;
    if (base >= s1) return;
    int nrow = min(64, s1 - base);
    int tid = threadIdx.x;
    // staging: 4 threads per segment-row, each covers 32 cols
    {
        int row = tid >> 2;
        int c0 = (tid & 3) * 32;
        float a[32];
        #pragma unroll
        for (int j = 0; j < 32; ++j) a[j] = 0.f;
        if (row < nrow) {
            int key = seglist[base + row];
            int st = soff[key], len = slen[key];
            for (int i = 0; i < len; ++i) {
                const float* xr = x + (size_t)ssrc[st + i] * 128 + c0;
                #pragma unroll
                for (int j = 0; j < 8; ++j) {
                    float4 v = *(const float4*)(xr + j * 4);
                    a[j*4+0] += v.x; a[j*4+1] += v.y; a[j*4+2] += v.z; a[j*4+3] += v.w;
                }
            }
            float inv = 1.0f / (float)max(len, 1);
            #pragma unroll
            for (int j = 0; j < 32; ++j) Al[row * 132 + c0 + j] = a[j] * inv;
        }
    }
    int tr = (tid >> 5) * 8, tc = (tid & 31) * 4;
    float acc[8][4] = {};
    for (int kc = 0; kc < 2; ++kc) {
        __syncthreads();
        for (int i = tid; i < 64 * 32; i += 256)
            ((float4*)Wl)[i] = ((const float4*)(w + kc * 64 * 128))[i];
        __syncthreads();
        for (int k = 0; k < 64; ++k) {
            float4 wv = *(const float4*)&Wl[k * 128 + tc];
            #pragma unroll
            for (int rr = 0; rr < 8; ++rr) {
                float av = Al[(tr + rr) * 132 + kc * 64 + k];
                acc[rr][0] += av * wv.x; acc[rr][1] += av * wv.y;
                acc[rr][2] += av * wv.z; acc[rr][3] += av * wv.w;
            }
        }
    }
    #pragma unroll
    for (int rr = 0; rr < 8; ++rr) {
        int row = tr + rr;
        if (row < nrow) {
            int dst = seglist[base + row] - r * DN;
            float* c = kg + (size_t)dst * 128 + tc;
            float4 o = *(const float4*)c;
            o.x += acc[rr][0]; o.y += acc[rr][1]; o.z += acc[rr][2]; o.w += acc[rr][3];
            *(float4*)c = o;
        }
    }
}

__global__ void k_wcomp(const float* __restrict__ comp, const float* __restrict__ bases,
                        float* __restrict__ w_all)
{
    int i = blockIdx.x * blockDim.x + threadIdx.x;
    if (i >= DR * DD * DD) return;
    int r = i / (DD * DD), io = i % (DD * DD);
    float s = 0.f;
    #pragma unroll
    for (int b = 0; b < DNB; ++b) s += comp[r * DNB + b] * bases[(size_t)b * DD * DD + io];
    w_all[i] = s;
}

// ---------------------------------------------------------------- hypergraph
__global__ void k_hist_p(const int* __restrict__ he, int* hist, int P)
{
    int i = blockIdx.x * blockDim.x + threadIdx.x;
    if (i < P) atomicAdd(&hist[he[i]], 1);
}

__global__ void k_bucket_p(const int* __restrict__ nodes, const int* __restrict__ he,
                           const int* __restrict__ off, int* cur, int* pns, int P)
{
    int i = blockIdx.x * blockDim.x + threadIdx.x;
    if (i >= P) return;
    int e = he[i];
    int pos = off[e] + atomicAdd(&cur[e], 1);
    pns[pos] = nodes[i];
}

// one wave per hyperedge: efeat[he] = mean of xt[node] over its incidences
__global__ void k_hyper_agg(const float* __restrict__ xt, const int* __restrict__ pns,
                            const int* __restrict__ hoff, const int* __restrict__ hcnt,
                            float* __restrict__ efeat)
{
    int lane = threadIdx.x & 63;
    int he = (blockIdx.x * blockDim.x + threadIdx.x) >> 6;
    if (he >= DHE) return;
    int st = hoff[he], len = hcnt[he];
    float2 acc = make_float2(0.f, 0.f);
    for (int c = 0; c < len; c += 64) {
        int m = min(64, len - c);
        int nid = (c + lane < len) ? pns[st + c + lane] : 0;
        for (int j = 0; j < m; ++j) {
            int node = __shfl(nid, j);
            float2 v = *(const float2*)&xt[(size_t)node * 128 + lane * 2];
            acc.x += v.x; acc.y += v.y;
        }
    }
    float inv = (len > 0) ? 1.0f / (float)len : 0.f;
    acc.x *= inv; acc.y *= inv;
    *(float2*)&efeat[(size_t)he * 128 + lane * 2] = acc;
}

__global__ void k_slot_assign(const int* __restrict__ idx, int* slot, int* counter, int n)
{
    int i = blockIdx.x * blockDim.x + threadIdx.x;
    if (i >= n) return;
    int node = idx[i];
    if (atomicCAS(&slot[node], -1, -2) == -1) {
        int s = atomicAdd(counter, 1);
        slot[node] = s;
    }
}

__global__ void k_sdeg(const int* __restrict__ nodes, const int* __restrict__ slot,
                       float* sdeg, int P)
{
    int i = blockIdx.x * blockDim.x + threadIdx.x;
    if (i < P) {
        int s = slot[nodes[i]];
        if (s >= 0) atomicAdd(&sdeg[s], 1.0f);
    }
}

__global__ void k_match(const int* __restrict__ nodes, const int* __restrict__ he,
                        const int* __restrict__ slot, int* mcnt, int* mhe, int* msl, int P)
{
    int i = blockIdx.x * blockDim.x + threadIdx.x;
    if (i >= P) return;
    int s = slot[nodes[i]];
    if (s >= 0) {
        int idx = atomicAdd(mcnt, 1);
        if (idx < MCAP) { mhe[idx] = he[i]; msl[idx] = s; }
    }
}

__global__ void k_accmatch(const float* __restrict__ efeat, const int* __restrict__ mhe,
                           const int* __restrict__ msl, const int* __restrict__ mcnt,
                           float* sacc)
{
    int lane = threadIdx.x & 63;
    int w = (blockIdx.x * blockDim.x + threadIdx.x) >> 6;
    int nw = (gridDim.x * blockDim.x) >> 6;
    int M = min(*mcnt, MCAP);
    for (int i = w; i < M; i += nw) {
        float2 v = *(const float2*)&efeat[(size_t)mhe[i] * 128 + lane * 2];
        atomicAdd(&sacc[(size_t)msl[i] * 128 + lane * 2],     v.x);
        atomicAdd(&sacc[(size_t)msl[i] * 128 + lane * 2 + 1], v.y);
    }
}

__global__ void k_hyper_gather(const float* __restrict__ sacc, const float* __restrict__ sdeg,
                               const int* __restrict__ slot, const int* __restrict__ rel_idx,
                               const float* __restrict__ bias, float* related,
                               int nIdx, int colOff)
{
    int gid = blockIdx.x * blockDim.x + threadIdx.x;
    int i = gid >> 6, lane = gid & 63;
    if (i >= nIdx) return;
    int node = rel_idx[i];
    int s = slot[node];
    float dd = sdeg[s];
    float inv = (dd > 0.f) ? 1.0f / dd : 0.f;
    int b = i / DLR, l = i % DLR;
    float2 v = *(const float2*)&sacc[(size_t)s * 128 + lane * 2];
    float2 o = make_float2(v.x * inv + bias[lane * 2], v.y * inv + bias[lane * 2 + 1]);
    *(float2*)&related[((size_t)b * 128 + colOff + l) * 128 + lane * 2] = o;
}

// ---------------------------------------------------------------- gathers / misc
__global__ void k_gather_rows(const float* __restrict__ src, const int* __restrict__ idx,
                              float* dst, int nRows)
{
    int i = blockIdx.x * blockDim.x + threadIdx.x;
    if (i >= nRows * 128) return;
    int row = i >> 7, d = i & 127;
    dst[i] = src[(size_t)idx[row] * 128 + d];
}

__global__ void k_build_ucat(const float* __restrict__ ctx, const float* __restrict__ his,
                             float* ucat)
{
    int i = blockIdx.x * blockDim.x + threadIdx.x;
    if (i >= DB * 33 * 128) return;
    int d = i & 127, l = (i >> 7) % 33, b = i / (33 * 128);
    ucat[i] = (l < 32) ? ctx[((size_t)b * 32 + l) * 128 + d] : his[(size_t)b * 128 + d];
}

// ---------------------------------------------------------------- MHA: one block per (b,h)
__global__ __launch_bounds__(256) void k_mha(const float* __restrict__ qb,
                                             const float* __restrict__ kb,
                                             const float* __restrict__ vb,
                                             float* __restrict__ ob)
{
    int b = blockIdx.x >> 3, h = blockIdx.x & 7;
    __shared__ float Ks[128][16], Vs[128][16], Qs[32][16];
    int tid = threadIdx.x;
    for (int i = tid; i < 128 * 16; i += 256) {
        int j = i >> 4, d = i & 15;
        Ks[j][d] = kb[((size_t)b * 128 + j) * 128 + h * 16 + d];
        Vs[j][d] = vb[((size_t)b * 128 + j) * 128 + h * 16 + d];
    }
    for (int i = tid; i < 32 * 16; i += 256) {
        int q = i >> 4, d = i & 15;
        Qs[q][d] = qb[((size_t)b * 32 + q) * 128 + h * 16 + d] * 0.25f;
    }
    __syncthreads();
    int q = tid >> 3;
    int jg = tid & 7;
    float lg[16];
    float m = -1e30f;
    #pragma unroll
    for (int jj = 0; jj < 16; ++jj) {
        int j = jg * 16 + jj;
        float s = 0.f;
        #pragma unroll
        for (int d = 0; d < 16; ++d) s += Qs[q][d] * Ks[j][d];
        lg[jj] = s;
        m = fmaxf(m, s);
    }
    #pragma unroll
    for (int o = 1; o < 8; o <<= 1) m = fmaxf(m, __shfl_xor(m, o));
    float sum = 0.f;
    float acc[16] = {};
    #pragma unroll
    for (int jj = 0; jj < 16; ++jj) {
        float p = __expf(lg[jj] - m);
        sum += p;
        int j = jg * 16 + jj;
        #pragma unroll
        for (int d = 0; d < 16; ++d) acc[d] += p * Vs[j][d];
    }
    #pragma unroll
    for (int o = 1; o < 8; o <<= 1) {
        sum += __shfl_xor(sum, o);
        #pragma unroll
        for (int d = 0; d < 16; ++d) acc[d] += __shfl_xor(acc[d], o);
    }
    if (jg == 0) {
        float inv = 1.0f / sum;
        #pragma unroll
        for (int d = 0; d < 16; ++d)
            ob[((size_t)b * 32 + q) * 128 + h * 16 + d] = acc[d] * inv;
    }
}

// ---------------------------------------------------------------- tanh-attention pooling
template <int L>
__global__ __launch_bounds__(128) void k_selfattn(const float* __restrict__ h,
                                                  const float* __restrict__ a,
                                                  const float* __restrict__ bvec,
                                                  float* __restrict__ out)
{
    __shared__ float As[64 * 128];
    __shared__ float Hs[33 * 128];
    __shared__ float Ts[33];
    __shared__ float Ws[33];
    int b = blockIdx.x, tid = threadIdx.x;
    const float* hb = h + (size_t)b * L * 128;
    for (int i = tid; i < L * 32; i += 128) ((float4*)Hs)[i] = ((const float4*)hb)[i];
    float sacc[L];
    #pragma unroll
    for (int l = 0; l < L; ++l) sacc[l] = 0.f;
    for (int kc = 0; kc < 2; ++kc) {
        __syncthreads();
        for (int i = tid; i < 64 * 32; i += 128)
            ((float4*)As)[i] = ((const float4*)(a + kc * 64 * 128))[i];
        __syncthreads();
        #pragma unroll
        for (int l = 0; l < L; ++l) {
            float s = 0.f;
            for (int k = 0; k < 64; ++k) s += Hs[l * 128 + kc * 64 + k] * As[k * 128 + tid];
            sacc[l] += s;
        }
    }
    float bv = bvec[tid];
    __syncthreads();
    #pragma unroll
    for (int l = 0; l < L; ++l) As[l * 128 + tid] = tanhf(sacc[l]) * bv;
    __syncthreads();
    if (tid < L) {
        float e = 0.f;
        for (int d = 0; d < 128; ++d) e += As[tid * 128 + d];
        Ts[tid] = e;
    }
    __syncthreads();
    if (tid == 0) {
        float m = -1e30f;
        for (int l = 0; l < L; ++l) m = fmaxf(m, Ts[l]);
        float s = 0.f;
        for (int l = 0; l < L; ++l) { float w = __expf(Ts[l] - m); Ws[l] = w; s += w; }
        float inv = 1.0f / s;
        for (int l = 0; l < L; ++l) Ws[l] *= inv;
    }
    __syncthreads();
    float o = 0.f;
    #pragma unroll
    for (int l = 0; l < L; ++l) o += Ws[l] * Hs[l * 128 + tid];
    out[(size_t)b * 128 + tid] = o;
}

// ---------------------------------------------------------------- scoring
__global__ __launch_bounds__(256) void k_score(const float* __restrict__ user,
                                               const float* __restrict__ kg,
                                               const float* __restrict__ rb,
                                               float* __restrict__ out, int Ntot)
{
    __shared__ float Us[64 * 128];
    for (int i = threadIdx.x; i < 64 * 32; i += 256)
        ((float4*)Us)[i] = ((const float4*)user)[i];
    __syncthreads();
    int n = blockIdx.x * blockDim.x + threadIdx.x;
    if (n >= Ntot) return;
    float acc[64] = {};
    const float* kr = kg + (size_t)n * 128;
    for (int d = 0; d < 128; d += 4) {
        float4 kv = *(const float4*)(kr + d);
        #pragma unroll
        for (int b = 0; b < 64; ++b) {
            acc[b] += kv.x * Us[b * 128 + d] + kv.y * Us[b * 128 + d + 1]
                    + kv.z * Us[b * 128 + d + 2] + kv.w * Us[b * 128 + d + 3];
        }
    }
    float rbn = rb[n];
    #pragma unroll
    for (int b = 0; b < 64; ++b) out[(size_t)b * Ntot + n] = acc[b] + rbn;
}

// ---------------------------------------------------------------- launch
extern "C" void kernel_launch(void* const* d_in, const int* in_sizes, int n_in,
                              void* d_out, int out_size, void* d_ws, size_t ws_size,
                              hipStream_t stream)
{
    const float* emb        = (const float*)d_in[0];
    const float* bases      = (const float*)d_in[1];
    const float* comp       = (const float*)d_in[2];
    const float* root       = (const float*)d_in[3];
    const float* rgcn_bias  = (const float*)d_in[4];
    const float* sess_theta = (const float*)d_in[5];
    const float* sess_bias  = (const float*)d_in[6];
    const float* know_theta = (const float*)d_in[7];
    const float* know_bias  = (const float*)d_in[8];
    const float* in_proj_w  = (const float*)d_in[9];
    const float* in_proj_b  = (const float*)d_in[10];
    const float* out_proj_w = (const float*)d_in[11];
    const float* out_proj_b = (const float*)d_in[12];
    const float* attn_his_a = (const float*)d_in[13];
    const float* attn_his_b = (const float*)d_in[14];
    const float* attn_a     = (const float*)d_in[15];
    const float* attn_b     = (const float*)d_in[16];
    const float* rec_bias   = (const float*)d_in[17];
    const int* edge_src     = (const int*)d_in[18];
    const int* edge_dst     = (const int*)d_in[19];
    const int* edge_type    = (const int*)d_in[20];
    const int* sess_nodes   = (const int*)d_in[21];
    const int* sess_edges   = (const int*)d_in[22];
    const int* know_nodes   = (const int*)d_in[23];
    const int* know_edges   = (const int*)d_in[24];
    const int* sess_rel_idx = (const int*)d_in[25];
    const int* know_rel_idx = (const int*)d_in[26];
    const int* context_idx  = (const int*)d_in[27];
    float* out = (float*)d_out;

    float* wsf = (float*)d_ws;
    size_t off = 0;
    auto alloc = [&](size_t n) { size_t r = off; off += (n + 255) & ~(size_t)255; return r; };
    float* kg      = wsf + alloc(12800000);          // N*D
    float* tmp     = wsf + alloc(12800000);          // xt (hyper phase); RGCN sort bufs (rgcn phase)
    float* w_all   = wsf + alloc(196608);
    int*   bsum    = (int*)(wsf + alloc(2048));
    int*   stybase = (int*)(wsf + alloc(16));        // [0..11] type seg base, [12] = total S
    int*   hhist   = (int*)(wsf + alloc(20000));
    int*   hoff    = (int*)(wsf + alloc(20000));
    int*   hcur    = (int*)(wsf + alloc(20000));
    int*   pns     = (int*)(wsf + alloc(400000));
    int*   mcnt    = (int*)(wsf + alloc(16));
    int*   mhe     = (int*)(wsf + alloc(MCAP));
    int*   msl     = (int*)(wsf + alloc(MCAP));
    int*   slot_s  = (int*)(wsf + alloc(100000));
    int*   slot_k  = (int*)(wsf + alloc(100000));
    int*   scnt    = (int*)(wsf + alloc(16));
    float* efeat   = wsf + alloc(2560000);
    float* sdeg    = wsf + alloc(4096);
    float* sacc    = wsf + alloc(524288);
    float* related = wsf + alloc(1048576);
    float* ctx     = wsf + alloc(262144);
    float* qb      = wsf + alloc(262144);
    float* kb      = wsf + alloc(1048576);
    float* vb      = wsf + alloc(1048576);
    float* obuf    = wsf + alloc(262144);
    float* attrel  = wsf + alloc(262144);
    float* his     = wsf + alloc(8192);
    float* ucat    = wsf + alloc(270336);
    float* userb   = wsf + alloc(8192);
    (void)ws_size; (void)in_sizes; (void)n_in; (void)out_size;

    // RGCN sort buffers live inside tmp (xt written only after RGCN completes)
    int* hist    = (int*)tmp;                 // 1.2M
    int* soff    = (int*)tmp + 1200000;       // 1.2M
    int* segpos  = (int*)tmp + 2400000;       // 1.2M (reused as bucket cursor)
    int* seglist = (int*)tmp + 3600000;       // 1.2M
    int* ssrc    = (int*)tmp + 4800000;       // 1.0M

    const int nbR = (NRBINS + SCAN_CHUNK - 1) / SCAN_CHUNK;   // 1172
    const int nbH = (DHE + SCAN_CHUNK - 1) / SCAN_CHUNK;      // 20

    // ---------------- RGCN: sort edges by (type, dst)
    hipMemsetAsync(hist, 0, NRBINS * 4, stream);
    hipMemsetAsync(slot_s, 0xFF, 100000 * 4, stream);
    hipMemsetAsync(slot_k, 0xFF, 100000 * 4, stream);
    hipMemsetAsync(scnt, 0, 16 * 4, stream);
    k_hist_rgcn<<<(DE + 255) / 256, 256, 0, stream>>>(edge_dst, edge_type, hist, DE);
    // scan hist -> soff
    k_scan_pass1<<<nbR, 256, 0, stream>>>(hist, NRBINS, bsum, 0);
    k_scan_pass2<<<1, 64, 0, stream>>>(bsum, nbR, nullptr);
    k_scan_pass3<<<nbR, 256, 0, stream>>>(hist, NRBINS, bsum, soff, 0);
    // predicate scan hist -> segpos (+ total S)
    k_scan_pass1<<<nbR, 256, 0, stream>>>(hist, NRBINS, bsum, 1);
    k_scan_pass2<<<1, 64, 0, stream>>>(bsum, nbR, stybase + DR);
    k_scan_pass3<<<nbR, 256, 0, stream>>>(hist, NRBINS, bsum, segpos, 1);
    k_stypebase<<<1, 64, 0, stream>>>(segpos, stybase);
    k_seglist<<<(NRBINS + 255) / 256, 256, 0, stream>>>(hist, segpos, seglist, NRBINS);
    // segpos now free -> bucket cursor
    hipMemsetAsync(segpos, 0, NRBINS * 4, stream);
    k_bucket_rgcn<<<(DE + 255) / 256, 256, 0, stream>>>(edge_src, edge_dst, edge_type,
                                                        soff, segpos, ssrc, DE);
    k_wcomp<<<(DR * DD * DD + 255) / 256, 256, 0, stream>>>(comp, bases, w_all);

    int gemmN = (DN + 63) / 64;
    k_gemm128<<<gemmN, 256, 0, stream>>>(emb, root, rgcn_bias, kg, DN, 0);
    for (int r = 0; r < DR; ++r)
        k_rgcn_gemm_scatter<<<gemmN, 256, 0, stream>>>(emb, w_all + (size_t)r * DD * DD,
                                                       seglist, soff, hist, ssrc, stybase, kg, r);

    // ---------------- sess hypergraph
    k_slot_assign<<<16, 256, 0, stream>>>(sess_rel_idx, slot_s, scnt, DB * DLR);
    k_gemm128<<<gemmN, 256, 0, stream>>>(kg, sess_theta, nullptr, tmp, DN, 0);
    hipMemsetAsync(hhist, 0, DHE * 4, stream);
    hipMemsetAsync(hcur, 0, DHE * 4, stream);
    hipMemsetAsync(sdeg, 0, 4096 * 4, stream);
    hipMemsetAsync(sacc, 0, 524288 * 4, stream);
    hipMemsetAsync(mcnt, 0, 16 * 4, stream);
    k_hist_p<<<(DP + 255) / 256, 256, 0, stream>>>(sess_edges, hhist, DP);
    k_scan_pass1<<<nbH, 256, 0, stream>>>(hhist, DHE, bsum, 0);
    k_scan_pass2<<<1, 64, 0, stream>>>(bsum, nbH, nullptr);
    k_scan_pass3<<<nbH, 256, 0, stream>>>(hhist, DHE, bsum, hoff, 0);
    k_bucket_p<<<(DP + 255) / 256, 256, 0, stream>>>(sess_nodes, sess_edges, hoff, hcur, pns, DP);
    k_hyper_agg<<<(DHE * 64 + 255) / 256, 256, 0, stream>>>(tmp, pns, hoff, hhist, efeat);
    k_sdeg<<<(DP + 255) / 256, 256, 0, stream>>>(sess_nodes, slot_s, sdeg, DP);
    k_match<<<(DP + 255) / 256, 256, 0, stream>>>(sess_nodes, sess_edges, slot_s, mcnt, mhe, msl, DP);
    k_accmatch<<<256, 256, 0, stream>>>(efeat, mhe, msl, mcnt, sacc);
    k_hyper_gather<<<(DB * DLR * 64 + 255) / 256, 256, 0, stream>>>(
        sacc, sdeg, slot_s, sess_rel_idx, sess_bias, related, DB * DLR, 0);

    // ---------------- know hypergraph
    k_slot_assign<<<16, 256, 0, stream>>>(know_rel_idx, slot_k, scnt + 1, DB * DLR);
    k_gemm128<<<gemmN, 256, 0, stream>>>(kg, know_theta, nullptr, tmp, DN, 0);
    hipMemsetAsync(hhist, 0, DHE * 4, stream);
    hipMemsetAsync(hcur, 0, DHE * 4, stream);
    hipMemsetAsync(sdeg, 0, 4096 * 4, stream);
    hipMemsetAsync(sacc, 0, 524288 * 4, stream);
    hipMemsetAsync(mcnt, 0, 16 * 4, stream);
    k_hist_p<<<(DP + 255) / 256, 256, 0, stream>>>(know_edges, hhist, DP);
    k_scan_pass1<<<nbH, 256, 0, stream>>>(hhist, DHE, bsum, 0);
    k_scan_pass2<<<1, 64, 0, stream>>>(bsum, nbH, nullptr);
    k_scan_pass3<<<nbH, 256, 0, stream>>>(hhist, DHE, bsum, hoff, 0);
    k_bucket_p<<<(DP + 255) / 256, 256, 0, stream>>>(know_nodes, know_edges, hoff, hcur, pns, DP);
    k_hyper_agg<<<(DHE * 64 + 255) / 256, 256, 0, stream>>>(tmp, pns, hoff, hhist, efeat);
    k_sdeg<<<(DP + 255) / 256, 256, 0, stream>>>(know_nodes, slot_k, sdeg, DP);
    k_match<<<(DP + 255) / 256, 256, 0, stream>>>(know_nodes, know_edges, slot_k, mcnt, mhe, msl, DP);
    k_accmatch<<<256, 256, 0, stream>>>(efeat, mhe, msl, mcnt, sacc);
    k_hyper_gather<<<(DB * DLR * 64 + 255) / 256, 256, 0, stream>>>(
        sacc, sdeg, slot_k, know_rel_idx, know_bias, related, DB * DLR, 64);

    // ---------------- context + MHA
    k_gather_rows<<<(DB * DLC * 128 + 255) / 256, 256, 0, stream>>>(kg, context_idx, ctx, DB * DLC);
    k_gemm128<<<(DB * DLC + 63) / 64, 256, 0, stream>>>(ctx, in_proj_w, in_proj_b, qb, DB * DLC, 1);
    k_gemm128<<<(DB * 128 + 63) / 64, 256, 0, stream>>>(related, in_proj_w + DD * DD,
                                                        in_proj_b + DD, kb, DB * 128, 1);
    k_gemm128<<<(DB * 128 + 63) / 64, 256, 0, stream>>>(related, in_proj_w + 2 * DD * DD,
                                                        in_proj_b + 2 * DD, vb, DB * 128, 1);
    k_mha<<<DB * DNH, 256, 0, stream>>>(qb, kb, vb, obuf);
    k_gemm128<<<(DB * DLC + 63) / 64, 256, 0, stream>>>(obuf, out_proj_w, out_proj_b, attrel, DB * DLC, 1);

    // ---------------- pooling + score
    k_selfattn<32><<<DB, 128, 0, stream>>>(attrel, attn_his_a, attn_his_b, his);
    k_build_ucat<<<(DB * 33 * 128 + 255) / 256, 256, 0, stream>>>(ctx, his, ucat);
    k_selfattn<33><<<DB, 128, 0, stream>>>(ucat, attn_a, attn_b, userb);
    k_score<<<(DN + 255) / 256, 256, 0, stream>>>(userb, kg, rec_bias, out, DN);
}

// Round 3
// 1474.206 us; speedup vs baseline: 2.0603x; 1.2879x over previous
//
#include <hip/hip_runtime.h>
#include <hip/hip_bf16.h>

#define DN 100000     // N entities
#define DD 128        // D
#define DR 12         // R relations
#define DNB 8         // bases
#define DE 1000000    // edges
#define DP 400000     // hyperedge incidences
#define DHE 20000     // hyperedges
#define DB 64         // batch
#define DLR 64
#define DLC 32
#define DNH 8
#define DHD 16
#define NRBINS (DR * DN)   // 1.2M
#define SCAN_CHUNK 1024
#define MCAP 65536

typedef unsigned short ushortT;
typedef unsigned int uintT;
typedef __attribute__((ext_vector_type(8))) short s8v;
typedef __attribute__((ext_vector_type(4))) float f4v;

#define APAD 136   // 64 rows of K=128 bf16, stride 272B (16B-aligned, 2-way-free banks)
#define BPAD 40    // 128 rows of K=32 bf16, stride 80B  (16B-aligned, 2-way-free banks)

__device__ __forceinline__ ushortT rneb(float v) {
    uintT b = __float_as_uint(v);
    return (ushortT)((b + 0x7FFFu + ((b >> 16) & 1u)) >> 16);
}
__device__ __forceinline__ float b2f(ushortT h) {
    return __uint_as_float(((uintT)h) << 16);
}

// convert 8 floats -> hi/lo bf16 packed uint4 each, store to LDS (16B aligned)
__device__ __forceinline__ void split_store8(ushortT* hbase, ushortT* lbase, const float* v)
{
    ushortT h[8], l[8];
    #pragma unroll
    for (int j = 0; j < 8; ++j) {
        h[j] = rneb(v[j]);
        l[j] = rneb(v[j] - b2f(h[j]));
    }
    uint4 hv = make_uint4((uintT)h[0] | ((uintT)h[1] << 16), (uintT)h[2] | ((uintT)h[3] << 16),
                          (uintT)h[4] | ((uintT)h[5] << 16), (uintT)h[6] | ((uintT)h[7] << 16));
    uint4 lv = make_uint4((uintT)l[0] | ((uintT)l[1] << 16), (uintT)l[2] | ((uintT)l[3] << 16),
                          (uintT)l[4] | ((uintT)l[5] << 16), (uintT)l[6] | ((uintT)l[7] << 16));
    *(uint4*)hbase = hv;
    *(uint4*)lbase = lv;
}

// ---------------------------------------------------------------- MFMA GEMM (split-bf16, ~fp32 accuracy)
// C[m,n] = sum_k A[m,k]*W(k,n) + bias[n]; W(k,n) = trans ? W[n*128+k] : W[k*128+n]
__global__ __launch_bounds__(256) void k_mfma_gemm(
    const float* __restrict__ A, const float* __restrict__ W,
    const float* __restrict__ bias, float* __restrict__ C, int M, int trans)
{
    __shared__ __align__(16) ushortT Ah[64 * APAD], Al[64 * APAD];
    __shared__ __align__(16) ushortT Bh[128 * BPAD], Bl[128 * BPAD];
    int tid = threadIdx.x;
    int row0 = blockIdx.x * 64;
    // ---- A stage (full K, split)
    {
        int row = tid >> 2, c0 = (tid & 3) * 32;
        int gr = row0 + row;
        const float* ar = A + (size_t)gr * 128 + c0;
        #pragma unroll
        for (int g = 0; g < 4; ++g) {
            float v[8] = {};
            if (gr < M) {
                float4 u0 = *(const float4*)(ar + g * 8);
                float4 u1 = *(const float4*)(ar + g * 8 + 4);
                v[0]=u0.x; v[1]=u0.y; v[2]=u0.z; v[3]=u0.w;
                v[4]=u1.x; v[5]=u1.y; v[6]=u1.z; v[7]=u1.w;
            }
            split_store8(&Ah[row * APAD + c0 + g * 8], &Al[row * APAD + c0 + g * 8], v);
        }
    }
    f4v acc[8] = {};
    int w = tid >> 6, lane = tid & 63, m = lane & 15, quad = lane >> 4;
    for (int kc = 0; kc < 4; ++kc) {
        __syncthreads();
        // ---- B chunk stage (K=32, transposed to [n][k], split)
        #pragma unroll
        for (int t2 = 0; t2 < 2; ++t2) {
            int task = tid + t2 * 256;
            int n = task & 127, kg = task >> 7;
            float v[8];
            if (!trans) {
                #pragma unroll
                for (int j = 0; j < 8; ++j)
                    v[j] = W[(size_t)(kc * 32 + kg * 8 + j) * 128 + n];
            } else {
                const float* wr = W + (size_t)n * 128 + kc * 32 + kg * 8;
                float4 u0 = *(const float4*)wr, u1 = *(const float4*)(wr + 4);
                v[0]=u0.x; v[1]=u0.y; v[2]=u0.z; v[3]=u0.w;
                v[4]=u1.x; v[5]=u1.y; v[6]=u1.z; v[7]=u1.w;
            }
            split_store8(&Bh[n * BPAD + kg * 8], &Bl[n * BPAD + kg * 8], v);
        }
        __syncthreads();
        s8v ah = *(const s8v*)&Ah[(w * 16 + m) * APAD + kc * 32 + quad * 8];
        s8v al = *(const s8v*)&Al[(w * 16 + m) * APAD + kc * 32 + quad * 8];
        #pragma unroll
        for (int nt = 0; nt < 8; ++nt) {
            s8v bh = *(const s8v*)&Bh[(nt * 16 + m) * BPAD + quad * 8];
            s8v bl = *(const s8v*)&Bl[(nt * 16 + m) * BPAD + quad * 8];
            acc[nt] = __builtin_amdgcn_mfma_f32_16x16x32_bf16(ah, bh, acc[nt], 0, 0, 0);
            acc[nt] = __builtin_amdgcn_mfma_f32_16x16x32_bf16(al, bh, acc[nt], 0, 0, 0);
            acc[nt] = __builtin_amdgcn_mfma_f32_16x16x32_bf16(ah, bl, acc[nt], 0, 0, 0);
        }
    }
    float bv[8];
    #pragma unroll
    for (int nt = 0; nt < 8; ++nt) bv[nt] = bias ? bias[nt * 16 + m] : 0.f;
    #pragma unroll
    for (int rr = 0; rr < 4; ++rr) {
        int gr = row0 + w * 16 + quad * 4 + rr;
        if (gr < M) {
            #pragma unroll
            for (int nt = 0; nt < 8; ++nt)
                C[(size_t)gr * 128 + nt * 16 + m] = acc[nt][rr] + bv[nt];
        }
    }
}

// ---------------------------------------------------------------- RGCN fused segment-mean @ w[r] -> kg += (MFMA)
__global__ __launch_bounds__(256) void k_mfma_rgcn(
    const float* __restrict__ x, const float* __restrict__ wmat,
    const int* __restrict__ seglist, const int* __restrict__ soff,
    const int* __restrict__ slen, const int* __restrict__ ssrc,
    const int* __restrict__ stypebase, float* __restrict__ kg, int r)
{
    __shared__ __align__(16) ushortT Ah[64 * APAD], Al[64 * APAD];
    __shared__ __align__(16) ushortT Bh[128 * BPAD], Bl[128 * BPAD];
    int s0 = stypebase[r], s1 = stypebase[r + 1];
    int base = s0 + blockIdx.x * 64;
    if (base >= s1) return;
    int nrow = min(64, s1 - base);
    int tid = threadIdx.x;
    // ---- A stage: segment means (full K, split)
    {
        int row = tid >> 2, c0 = (tid & 3) * 32;
        float a[32] = {};
        if (row < nrow) {
            int key = seglist[base + row];
            int st = soff[key], len = slen[key];
            for (int i = 0; i < len; ++i) {
                const float* xr = x + (size_t)ssrc[st + i] * 128 + c0;
                #pragma unroll
                for (int j = 0; j < 8; ++j) {
                    float4 v = *(const float4*)(xr + j * 4);
                    a[j*4+0] += v.x; a[j*4+1] += v.y; a[j*4+2] += v.z; a[j*4+3] += v.w;
                }
            }
            float inv = 1.0f / (float)max(len, 1);
            #pragma unroll
            for (int j = 0; j < 32; ++j) a[j] *= inv;
        }
        #pragma unroll
        for (int g = 0; g < 4; ++g)
            split_store8(&Ah[row * APAD + c0 + g * 8], &Al[row * APAD + c0 + g * 8], a + g * 8);
    }
    f4v acc[8] = {};
    int w = tid >> 6, lane = tid & 63, m = lane & 15, quad = lane >> 4;
    for (int kc = 0; kc < 4; ++kc) {
        __syncthreads();
        #pragma unroll
        for (int t2 = 0; t2 < 2; ++t2) {
            int task = tid + t2 * 256;
            int n = task & 127, kg2 = task >> 7;
            float v[8];
            #pragma unroll
            for (int j = 0; j < 8; ++j)
                v[j] = wmat[(size_t)(kc * 32 + kg2 * 8 + j) * 128 + n];
            split_store8(&Bh[n * BPAD + kg2 * 8], &Bl[n * BPAD + kg2 * 8], v);
        }
        __syncthreads();
        s8v ah = *(const s8v*)&Ah[(w * 16 + m) * APAD + kc * 32 + quad * 8];
        s8v al = *(const s8v*)&Al[(w * 16 + m) * APAD + kc * 32 + quad * 8];
        #pragma unroll
        for (int nt = 0; nt < 8; ++nt) {
            s8v bh = *(const s8v*)&Bh[(nt * 16 + m) * BPAD + quad * 8];
            s8v bl = *(const s8v*)&Bl[(nt * 16 + m) * BPAD + quad * 8];
            acc[nt] = __builtin_amdgcn_mfma_f32_16x16x32_bf16(ah, bh, acc[nt], 0, 0, 0);
            acc[nt] = __builtin_amdgcn_mfma_f32_16x16x32_bf16(al, bh, acc[nt], 0, 0, 0);
            acc[nt] = __builtin_amdgcn_mfma_f32_16x16x32_bf16(ah, bl, acc[nt], 0, 0, 0);
        }
    }
    // ---- epilogue: non-atomic RMW into kg (dst unique within type pass)
    #pragma unroll
    for (int rr = 0; rr < 4; ++rr) {
        int rt = w * 16 + quad * 4 + rr;
        if (rt < nrow) {
            int dst = seglist[base + rt] - r * DN;
            float* kr = kg + (size_t)dst * 128 + m;
            #pragma unroll
            for (int nt = 0; nt < 8; ++nt)
                kr[nt * 16] += acc[nt][rr];
        }
    }
}

// ---------------------------------------------------------------- fp32 GEMM (small M only)
__global__ __launch_bounds__(256) void k_gemm128(
    const float* __restrict__ A, const float* __restrict__ W,
    const float* __restrict__ bias, float* __restrict__ C, int M, int trans)
{
    __shared__ float Wl[64 * 128];
    __shared__ float Alds[64 * 68];
    int tid = threadIdx.x;
    int row0 = blockIdx.x * 64;
    int tr = (tid >> 5) * 8;
    int tc = (tid & 31) * 4;
    float acc[8][4] = {};
    for (int kc = 0; kc < 2; ++kc) {
        __syncthreads();
        if (!trans) {
            for (int i = tid; i < 64 * 32; i += 256)
                ((float4*)Wl)[i] = ((const float4*)(W + kc * 64 * 128))[i];
        } else {
            for (int i = tid; i < 64 * 128; i += 256) {
                int n = i >> 6, k = i & 63;
                Wl[k * 128 + n] = W[(size_t)n * 128 + kc * 64 + k];
            }
        }
        for (int i = tid; i < 64 * 16; i += 256) {
            int r = i >> 4, c4 = i & 15;
            int gr = row0 + r;
            float4 v = make_float4(0.f, 0.f, 0.f, 0.f);
            if (gr < M) v = *((const float4*)(A + (size_t)gr * 128 + kc * 64) + c4);
            *(float4*)&Alds[r * 68 + c4 * 4] = v;
        }
        __syncthreads();
        for (int k = 0; k < 64; ++k) {
            float4 wv = *(const float4*)&Wl[k * 128 + tc];
            #pragma unroll
            for (int r = 0; r < 8; ++r) {
                float av = Alds[(tr + r) * 68 + k];
                acc[r][0] += av * wv.x; acc[r][1] += av * wv.y;
                acc[r][2] += av * wv.z; acc[r][3] += av * wv.w;
            }
        }
    }
    float4 bv = make_float4(0.f, 0.f, 0.f, 0.f);
    if (bias) bv = *(const float4*)&bias[tc];
    #pragma unroll
    for (int r = 0; r < 8; ++r) {
        int gr = row0 + tr + r;
        if (gr < M) {
            float4 o = make_float4(acc[r][0] + bv.x, acc[r][1] + bv.y,
                                   acc[r][2] + bv.z, acc[r][3] + bv.w);
            *(float4*)(C + (size_t)gr * 128 + tc) = o;
        }
    }
}

// ---------------------------------------------------------------- scans
__global__ void k_scan_pass1(const int* __restrict__ in, int n, int* __restrict__ bsum, int mode)
{
    __shared__ int red[256];
    int b = blockIdx.x, t = threadIdx.x;
    int i0 = b * SCAN_CHUNK + t * 4;
    int s = 0;
    #pragma unroll
    for (int j = 0; j < 4; ++j) {
        int i = i0 + j;
        if (i < n) { int v = in[i]; s += mode ? (v > 0) : v; }
    }
    red[t] = s;
    __syncthreads();
    for (int o = 128; o > 0; o >>= 1) {
        if (t < o) red[t] += red[t + o];
        __syncthreads();
    }
    if (t == 0) bsum[b] = red[0];
}

// parallel single-block scan of block sums (replaces serial pass2)
__global__ __launch_bounds__(256) void k_scan_pass2p(int* bsum, int nb, int* total)
{
    __shared__ int lds[256];
    __shared__ int carry;
    int t = threadIdx.x;
    if (t == 0) carry = 0;
    __syncthreads();
    for (int c0 = 0; c0 < nb; c0 += 256) {
        int i = c0 + t;
        int v = (i < nb) ? bsum[i] : 0;
        lds[t] = v;
        __syncthreads();
        for (int o = 1; o < 256; o <<= 1) {
            int add = (t >= o) ? lds[t - o] : 0;
            __syncthreads();
            lds[t] += add;
            __syncthreads();
        }
        int myc = carry;
        if (i < nb) bsum[i] = lds[t] - v + myc;
        int tot = lds[255];
        __syncthreads();
        if (t == 0) carry = myc + tot;
        __syncthreads();
    }
    if (total && t == 0) *total = carry;
}

__global__ void k_scan_pass3(const int* __restrict__ in, int n, const int* __restrict__ bsum,
                             int* __restrict__ out, int mode)
{
    __shared__ int lds[256];
    int b = blockIdx.x, t = threadIdx.x;
    int i0 = b * SCAN_CHUNK + t * 4;
    int v[4]; int s = 0;
    #pragma unroll
    for (int j = 0; j < 4; ++j) {
        int i = i0 + j;
        int x = 0;
        if (i < n) { int raw = in[i]; x = mode ? (raw > 0) : raw; }
        v[j] = x; s += x;
    }
    lds[t] = s;
    __syncthreads();
    for (int o = 1; o < 256; o <<= 1) {
        int add = (t >= o) ? lds[t - o] : 0;
        __syncthreads();
        lds[t] += add;
        __syncthreads();
    }
    int run = lds[t] - s + bsum[b];
    #pragma unroll
    for (int j = 0; j < 4; ++j) {
        int i = i0 + j;
        if (i < n) { out[i] = run; run += v[j]; }
    }
}

// ---------------------------------------------------------------- RGCN sort
__global__ void k_hist_rgcn(const int* __restrict__ dst, const int* __restrict__ et,
                            int* hist, int E)
{
    int i = blockIdx.x * blockDim.x + threadIdx.x;
    if (i < E) atomicAdd(&hist[(size_t)et[i] * DN + dst[i]], 1);
}

__global__ void k_seglist(const int* __restrict__ hist, const int* __restrict__ segpos,
                          int* __restrict__ seglist, int n)
{
    int i = blockIdx.x * blockDim.x + threadIdx.x;
    if (i < n && hist[i] > 0) seglist[segpos[i]] = i;
}

__global__ void k_stypebase(const int* __restrict__ segpos, int* stypebase)
{
    int t = threadIdx.x;
    if (t < DR) stypebase[t] = segpos[(size_t)t * DN];
}

__global__ void k_bucket_rgcn(const int* __restrict__ src, const int* __restrict__ dst,
                              const int* __restrict__ et, const int* __restrict__ off,
                              int* cur, int* ssrc, int E)
{
    int i = blockIdx.x * blockDim.x + threadIdx.x;
    if (i >= E) return;
    int key = et[i] * DN + dst[i];
    int pos = off[key] + atomicAdd(&cur[key], 1);
    ssrc[pos] = src[i];
}

__global__ void k_wcomp(const float* __restrict__ comp, const float* __restrict__ bases,
                        float* __restrict__ w_all)
{
    int i = blockIdx.x * blockDim.x + threadIdx.x;
    if (i >= DR * DD * DD) return;
    int r = i / (DD * DD), io = i % (DD * DD);
    float s = 0.f;
    #pragma unroll
    for (int b = 0; b < DNB; ++b) s += comp[r * DNB + b] * bases[(size_t)b * DD * DD + io];
    w_all[i] = s;
}

// ---------------------------------------------------------------- hypergraph
__global__ void k_hist_p(const int* __restrict__ he, int* hist, int P)
{
    int i = blockIdx.x * blockDim.x + threadIdx.x;
    if (i < P) atomicAdd(&hist[he[i]], 1);
}

__global__ void k_bucket_p(const int* __restrict__ nodes, const int* __restrict__ he,
                           const int* __restrict__ off, int* cur, int* pns, int P)
{
    int i = blockIdx.x * blockDim.x + threadIdx.x;
    if (i >= P) return;
    int e = he[i];
    int pos = off[e] + atomicAdd(&cur[e], 1);
    pns[pos] = nodes[i];
}

__global__ void k_hyper_agg(const float* __restrict__ xt, const int* __restrict__ pns,
                            const int* __restrict__ hoff, const int* __restrict__ hcnt,
                            float* __restrict__ efeat)
{
    int lane = threadIdx.x & 63;
    int he = (blockIdx.x * blockDim.x + threadIdx.x) >> 6;
    if (he >= DHE) return;
    int st = hoff[he], len = hcnt[he];
    float2 acc = make_float2(0.f, 0.f);
    for (int c = 0; c < len; c += 64) {
        int m = min(64, len - c);
        int nid = (c + lane < len) ? pns[st + c + lane] : 0;
        for (int j = 0; j < m; ++j) {
            int node = __shfl(nid, j);
            float2 v = *(const float2*)&xt[(size_t)node * 128 + lane * 2];
            acc.x += v.x; acc.y += v.y;
        }
    }
    float inv = (len > 0) ? 1.0f / (float)len : 0.f;
    acc.x *= inv; acc.y *= inv;
    *(float2*)&efeat[(size_t)he * 128 + lane * 2] = acc;
}

__global__ void k_slot_assign(const int* __restrict__ idx, int* slot, int* counter, int n)
{
    int i = blockIdx.x * blockDim.x + threadIdx.x;
    if (i >= n) return;
    int node = idx[i];
    if (atomicCAS(&slot[node], -1, -2) == -1) {
        int s = atomicAdd(counter, 1);
        slot[node] = s;
    }
}

__global__ void k_sdeg(const int* __restrict__ nodes, const int* __restrict__ slot,
                       float* sdeg, int P)
{
    int i = blockIdx.x * blockDim.x + threadIdx.x;
    if (i < P) {
        int s = slot[nodes[i]];
        if (s >= 0) atomicAdd(&sdeg[s], 1.0f);
    }
}

__global__ void k_match(const int* __restrict__ nodes, const int* __restrict__ he,
                        const int* __restrict__ slot, int* mcnt, int* mhe, int* msl, int P)
{
    int i = blockIdx.x * blockDim.x + threadIdx.x;
    if (i >= P) return;
    int s = slot[nodes[i]];
    if (s >= 0) {
        int idx = atomicAdd(mcnt, 1);
        if (idx < MCAP) { mhe[idx] = he[i]; msl[idx] = s; }
    }
}

__global__ void k_accmatch(const float* __restrict__ efeat, const int* __restrict__ mhe,
                           const int* __restrict__ msl, const int* __restrict__ mcnt,
                           float* sacc)
{
    int lane = threadIdx.x & 63;
    int w = (blockIdx.x * blockDim.x + threadIdx.x) >> 6;
    int nw = (gridDim.x * blockDim.x) >> 6;
    int M = min(*mcnt, MCAP);
    for (int i = w; i < M; i += nw) {
        float2 v = *(const float2*)&efeat[(size_t)mhe[i] * 128 + lane * 2];
        atomicAdd(&sacc[(size_t)msl[i] * 128 + lane * 2],     v.x);
        atomicAdd(&sacc[(size_t)msl[i] * 128 + lane * 2 + 1], v.y);
    }
}

__global__ void k_hyper_gather(const float* __restrict__ sacc, const float* __restrict__ sdeg,
                               const int* __restrict__ slot, const int* __restrict__ rel_idx,
                               const float* __restrict__ bias, float* related,
                               int nIdx, int colOff)
{
    int gid = blockIdx.x * blockDim.x + threadIdx.x;
    int i = gid >> 6, lane = gid & 63;
    if (i >= nIdx) return;
    int node = rel_idx[i];
    int s = slot[node];
    float dd = sdeg[s];
    float inv = (dd > 0.f) ? 1.0f / dd : 0.f;
    int b = i / DLR, l = i % DLR;
    float2 v = *(const float2*)&sacc[(size_t)s * 128 + lane * 2];
    float2 o = make_float2(v.x * inv + bias[lane * 2], v.y * inv + bias[lane * 2 + 1]);
    *(float2*)&related[((size_t)b * 128 + colOff + l) * 128 + lane * 2] = o;
}

// ---------------------------------------------------------------- gathers / misc
__global__ void k_gather_rows(const float* __restrict__ src, const int* __restrict__ idx,
                              float* dst, int nRows)
{
    int i = blockIdx.x * blockDim.x + threadIdx.x;
    if (i >= nRows * 128) return;
    int row = i >> 7, d = i & 127;
    dst[i] = src[(size_t)idx[row] * 128 + d];
}

__global__ void k_build_ucat(const float* __restrict__ ctx, const float* __restrict__ his,
                             float* ucat)
{
    int i = blockIdx.x * blockDim.x + threadIdx.x;
    if (i >= DB * 33 * 128) return;
    int d = i & 127, l = (i >> 7) % 33, b = i / (33 * 128);
    ucat[i] = (l < 32) ? ctx[((size_t)b * 32 + l) * 128 + d] : his[(size_t)b * 128 + d];
}

// ---------------------------------------------------------------- MHA: one block per (b,h)
__global__ __launch_bounds__(256) void k_mha(const float* __restrict__ qb,
                                             const float* __restrict__ kb,
                                             const float* __restrict__ vb,
                                             float* __restrict__ ob)
{
    int b = blockIdx.x >> 3, h = blockIdx.x & 7;
    __shared__ float Ks[128][16], Vs[128][16], Qs[32][16];
    int tid = threadIdx.x;
    for (int i = tid; i < 128 * 16; i += 256) {
        int j = i >> 4, d = i & 15;
        Ks[j][d] = kb[((size_t)b * 128 + j) * 128 + h * 16 + d];
        Vs[j][d] = vb[((size_t)b * 128 + j) * 128 + h * 16 + d];
    }
    for (int i = tid; i < 32 * 16; i += 256) {
        int q = i >> 4, d = i & 15;
        Qs[q][d] = qb[((size_t)b * 32 + q) * 128 + h * 16 + d] * 0.25f;
    }
    __syncthreads();
    int q = tid >> 3;
    int jg = tid & 7;
    float lg[16];
    float m = -1e30f;
    #pragma unroll
    for (int jj = 0; jj < 16; ++jj) {
        int j = jg * 16 + jj;
        float s = 0.f;
        #pragma unroll
        for (int d = 0; d < 16; ++d) s += Qs[q][d] * Ks[j][d];
        lg[jj] = s;
        m = fmaxf(m, s);
    }
    #pragma unroll
    for (int o = 1; o < 8; o <<= 1) m = fmaxf(m, __shfl_xor(m, o));
    float sum = 0.f;
    float acc[16] = {};
    #pragma unroll
    for (int jj = 0; jj < 16; ++jj) {
        float p = __expf(lg[jj] - m);
        sum += p;
        int j = jg * 16 + jj;
        #pragma unroll
        for (int d = 0; d < 16; ++d) acc[d] += p * Vs[j][d];
    }
    #pragma unroll
    for (int o = 1; o < 8; o <<= 1) {
        sum += __shfl_xor(sum, o);
        #pragma unroll
        for (int d = 0; d < 16; ++d) acc[d] += __shfl_xor(acc[d], o);
    }
    if (jg == 0) {
        float inv = 1.0f / sum;
        #pragma unroll
        for (int d = 0; d < 16; ++d)
            ob[((size_t)b * 32 + q) * 128 + h * 16 + d] = acc[d] * inv;
    }
}

// ---------------------------------------------------------------- tanh-attention pooling
template <int L>
__global__ __launch_bounds__(128) void k_selfattn(const float* __restrict__ h,
                                                  const float* __restrict__ a,
                                                  const float* __restrict__ bvec,
                                                  float* __restrict__ out)
{
    __shared__ float As[64 * 128];
    __shared__ float Hs[33 * 128];
    __shared__ float Ts[33];
    __shared__ float Ws[33];
    int b = blockIdx.x, tid = threadIdx.x;
    const float* hb = h + (size_t)b * L * 128;
    for (int i = tid; i < L * 32; i += 128) ((float4*)Hs)[i] = ((const float4*)hb)[i];
    float sacc[L];
    #pragma unroll
    for (int l = 0; l < L; ++l) sacc[l] = 0.f;
    for (int kc = 0; kc < 2; ++kc) {
        __syncthreads();
        for (int i = tid; i < 64 * 32; i += 128)
            ((float4*)As)[i] = ((const float4*)(a + kc * 64 * 128))[i];
        __syncthreads();
        #pragma unroll
        for (int l = 0; l < L; ++l) {
            float s = 0.f;
            for (int k = 0; k < 64; ++k) s += Hs[l * 128 + kc * 64 + k] * As[k * 128 + tid];
            sacc[l] += s;
        }
    }
    float bv = bvec[tid];
    __syncthreads();
    #pragma unroll
    for (int l = 0; l < L; ++l) As[l * 128 + tid] = tanhf(sacc[l]) * bv;
    __syncthreads();
    if (tid < L) {
        float e = 0.f;
        for (int d = 0; d < 128; ++d) e += As[tid * 128 + d];
        Ts[tid] = e;
    }
    __syncthreads();
    if (tid == 0) {
        float m = -1e30f;
        for (int l = 0; l < L; ++l) m = fmaxf(m, Ts[l]);
        float s = 0.f;
        for (int l = 0; l < L; ++l) { float w = __expf(Ts[l] - m); Ws[l] = w; s += w; }
        float inv = 1.0f / s;
        for (int l = 0; l < L; ++l) Ws[l] *= inv;
    }
    __syncthreads();
    float o = 0.f;
    #pragma unroll
    for (int l = 0; l < L; ++l) o += Ws[l] * Hs[l * 128 + tid];
    out[(size_t)b * 128 + tid] = o;
}

// ---------------------------------------------------------------- scoring
__global__ __launch_bounds__(256) void k_score(const float* __restrict__ user,
                                               const float* __restrict__ kg,
                                               const float* __restrict__ rb,
                                               float* __restrict__ out, int Ntot)
{
    __shared__ float Us[64 * 128];
    for (int i = threadIdx.x; i < 64 * 32; i += 256)
        ((float4*)Us)[i] = ((const float4*)user)[i];
    __syncthreads();
    int n = blockIdx.x * blockDim.x + threadIdx.x;
    if (n >= Ntot) return;
    float acc[64] = {};
    const float* kr = kg + (size_t)n * 128;
    for (int d = 0; d < 128; d += 4) {
        float4 kv = *(const float4*)(kr + d);
        #pragma unroll
        for (int b = 0; b < 64; ++b) {
            acc[b] += kv.x * Us[b * 128 + d] + kv.y * Us[b * 128 + d + 1]
                    + kv.z * Us[b * 128 + d + 2] + kv.w * Us[b * 128 + d + 3];
        }
    }
    float rbn = rb[n];
    #pragma unroll
    for (int b = 0; b < 64; ++b) out[(size_t)b * Ntot + n] = acc[b] + rbn;
}

// ---------------------------------------------------------------- launch
extern "C" void kernel_launch(void* const* d_in, const int* in_sizes, int n_in,
                              void* d_out, int out_size, void* d_ws, size_t ws_size,
                              hipStream_t stream)
{
    const float* emb        = (const float*)d_in[0];
    const float* bases      = (const float*)d_in[1];
    const float* comp       = (const float*)d_in[2];
    const float* root       = (const float*)d_in[3];
    const float* rgcn_bias  = (const float*)d_in[4];
    const float* sess_theta = (const float*)d_in[5];
    const float* sess_bias  = (const float*)d_in[6];
    const float* know_theta = (const float*)d_in[7];
    const float* know_bias  = (const float*)d_in[8];
    const float* in_proj_w  = (const float*)d_in[9];
    const float* in_proj_b  = (const float*)d_in[10];
    const float* out_proj_w = (const float*)d_in[11];
    const float* out_proj_b = (const float*)d_in[12];
    const float* attn_his_a = (const float*)d_in[13];
    const float* attn_his_b = (const float*)d_in[14];
    const float* attn_a     = (const float*)d_in[15];
    const float* attn_b     = (const float*)d_in[16];
    const float* rec_bias   = (const float*)d_in[17];
    const int* edge_src     = (const int*)d_in[18];
    const int* edge_dst     = (const int*)d_in[19];
    const int* edge_type    = (const int*)d_in[20];
    const int* sess_nodes   = (const int*)d_in[21];
    const int* sess_edges   = (const int*)d_in[22];
    const int* know_nodes   = (const int*)d_in[23];
    const int* know_edges   = (const int*)d_in[24];
    const int* sess_rel_idx = (const int*)d_in[25];
    const int* know_rel_idx = (const int*)d_in[26];
    const int* context_idx  = (const int*)d_in[27];
    float* out = (float*)d_out;

    float* wsf = (float*)d_ws;
    size_t off = 0;
    auto alloc = [&](size_t n) { size_t r = off; off += (n + 255) & ~(size_t)255; return r; };
    float* kg      = wsf + alloc(12800000);          // N*D
    float* tmp     = wsf + alloc(12800000);          // xt (hyper phase); RGCN sort bufs (rgcn phase)
    float* w_all   = wsf + alloc(196608);
    int*   bsum    = (int*)(wsf + alloc(2048));
    int*   stybase = (int*)(wsf + alloc(16));        // [0..11] type seg base, [12] = total S
    int*   hhist   = (int*)(wsf + alloc(20000));
    int*   hoff    = (int*)(wsf + alloc(20000));
    int*   hcur    = (int*)(wsf + alloc(20000));
    int*   pns     = (int*)(wsf + alloc(400000));
    int*   mcnt    = (int*)(wsf + alloc(16));
    int*   mhe     = (int*)(wsf + alloc(MCAP));
    int*   msl     = (int*)(wsf + alloc(MCAP));
    int*   slot_s  = (int*)(wsf + alloc(100000));
    int*   slot_k  = (int*)(wsf + alloc(100000));
    int*   scnt    = (int*)(wsf + alloc(16));
    float* efeat   = wsf + alloc(2560000);
    float* sdeg    = wsf + alloc(4096);
    float* sacc    = wsf + alloc(524288);
    float* related = wsf + alloc(1048576);
    float* ctx     = wsf + alloc(262144);
    float* qb      = wsf + alloc(262144);
    float* kb      = wsf + alloc(1048576);
    float* vb      = wsf + alloc(1048576);
    float* obuf    = wsf + alloc(262144);
    float* attrel  = wsf + alloc(262144);
    float* his     = wsf + alloc(8192);
    float* ucat    = wsf + alloc(270336);
    float* userb   = wsf + alloc(8192);
    (void)ws_size; (void)in_sizes; (void)n_in; (void)out_size;

    // RGCN sort buffers live inside tmp (xt written only after RGCN completes)
    int* hist    = (int*)tmp;                 // 1.2M
    int* soff    = (int*)tmp + 1200000;       // 1.2M
    int* segpos  = (int*)tmp + 2400000;       // 1.2M (reused as bucket cursor)
    int* seglist = (int*)tmp + 3600000;       // 1.2M
    int* ssrc    = (int*)tmp + 4800000;       // 1.0M

    const int nbR = (NRBINS + SCAN_CHUNK - 1) / SCAN_CHUNK;   // 1172
    const int nbH = (DHE + SCAN_CHUNK - 1) / SCAN_CHUNK;      // 20

    // ---------------- RGCN: sort edges by (type, dst)
    hipMemsetAsync(hist, 0, NRBINS * 4, stream);
    hipMemsetAsync(slot_s, 0xFF, 100000 * 4, stream);
    hipMemsetAsync(slot_k, 0xFF, 100000 * 4, stream);
    hipMemsetAsync(scnt, 0, 16 * 4, stream);
    k_hist_rgcn<<<(DE + 255) / 256, 256, 0, stream>>>(edge_dst, edge_type, hist, DE);
    k_scan_pass1<<<nbR, 256, 0, stream>>>(hist, NRBINS, bsum, 0);
    k_scan_pass2p<<<1, 256, 0, stream>>>(bsum, nbR, nullptr);
    k_scan_pass3<<<nbR, 256, 0, stream>>>(hist, NRBINS, bsum, soff, 0);
    k_scan_pass1<<<nbR, 256, 0, stream>>>(hist, NRBINS, bsum, 1);
    k_scan_pass2p<<<1, 256, 0, stream>>>(bsum, nbR, stybase + DR);
    k_scan_pass3<<<nbR, 256, 0, stream>>>(hist, NRBINS, bsum, segpos, 1);
    k_stypebase<<<1, 64, 0, stream>>>(segpos, stybase);
    k_seglist<<<(NRBINS + 255) / 256, 256, 0, stream>>>(hist, segpos, seglist, NRBINS);
    hipMemsetAsync(segpos, 0, NRBINS * 4, stream);
    k_bucket_rgcn<<<(DE + 255) / 256, 256, 0, stream>>>(edge_src, edge_dst, edge_type,
                                                        soff, segpos, ssrc, DE);
    k_wcomp<<<(DR * DD * DD + 255) / 256, 256, 0, stream>>>(comp, bases, w_all);

    int gemmN = (DN + 63) / 64;
    k_mfma_gemm<<<gemmN, 256, 0, stream>>>(emb, root, rgcn_bias, kg, DN, 0);
    for (int r = 0; r < DR; ++r)
        k_mfma_rgcn<<<gemmN, 256, 0, stream>>>(emb, w_all + (size_t)r * DD * DD,
                                               seglist, soff, hist, ssrc, stybase, kg, r);

    // ---------------- sess hypergraph
    k_slot_assign<<<16, 256, 0, stream>>>(sess_rel_idx, slot_s, scnt, DB * DLR);
    k_mfma_gemm<<<gemmN, 256, 0, stream>>>(kg, sess_theta, nullptr, tmp, DN, 0);
    hipMemsetAsync(hhist, 0, DHE * 4, stream);
    hipMemsetAsync(hcur, 0, DHE * 4, stream);
    hipMemsetAsync(sdeg, 0, 4096 * 4, stream);
    hipMemsetAsync(sacc, 0, 524288 * 4, stream);
    hipMemsetAsync(mcnt, 0, 16 * 4, stream);
    k_hist_p<<<(DP + 255) / 256, 256, 0, stream>>>(sess_edges, hhist, DP);
    k_scan_pass1<<<nbH, 256, 0, stream>>>(hhist, DHE, bsum, 0);
    k_scan_pass2p<<<1, 256, 0, stream>>>(bsum, nbH, nullptr);
    k_scan_pass3<<<nbH, 256, 0, stream>>>(hhist, DHE, bsum, hoff, 0);
    k_bucket_p<<<(DP + 255) / 256, 256, 0, stream>>>(sess_nodes, sess_edges, hoff, hcur, pns, DP);
    k_hyper_agg<<<(DHE * 64 + 255) / 256, 256, 0, stream>>>(tmp, pns, hoff, hhist, efeat);
    k_sdeg<<<(DP + 255) / 256, 256, 0, stream>>>(sess_nodes, slot_s, sdeg, DP);
    k_match<<<(DP + 255) / 256, 256, 0, stream>>>(sess_nodes, sess_edges, slot_s, mcnt, mhe, msl, DP);
    k_accmatch<<<256, 256, 0, stream>>>(efeat, mhe, msl, mcnt, sacc);
    k_hyper_gather<<<(DB * DLR * 64 + 255) / 256, 256, 0, stream>>>(
        sacc, sdeg, slot_s, sess_rel_idx, sess_bias, related, DB * DLR, 0);

    // ---------------- know hypergraph
    k_slot_assign<<<16, 256, 0, stream>>>(know_rel_idx, slot_k, scnt + 1, DB * DLR);
    k_mfma_gemm<<<gemmN, 256, 0, stream>>>(kg, know_theta, nullptr, tmp, DN, 0);
    hipMemsetAsync(hhist, 0, DHE * 4, stream);
    hipMemsetAsync(hcur, 0, DHE * 4, stream);
    hipMemsetAsync(sdeg, 0, 4096 * 4, stream);
    hipMemsetAsync(sacc, 0, 524288 * 4, stream);
    hipMemsetAsync(mcnt, 0, 16 * 4, stream);
    k_hist_p<<<(DP + 255) / 256, 256, 0, stream>>>(know_edges, hhist, DP);
    k_scan_pass1<<<nbH, 256, 0, stream>>>(hhist, DHE, bsum, 0);
    k_scan_pass2p<<<1, 256, 0, stream>>>(bsum, nbH, nullptr);
    k_scan_pass3<<<nbH, 256, 0, stream>>>(hhist, DHE, bsum, hoff, 0);
    k_bucket_p<<<(DP + 255) / 256, 256, 0, stream>>>(know_nodes, know_edges, hoff, hcur, pns, DP);
    k_hyper_agg<<<(DHE * 64 + 255) / 256, 256, 0, stream>>>(tmp, pns, hoff, hhist, efeat);
    k_sdeg<<<(DP + 255) / 256, 256, 0, stream>>>(know_nodes, slot_k, sdeg, DP);
    k_match<<<(DP + 255) / 256, 256, 0, stream>>>(know_nodes, know_edges, slot_k, mcnt, mhe, msl, DP);
    k_accmatch<<<256, 256, 0, stream>>>(efeat, mhe, msl, mcnt, sacc);
    k_hyper_gather<<<(DB * DLR * 64 + 255) / 256, 256, 0, stream>>>(
        sacc, sdeg, slot_k, know_rel_idx, know_bias, related, DB * DLR, 64);

    // ---------------- context + MHA
    k_gather_rows<<<(DB * DLC * 128 + 255) / 256, 256, 0, stream>>>(kg, context_idx, ctx, DB * DLC);
    k_gemm128<<<(DB * DLC + 63) / 64, 256, 0, stream>>>(ctx, in_proj_w, in_proj_b, qb, DB * DLC, 1);
    k_gemm128<<<(DB * 128 + 63) / 64, 256, 0, stream>>>(related, in_proj_w + DD * DD,
                                                        in_proj_b + DD, kb, DB * 128, 1);
    k_gemm128<<<(DB * 128 + 63) / 64, 256, 0, stream>>>(related, in_proj_w + 2 * DD * DD,
                                                        in_proj_b + 2 * DD, vb, DB * 128, 1);
    k_mha<<<DB * DNH, 256, 0, stream>>>(qb, kb, vb, obuf);
    k_gemm128<<<(DB * DLC + 63) / 64, 256, 0, stream>>>(obuf, out_proj_w, out_proj_b, attrel, DB * DLC, 1);

    // ---------------- pooling + score
    k_selfattn<32><<<DB, 128, 0, stream>>>(attrel, attn_his_a, attn_his_b, his);
    k_build_ucat<<<(DB * 33 * 128 + 255) / 256, 256, 0, stream>>>(ctx, his, ucat);
    k_selfattn<33><<<DB, 128, 0, stream>>>(ucat, attn_a, attn_b, userb);
    k_score<<<(DN + 255) / 256, 256, 0, stream>>>(userb, kg, rec_bias, out, DN);
}

// Round 4
// 1327.050 us; speedup vs baseline: 2.2888x; 1.1109x over previous
//
#include <hip/hip_runtime.h>
#include <hip/hip_bf16.h>

#define DN 100000     // N entities
#define DD 128        // D
#define DR 12         // R relations
#define DNB 8         // bases
#define DE 1000000    // edges
#define DP 400000     // hyperedge incidences
#define DHE 20000     // hyperedges
#define DB 64         // batch
#define DLR 64
#define DLC 32
#define DNH 8
#define DHD 16
#define NRBINS (DR * DN)   // 1.2M
#define SCAN_CHUNK 1024
#define MCAP 65536

typedef unsigned short ushortT;
typedef unsigned int uintT;
typedef __attribute__((ext_vector_type(8))) short s8v;
typedef __attribute__((ext_vector_type(4))) float f4v;

#define APAD 136   // 64 rows of K=128 bf16, stride 272B
#define BPAD 40    // 128 rows of K=32 bf16, stride 80B

__device__ __forceinline__ ushortT rneb(float v) {
    uintT b = __float_as_uint(v);
    return (ushortT)((b + 0x7FFFu + ((b >> 16) & 1u)) >> 16);
}
__device__ __forceinline__ float b2f(ushortT h) {
    return __uint_as_float(((uintT)h) << 16);
}

__device__ __forceinline__ void split_store8(ushortT* hbase, ushortT* lbase, const float* v)
{
    ushortT h[8], l[8];
    #pragma unroll
    for (int j = 0; j < 8; ++j) {
        h[j] = rneb(v[j]);
        l[j] = rneb(v[j] - b2f(h[j]));
    }
    uint4 hv = make_uint4((uintT)h[0] | ((uintT)h[1] << 16), (uintT)h[2] | ((uintT)h[3] << 16),
                          (uintT)h[4] | ((uintT)h[5] << 16), (uintT)h[6] | ((uintT)h[7] << 16));
    uint4 lv = make_uint4((uintT)l[0] | ((uintT)l[1] << 16), (uintT)l[2] | ((uintT)l[3] << 16),
                          (uintT)l[4] | ((uintT)l[5] << 16), (uintT)l[6] | ((uintT)l[7] << 16));
    *(uint4*)hbase = hv;
    *(uint4*)lbase = lv;
}

// ---------------------------------------------------------------- MFMA GEMM (split-bf16, ~fp32 accuracy)
// C[m,n] = sum_k A[m,k]*W(k,n) + bias[n]; W(k,n) = trans ? W[n*128+k] : W[k*128+n]
// rs: optional per-row scale on A (nullptr = 1)
__global__ __launch_bounds__(256) void k_mfma_gemm(
    const float* __restrict__ A, const float* __restrict__ W,
    const float* __restrict__ bias, const float* __restrict__ rs,
    float* __restrict__ C, int M, int trans)
{
    __shared__ __align__(16) ushortT Ah[64 * APAD], Al[64 * APAD];
    __shared__ __align__(16) ushortT Bh[128 * BPAD], Bl[128 * BPAD];
    int tid = threadIdx.x;
    int row0 = blockIdx.x * 64;
    {
        int row = tid >> 2, c0 = (tid & 3) * 32;
        int gr = row0 + row;
        const float* ar = A + (size_t)gr * 128 + c0;
        float sc = 1.0f;
        if (rs && gr < M) { float d = rs[gr]; sc = (d > 0.f) ? 1.0f / d : 0.f; }
        #pragma unroll
        for (int g = 0; g < 4; ++g) {
            float v[8] = {};
            if (gr < M) {
                float4 u0 = *(const float4*)(ar + g * 8);
                float4 u1 = *(const float4*)(ar + g * 8 + 4);
                v[0]=u0.x*sc; v[1]=u0.y*sc; v[2]=u0.z*sc; v[3]=u0.w*sc;
                v[4]=u1.x*sc; v[5]=u1.y*sc; v[6]=u1.z*sc; v[7]=u1.w*sc;
            }
            split_store8(&Ah[row * APAD + c0 + g * 8], &Al[row * APAD + c0 + g * 8], v);
        }
    }
    f4v acc[8] = {};
    int w = tid >> 6, lane = tid & 63, m = lane & 15, quad = lane >> 4;
    for (int kc = 0; kc < 4; ++kc) {
        __syncthreads();
        #pragma unroll
        for (int t2 = 0; t2 < 2; ++t2) {
            int task = tid + t2 * 256;
            int n = task & 127, kg = task >> 7;
            float v[8];
            if (!trans) {
                #pragma unroll
                for (int j = 0; j < 8; ++j)
                    v[j] = W[(size_t)(kc * 32 + kg * 8 + j) * 128 + n];
            } else {
                const float* wr = W + (size_t)n * 128 + kc * 32 + kg * 8;
                float4 u0 = *(const float4*)wr, u1 = *(const float4*)(wr + 4);
                v[0]=u0.x; v[1]=u0.y; v[2]=u0.z; v[3]=u0.w;
                v[4]=u1.x; v[5]=u1.y; v[6]=u1.z; v[7]=u1.w;
            }
            split_store8(&Bh[n * BPAD + kg * 8], &Bl[n * BPAD + kg * 8], v);
        }
        __syncthreads();
        s8v ah = *(const s8v*)&Ah[(w * 16 + m) * APAD + kc * 32 + quad * 8];
        s8v al = *(const s8v*)&Al[(w * 16 + m) * APAD + kc * 32 + quad * 8];
        #pragma unroll
        for (int nt = 0; nt < 8; ++nt) {
            s8v bh = *(const s8v*)&Bh[(nt * 16 + m) * BPAD + quad * 8];
            s8v bl = *(const s8v*)&Bl[(nt * 16 + m) * BPAD + quad * 8];
            acc[nt] = __builtin_amdgcn_mfma_f32_16x16x32_bf16(ah, bh, acc[nt], 0, 0, 0);
            acc[nt] = __builtin_amdgcn_mfma_f32_16x16x32_bf16(al, bh, acc[nt], 0, 0, 0);
            acc[nt] = __builtin_amdgcn_mfma_f32_16x16x32_bf16(ah, bl, acc[nt], 0, 0, 0);
        }
    }
    float bv[8];
    #pragma unroll
    for (int nt = 0; nt < 8; ++nt) bv[nt] = bias ? bias[nt * 16 + m] : 0.f;
    #pragma unroll
    for (int rr = 0; rr < 4; ++rr) {
        int gr = row0 + w * 16 + quad * 4 + rr;
        if (gr < M) {
            #pragma unroll
            for (int nt = 0; nt < 8; ++nt)
                C[(size_t)gr * 128 + nt * 16 + m] = acc[nt][rr] + bv[nt];
        }
    }
}

// ---------------------------------------------------------------- RGCN fused segment-mean @ w[r] -> kg += (MFMA)
__global__ __launch_bounds__(256) void k_mfma_rgcn(
    const float* __restrict__ x, const float* __restrict__ wmat,
    const int* __restrict__ seglist, const int* __restrict__ soff,
    const int* __restrict__ slen, const int* __restrict__ ssrc,
    const int* __restrict__ stypebase, float* __restrict__ kg, int r)
{
    __shared__ __align__(16) ushortT Ah[64 * APAD], Al[64 * APAD];
    __shared__ __align__(16) ushortT Bh[128 * BPAD], Bl[128 * BPAD];
    int s0 = stypebase[r], s1 = stypebase[r + 1];
    int base = s0 + blockIdx.x * 64;
    if (base >= s1) return;
    int nrow = min(64, s1 - base);
    int tid = threadIdx.x;
    {
        int row = tid >> 2, c0 = (tid & 3) * 32;
        float a[32] = {};
        if (row < nrow) {
            int key = seglist[base + row];
            int st = soff[key], len = slen[key];
            for (int i = 0; i < len; ++i) {
                const float* xr = x + (size_t)ssrc[st + i] * 128 + c0;
                #pragma unroll
                for (int j = 0; j < 8; ++j) {
                    float4 v = *(const float4*)(xr + j * 4);
                    a[j*4+0] += v.x; a[j*4+1] += v.y; a[j*4+2] += v.z; a[j*4+3] += v.w;
                }
            }
            float inv = 1.0f / (float)max(len, 1);
            #pragma unroll
            for (int j = 0; j < 32; ++j) a[j] *= inv;
        }
        #pragma unroll
        for (int g = 0; g < 4; ++g)
            split_store8(&Ah[row * APAD + c0 + g * 8], &Al[row * APAD + c0 + g * 8], a + g * 8);
    }
    f4v acc[8] = {};
    int w = tid >> 6, lane = tid & 63, m = lane & 15, quad = lane >> 4;
    for (int kc = 0; kc < 4; ++kc) {
        __syncthreads();
        #pragma unroll
        for (int t2 = 0; t2 < 2; ++t2) {
            int task = tid + t2 * 256;
            int n = task & 127, kg2 = task >> 7;
            float v[8];
            #pragma unroll
            for (int j = 0; j < 8; ++j)
                v[j] = wmat[(size_t)(kc * 32 + kg2 * 8 + j) * 128 + n];
            split_store8(&Bh[n * BPAD + kg2 * 8], &Bl[n * BPAD + kg2 * 8], v);
        }
        __syncthreads();
        s8v ah = *(const s8v*)&Ah[(w * 16 + m) * APAD + kc * 32 + quad * 8];
        s8v al = *(const s8v*)&Al[(w * 16 + m) * APAD + kc * 32 + quad * 8];
        #pragma unroll
        for (int nt = 0; nt < 8; ++nt) {
            s8v bh = *(const s8v*)&Bh[(nt * 16 + m) * BPAD + quad * 8];
            s8v bl = *(const s8v*)&Bl[(nt * 16 + m) * BPAD + quad * 8];
            acc[nt] = __builtin_amdgcn_mfma_f32_16x16x32_bf16(ah, bh, acc[nt], 0, 0, 0);
            acc[nt] = __builtin_amdgcn_mfma_f32_16x16x32_bf16(al, bh, acc[nt], 0, 0, 0);
            acc[nt] = __builtin_amdgcn_mfma_f32_16x16x32_bf16(ah, bl, acc[nt], 0, 0, 0);
        }
    }
    #pragma unroll
    for (int rr = 0; rr < 4; ++rr) {
        int rt = w * 16 + quad * 4 + rr;
        if (rt < nrow) {
            int dst = seglist[base + rt] - r * DN;
            float* kr = kg + (size_t)dst * 128 + m;
            #pragma unroll
            for (int nt = 0; nt < 8; ++nt)
                kr[nt * 16] += acc[nt][rr];
        }
    }
}

// ---------------------------------------------------------------- scoring: out[b,n] = user[b]·kg[n] + rb[n]  (MFMA)
__global__ __launch_bounds__(256) void k_score_mfma(
    const float* __restrict__ kg, const float* __restrict__ user,
    const float* __restrict__ rb, float* __restrict__ out)
{
    __shared__ __align__(16) ushortT Ah[64 * APAD], Al[64 * APAD];   // kg rows (n-dim)
    __shared__ __align__(16) ushortT Bh[64 * APAD], Bl[64 * APAD];   // user rows (b-dim)
    int tid = threadIdx.x;
    int n0 = blockIdx.x * 64;
    {
        int row = tid >> 2, c0 = (tid & 3) * 32;
        int gr = n0 + row;
        const float* ar = kg + (size_t)gr * 128 + c0;
        const float* ur = user + (size_t)row * 128 + c0;
        #pragma unroll
        for (int g = 0; g < 4; ++g) {
            float v[8] = {};
            if (gr < DN) {
                float4 u0 = *(const float4*)(ar + g * 8);
                float4 u1 = *(const float4*)(ar + g * 8 + 4);
                v[0]=u0.x; v[1]=u0.y; v[2]=u0.z; v[3]=u0.w;
                v[4]=u1.x; v[5]=u1.y; v[6]=u1.z; v[7]=u1.w;
            }
            split_store8(&Ah[row * APAD + c0 + g * 8], &Al[row * APAD + c0 + g * 8], v);
            float u[8];
            float4 w0 = *(const float4*)(ur + g * 8);
            float4 w1 = *(const float4*)(ur + g * 8 + 4);
            u[0]=w0.x; u[1]=w0.y; u[2]=w0.z; u[3]=w0.w;
            u[4]=w1.x; u[5]=w1.y; u[6]=w1.z; u[7]=w1.w;
            split_store8(&Bh[row * APAD + c0 + g * 8], &Bl[row * APAD + c0 + g * 8], u);
        }
    }
    __syncthreads();
    f4v acc[4] = {};
    int w = tid >> 6, lane = tid & 63, m = lane & 15, quad = lane >> 4;
    #pragma unroll
    for (int kc = 0; kc < 4; ++kc) {
        s8v ah = *(const s8v*)&Ah[(w * 16 + m) * APAD + kc * 32 + quad * 8];
        s8v al = *(const s8v*)&Al[(w * 16 + m) * APAD + kc * 32 + quad * 8];
        #pragma unroll
        for (int nt = 0; nt < 4; ++nt) {
            s8v bh = *(const s8v*)&Bh[(nt * 16 + m) * APAD + kc * 32 + quad * 8];
            s8v bl = *(const s8v*)&Bl[(nt * 16 + m) * APAD + kc * 32 + quad * 8];
            acc[nt] = __builtin_amdgcn_mfma_f32_16x16x32_bf16(ah, bh, acc[nt], 0, 0, 0);
            acc[nt] = __builtin_amdgcn_mfma_f32_16x16x32_bf16(al, bh, acc[nt], 0, 0, 0);
            acc[nt] = __builtin_amdgcn_mfma_f32_16x16x32_bf16(ah, bl, acc[nt], 0, 0, 0);
        }
    }
    int n = n0 + w * 16 + quad * 4;   // multiple of 4; DN % 4 == 0
    if (n < DN) {
        float4 rbv = *(const float4*)&rb[n];
        #pragma unroll
        for (int nt = 0; nt < 4; ++nt) {
            int b = nt * 16 + m;
            float4 o = make_float4(acc[nt][0] + rbv.x, acc[nt][1] + rbv.y,
                                   acc[nt][2] + rbv.z, acc[nt][3] + rbv.w);
            *(float4*)&out[(size_t)b * DN + n] = o;
        }
    }
}

// ---------------------------------------------------------------- scans
__global__ void k_scan_pass1(const int* __restrict__ in, int n, int* __restrict__ bsum, int mode)
{
    __shared__ int red[256];
    int b = blockIdx.x, t = threadIdx.x;
    int i0 = b * SCAN_CHUNK + t * 4;
    int s = 0;
    #pragma unroll
    for (int j = 0; j < 4; ++j) {
        int i = i0 + j;
        if (i < n) { int v = in[i]; s += mode ? (v > 0) : v; }
    }
    red[t] = s;
    __syncthreads();
    for (int o = 128; o > 0; o >>= 1) {
        if (t < o) red[t] += red[t + o];
        __syncthreads();
    }
    if (t == 0) bsum[b] = red[0];
}

__global__ __launch_bounds__(256) void k_scan_pass2p(int* bsum, int nb, int* total)
{
    __shared__ int lds[256];
    __shared__ int carry;
    int t = threadIdx.x;
    if (t == 0) carry = 0;
    __syncthreads();
    for (int c0 = 0; c0 < nb; c0 += 256) {
        int i = c0 + t;
        int v = (i < nb) ? bsum[i] : 0;
        lds[t] = v;
        __syncthreads();
        for (int o = 1; o < 256; o <<= 1) {
            int add = (t >= o) ? lds[t - o] : 0;
            __syncthreads();
            lds[t] += add;
            __syncthreads();
        }
        int myc = carry;
        if (i < nb) bsum[i] = lds[t] - v + myc;
        int tot = lds[255];
        __syncthreads();
        if (t == 0) carry = myc + tot;
        __syncthreads();
    }
    if (total && t == 0) *total = carry;
}

__global__ void k_scan_pass3(const int* __restrict__ in, int n, const int* __restrict__ bsum,
                             int* __restrict__ out, int mode)
{
    __shared__ int lds[256];
    int b = blockIdx.x, t = threadIdx.x;
    int i0 = b * SCAN_CHUNK + t * 4;
    int v[4]; int s = 0;
    #pragma unroll
    for (int j = 0; j < 4; ++j) {
        int i = i0 + j;
        int x = 0;
        if (i < n) { int raw = in[i]; x = mode ? (raw > 0) : raw; }
        v[j] = x; s += x;
    }
    lds[t] = s;
    __syncthreads();
    for (int o = 1; o < 256; o <<= 1) {
        int add = (t >= o) ? lds[t - o] : 0;
        __syncthreads();
        lds[t] += add;
        __syncthreads();
    }
    int run = lds[t] - s + bsum[b];
    #pragma unroll
    for (int j = 0; j < 4; ++j) {
        int i = i0 + j;
        if (i < n) { out[i] = run; run += v[j]; }
    }
}

// ---------------------------------------------------------------- RGCN sort
__global__ void k_hist_rgcn(const int* __restrict__ dst, const int* __restrict__ et,
                            int* hist, int E)
{
    int i = blockIdx.x * blockDim.x + threadIdx.x;
    if (i < E) atomicAdd(&hist[(size_t)et[i] * DN + dst[i]], 1);
}

__global__ void k_seglist(const int* __restrict__ hist, const int* __restrict__ segpos,
                          int* __restrict__ seglist, int n)
{
    int i = blockIdx.x * blockDim.x + threadIdx.x;
    if (i < n && hist[i] > 0) seglist[segpos[i]] = i;
}

__global__ void k_stypebase(const int* __restrict__ segpos, int* stypebase)
{
    int t = threadIdx.x;
    if (t < DR) stypebase[t] = segpos[(size_t)t * DN];
}

__global__ void k_bucket_rgcn(const int* __restrict__ src, const int* __restrict__ dst,
                              const int* __restrict__ et, const int* __restrict__ off,
                              int* cur, int* ssrc, int E)
{
    int i = blockIdx.x * blockDim.x + threadIdx.x;
    if (i >= E) return;
    int key = et[i] * DN + dst[i];
    int pos = off[key] + atomicAdd(&cur[key], 1);
    ssrc[pos] = src[i];
}

__global__ void k_wcomp(const float* __restrict__ comp, const float* __restrict__ bases,
                        float* __restrict__ w_all)
{
    int i = blockIdx.x * blockDim.x + threadIdx.x;
    if (i >= DR * DD * DD) return;
    int r = i / (DD * DD), io = i % (DD * DD);
    float s = 0.f;
    #pragma unroll
    for (int b = 0; b < DNB; ++b) s += comp[r * DNB + b] * bases[(size_t)b * DD * DD + io];
    w_all[i] = s;
}

// ---------------------------------------------------------------- hypergraph
__global__ void k_hist_p(const int* __restrict__ he, int* hist, int P)
{
    int i = blockIdx.x * blockDim.x + threadIdx.x;
    if (i < P) atomicAdd(&hist[he[i]], 1);
}

__global__ void k_bucket_p(const int* __restrict__ nodes, const int* __restrict__ he,
                           const int* __restrict__ off, int* cur, int* pns, int P)
{
    int i = blockIdx.x * blockDim.x + threadIdx.x;
    if (i >= P) return;
    int e = he[i];
    int pos = off[e] + atomicAdd(&cur[e], 1);
    pns[pos] = nodes[i];
}

// one wave per hyperedge: efeat[he] = mean of kg[node] over its incidences (theta pushed to end)
__global__ void k_hyper_agg(const float* __restrict__ xsrc, const int* __restrict__ pns,
                            const int* __restrict__ hoff, const int* __restrict__ hcnt,
                            float* __restrict__ efeat)
{
    int lane = threadIdx.x & 63;
    int he = (blockIdx.x * blockDim.x + threadIdx.x) >> 6;
    if (he >= DHE) return;
    int st = hoff[he], len = hcnt[he];
    float2 acc = make_float2(0.f, 0.f);
    for (int c = 0; c < len; c += 64) {
        int m = min(64, len - c);
        int nid = (c + lane < len) ? pns[st + c + lane] : 0;
        for (int j = 0; j < m; ++j) {
            int node = __shfl(nid, j);
            float2 v = *(const float2*)&xsrc[(size_t)node * 128 + lane * 2];
            acc.x += v.x; acc.y += v.y;
        }
    }
    float inv = (len > 0) ? 1.0f / (float)len : 0.f;
    acc.x *= inv; acc.y *= inv;
    *(float2*)&efeat[(size_t)he * 128 + lane * 2] = acc;
}

__global__ void k_slot_assign(const int* __restrict__ idx, int* slot, int* counter, int n)
{
    int i = blockIdx.x * blockDim.x + threadIdx.x;
    if (i >= n) return;
    int node = idx[i];
    if (atomicCAS(&slot[node], -1, -2) == -1) {
        int s = atomicAdd(counter, 1);
        slot[node] = s;
    }
}

__global__ void k_sdeg(const int* __restrict__ nodes, const int* __restrict__ slot,
                       float* sdeg, int P)
{
    int i = blockIdx.x * blockDim.x + threadIdx.x;
    if (i < P) {
        int s = slot[nodes[i]];
        if (s >= 0) atomicAdd(&sdeg[s], 1.0f);
    }
}

__global__ void k_match(const int* __restrict__ nodes, const int* __restrict__ he,
                        const int* __restrict__ slot, int* mcnt, int* mhe, int* msl, int P)
{
    int i = blockIdx.x * blockDim.x + threadIdx.x;
    if (i >= P) return;
    int s = slot[nodes[i]];
    if (s >= 0) {
        int idx = atomicAdd(mcnt, 1);
        if (idx < MCAP) { mhe[idx] = he[i]; msl[idx] = s; }
    }
}

__global__ void k_accmatch(const float* __restrict__ efeat, const int* __restrict__ mhe,
                           const int* __restrict__ msl, const int* __restrict__ mcnt,
                           float* sacc)
{
    int lane = threadIdx.x & 63;
    int w = (blockIdx.x * blockDim.x + threadIdx.x) >> 6;
    int nw = (gridDim.x * blockDim.x) >> 6;
    int M = min(*mcnt, MCAP);
    for (int i = w; i < M; i += nw) {
        float2 v = *(const float2*)&efeat[(size_t)mhe[i] * 128 + lane * 2];
        atomicAdd(&sacc[(size_t)msl[i] * 128 + lane * 2],     v.x);
        atomicAdd(&sacc[(size_t)msl[i] * 128 + lane * 2 + 1], v.y);
    }
}

// related[b, colOff+l, :] = slotout[slot[rel_idx]]
__global__ void k_rel_gather(const float* __restrict__ slotout, const int* __restrict__ slot,
                             const int* __restrict__ rel_idx, float* __restrict__ related,
                             int colOff)
{
    int gid = blockIdx.x * blockDim.x + threadIdx.x;
    int i = gid >> 5, c = gid & 31;
    if (i >= DB * DLR) return;
    int s = slot[rel_idx[i]];
    int b = i / DLR, l = i % DLR;
    ((float4*)&related[((size_t)b * 128 + colOff + l) * 128])[c] =
        ((const float4*)&slotout[(size_t)s * 128])[c];
}

// ---------------------------------------------------------------- gathers / misc
__global__ void k_gather_rows(const float* __restrict__ src, const int* __restrict__ idx,
                              float* dst, int nRows)
{
    int i = blockIdx.x * blockDim.x + threadIdx.x;
    if (i >= nRows * 128) return;
    int row = i >> 7, d = i & 127;
    dst[i] = src[(size_t)idx[row] * 128 + d];
}

__global__ void k_build_ucat(const float* __restrict__ ctx, const float* __restrict__ his,
                             float* ucat)
{
    int i = blockIdx.x * blockDim.x + threadIdx.x;
    if (i >= DB * 33 * 128) return;
    int d = i & 127, l = (i >> 7) % 33, b = i / (33 * 128);
    ucat[i] = (l < 32) ? ctx[((size_t)b * 32 + l) * 128 + d] : his[(size_t)b * 128 + d];
}

// ---------------------------------------------------------------- MHA: one block per (b,h)
__global__ __launch_bounds__(256) void k_mha(const float* __restrict__ qb,
                                             const float* __restrict__ kb,
                                             const float* __restrict__ vb,
                                             float* __restrict__ ob)
{
    int b = blockIdx.x >> 3, h = blockIdx.x & 7;
    __shared__ float Ks[128][16], Vs[128][16], Qs[32][16];
    int tid = threadIdx.x;
    for (int i = tid; i < 128 * 16; i += 256) {
        int j = i >> 4, d = i & 15;
        Ks[j][d] = kb[((size_t)b * 128 + j) * 128 + h * 16 + d];
        Vs[j][d] = vb[((size_t)b * 128 + j) * 128 + h * 16 + d];
    }
    for (int i = tid; i < 32 * 16; i += 256) {
        int q = i >> 4, d = i & 15;
        Qs[q][d] = qb[((size_t)b * 32 + q) * 128 + h * 16 + d] * 0.25f;
    }
    __syncthreads();
    int q = tid >> 3;
    int jg = tid & 7;
    float lg[16];
    float m = -1e30f;
    #pragma unroll
    for (int jj = 0; jj < 16; ++jj) {
        int j = jg * 16 + jj;
        float s = 0.f;
        #pragma unroll
        for (int d = 0; d < 16; ++d) s += Qs[q][d] * Ks[j][d];
        lg[jj] = s;
        m = fmaxf(m, s);
    }
    #pragma unroll
    for (int o = 1; o < 8; o <<= 1) m = fmaxf(m, __shfl_xor(m, o));
    float sum = 0.f;
    float acc[16] = {};
    #pragma unroll
    for (int jj = 0; jj < 16; ++jj) {
        float p = __expf(lg[jj] - m);
        sum += p;
        int j = jg * 16 + jj;
        #pragma unroll
        for (int d = 0; d < 16; ++d) acc[d] += p * Vs[j][d];
    }
    #pragma unroll
    for (int o = 1; o < 8; o <<= 1) {
        sum += __shfl_xor(sum, o);
        #pragma unroll
        for (int d = 0; d < 16; ++d) acc[d] += __shfl_xor(acc[d], o);
    }
    if (jg == 0) {
        float inv = 1.0f / sum;
        #pragma unroll
        for (int d = 0; d < 16; ++d)
            ob[((size_t)b * 32 + q) * 128 + h * 16 + d] = acc[d] * inv;
    }
}

// ---------------------------------------------------------------- tanh-attention pooling
template <int L>
__global__ __launch_bounds__(128) void k_selfattn(const float* __restrict__ h,
                                                  const float* __restrict__ a,
                                                  const float* __restrict__ bvec,
                                                  float* __restrict__ out)
{
    __shared__ float As[64 * 128];
    __shared__ float Hs[33 * 128];
    __shared__ float Ts[33];
    __shared__ float Ws[33];
    int b = blockIdx.x, tid = threadIdx.x;
    const float* hb = h + (size_t)b * L * 128;
    for (int i = tid; i < L * 32; i += 128) ((float4*)Hs)[i] = ((const float4*)hb)[i];
    float sacc[L];
    #pragma unroll
    for (int l = 0; l < L; ++l) sacc[l] = 0.f;
    for (int kc = 0; kc < 2; ++kc) {
        __syncthreads();
        for (int i = tid; i < 64 * 32; i += 128)
            ((float4*)As)[i] = ((const float4*)(a + kc * 64 * 128))[i];
        __syncthreads();
        #pragma unroll
        for (int l = 0; l < L; ++l) {
            float s = 0.f;
            for (int k = 0; k < 64; ++k) s += Hs[l * 128 + kc * 64 + k] * As[k * 128 + tid];
            sacc[l] += s;
        }
    }
    float bv = bvec[tid];
    __syncthreads();
    #pragma unroll
    for (int l = 0; l < L; ++l) As[l * 128 + tid] = tanhf(sacc[l]) * bv;
    __syncthreads();
    if (tid < L) {
        float e = 0.f;
        for (int d = 0; d < 128; ++d) e += As[tid * 128 + d];
        Ts[tid] = e;
    }
    __syncthreads();
    if (tid == 0) {
        float m = -1e30f;
        for (int l = 0; l < L; ++l) m = fmaxf(m, Ts[l]);
        float s = 0.f;
        for (int l = 0; l < L; ++l) { float w = __expf(Ts[l] - m); Ws[l] = w; s += w; }
        float inv = 1.0f / s;
        for (int l = 0; l < L; ++l) Ws[l] *= inv;
    }
    __syncthreads();
    float o = 0.f;
    #pragma unroll
    for (int l = 0; l < L; ++l) o += Ws[l] * Hs[l * 128 + tid];
    out[(size_t)b * 128 + tid] = o;
}

// ---------------------------------------------------------------- launch
extern "C" void kernel_launch(void* const* d_in, const int* in_sizes, int n_in,
                              void* d_out, int out_size, void* d_ws, size_t ws_size,
                              hipStream_t stream)
{
    const float* emb        = (const float*)d_in[0];
    const float* bases      = (const float*)d_in[1];
    const float* comp       = (const float*)d_in[2];
    const float* root       = (const float*)d_in[3];
    const float* rgcn_bias  = (const float*)d_in[4];
    const float* sess_theta = (const float*)d_in[5];
    const float* sess_bias  = (const float*)d_in[6];
    const float* know_theta = (const float*)d_in[7];
    const float* know_bias  = (const float*)d_in[8];
    const float* in_proj_w  = (const float*)d_in[9];
    const float* in_proj_b  = (const float*)d_in[10];
    const float* out_proj_w = (const float*)d_in[11];
    const float* out_proj_b = (const float*)d_in[12];
    const float* attn_his_a = (const float*)d_in[13];
    const float* attn_his_b = (const float*)d_in[14];
    const float* attn_a     = (const float*)d_in[15];
    const float* attn_b     = (const float*)d_in[16];
    const float* rec_bias   = (const float*)d_in[17];
    const int* edge_src     = (const int*)d_in[18];
    const int* edge_dst     = (const int*)d_in[19];
    const int* edge_type    = (const int*)d_in[20];
    const int* sess_nodes   = (const int*)d_in[21];
    const int* sess_edges   = (const int*)d_in[22];
    const int* know_nodes   = (const int*)d_in[23];
    const int* know_edges   = (const int*)d_in[24];
    const int* sess_rel_idx = (const int*)d_in[25];
    const int* know_rel_idx = (const int*)d_in[26];
    const int* context_idx  = (const int*)d_in[27];
    float* out = (float*)d_out;

    float* wsf = (float*)d_ws;
    size_t off = 0;
    auto alloc = [&](size_t n) { size_t r = off; off += (n + 255) & ~(size_t)255; return r; };
    float* kg      = wsf + alloc(12800000);          // N*D
    float* tmp     = wsf + alloc(12800000);          // RGCN sort buffers
    float* w_all   = wsf + alloc(196608);
    int*   bsum    = (int*)(wsf + alloc(2048));
    int*   stybase = (int*)(wsf + alloc(16));
    int*   hhist   = (int*)(wsf + alloc(20000));
    int*   hoff    = (int*)(wsf + alloc(20000));
    int*   hcur    = (int*)(wsf + alloc(20000));
    int*   pns     = (int*)(wsf + alloc(400000));
    int*   mcnt    = (int*)(wsf + alloc(16));
    int*   mhe     = (int*)(wsf + alloc(MCAP));
    int*   msl     = (int*)(wsf + alloc(MCAP));
    int*   slot_s  = (int*)(wsf + alloc(100000));
    int*   slot_k  = (int*)(wsf + alloc(100000));
    int*   scnt    = (int*)(wsf + alloc(16));
    float* efeat   = wsf + alloc(2560000);
    float* sdeg    = wsf + alloc(4096);
    float* sacc    = wsf + alloc(524288);
    float* slotout = wsf + alloc(524288);
    float* related = wsf + alloc(1048576);
    float* ctx     = wsf + alloc(262144);
    float* qb      = wsf + alloc(262144);
    float* kb      = wsf + alloc(1048576);
    float* vb      = wsf + alloc(1048576);
    float* obuf    = wsf + alloc(262144);
    float* attrel  = wsf + alloc(262144);
    float* his     = wsf + alloc(8192);
    float* ucat    = wsf + alloc(270336);
    float* userb   = wsf + alloc(8192);
    (void)ws_size; (void)in_sizes; (void)n_in; (void)out_size;

    int* hist    = (int*)tmp;
    int* soff    = (int*)tmp + 1200000;
    int* segpos  = (int*)tmp + 2400000;
    int* seglist = (int*)tmp + 3600000;
    int* ssrc    = (int*)tmp + 4800000;

    const int nbR = (NRBINS + SCAN_CHUNK - 1) / SCAN_CHUNK;
    const int nbH = (DHE + SCAN_CHUNK - 1) / SCAN_CHUNK;

    // ---------------- RGCN: sort edges by (type, dst)
    hipMemsetAsync(hist, 0, NRBINS * 4, stream);
    hipMemsetAsync(slot_s, 0xFF, 100000 * 4, stream);
    hipMemsetAsync(slot_k, 0xFF, 100000 * 4, stream);
    hipMemsetAsync(scnt, 0, 16 * 4, stream);
    k_hist_rgcn<<<(DE + 255) / 256, 256, 0, stream>>>(edge_dst, edge_type, hist, DE);
    k_scan_pass1<<<nbR, 256, 0, stream>>>(hist, NRBINS, bsum, 0);
    k_scan_pass2p<<<1, 256, 0, stream>>>(bsum, nbR, nullptr);
    k_scan_pass3<<<nbR, 256, 0, stream>>>(hist, NRBINS, bsum, soff, 0);
    k_scan_pass1<<<nbR, 256, 0, stream>>>(hist, NRBINS, bsum, 1);
    k_scan_pass2p<<<1, 256, 0, stream>>>(bsum, nbR, stybase + DR);
    k_scan_pass3<<<nbR, 256, 0, stream>>>(hist, NRBINS, bsum, segpos, 1);
    k_stypebase<<<1, 64, 0, stream>>>(segpos, stybase);
    k_seglist<<<(NRBINS + 255) / 256, 256, 0, stream>>>(hist, segpos, seglist, NRBINS);
    hipMemsetAsync(segpos, 0, NRBINS * 4, stream);
    k_bucket_rgcn<<<(DE + 255) / 256, 256, 0, stream>>>(edge_src, edge_dst, edge_type,
                                                        soff, segpos, ssrc, DE);
    k_wcomp<<<(DR * DD * DD + 255) / 256, 256, 0, stream>>>(comp, bases, w_all);

    int gemmN = (DN + 63) / 64;
    k_mfma_gemm<<<gemmN, 256, 0, stream>>>(emb, root, rgcn_bias, nullptr, kg, DN, 0);
    for (int r = 0; r < DR; ++r)
        k_mfma_rgcn<<<gemmN, 256, 0, stream>>>(emb, w_all + (size_t)r * DD * DD,
                                               seglist, soff, hist, ssrc, stybase, kg, r);

    // ---------------- sess hypergraph (theta pushed to 4096-slot GEMM)
    k_slot_assign<<<16, 256, 0, stream>>>(sess_rel_idx, slot_s, scnt, DB * DLR);
    hipMemsetAsync(hhist, 0, DHE * 4, stream);
    hipMemsetAsync(hcur, 0, DHE * 4, stream);
    hipMemsetAsync(sdeg, 0, 4096 * 4, stream);
    hipMemsetAsync(sacc, 0, 524288 * 4, stream);
    hipMemsetAsync(mcnt, 0, 16 * 4, stream);
    k_hist_p<<<(DP + 255) / 256, 256, 0, stream>>>(sess_edges, hhist, DP);
    k_scan_pass1<<<nbH, 256, 0, stream>>>(hhist, DHE, bsum, 0);
    k_scan_pass2p<<<1, 256, 0, stream>>>(bsum, nbH, nullptr);
    k_scan_pass3<<<nbH, 256, 0, stream>>>(hhist, DHE, bsum, hoff, 0);
    k_bucket_p<<<(DP + 255) / 256, 256, 0, stream>>>(sess_nodes, sess_edges, hoff, hcur, pns, DP);
    k_hyper_agg<<<(DHE * 64 + 255) / 256, 256, 0, stream>>>(kg, pns, hoff, hhist, efeat);
    k_sdeg<<<(DP + 255) / 256, 256, 0, stream>>>(sess_nodes, slot_s, sdeg, DP);
    k_match<<<(DP + 255) / 256, 256, 0, stream>>>(sess_nodes, sess_edges, slot_s, mcnt, mhe, msl, DP);
    k_accmatch<<<256, 256, 0, stream>>>(efeat, mhe, msl, mcnt, sacc);
    k_mfma_gemm<<<64, 256, 0, stream>>>(sacc, sess_theta, sess_bias, sdeg, slotout, 4096, 0);
    k_rel_gather<<<(DB * DLR * 32 + 255) / 256, 256, 0, stream>>>(slotout, slot_s, sess_rel_idx,
                                                                  related, 0);

    // ---------------- know hypergraph
    k_slot_assign<<<16, 256, 0, stream>>>(know_rel_idx, slot_k, scnt + 1, DB * DLR);
    hipMemsetAsync(hhist, 0, DHE * 4, stream);
    hipMemsetAsync(hcur, 0, DHE * 4, stream);
    hipMemsetAsync(sdeg, 0, 4096 * 4, stream);
    hipMemsetAsync(sacc, 0, 524288 * 4, stream);
    hipMemsetAsync(mcnt, 0, 16 * 4, stream);
    k_hist_p<<<(DP + 255) / 256, 256, 0, stream>>>(know_edges, hhist, DP);
    k_scan_pass1<<<nbH, 256, 0, stream>>>(hhist, DHE, bsum, 0);
    k_scan_pass2p<<<1, 256, 0, stream>>>(bsum, nbH, nullptr);
    k_scan_pass3<<<nbH, 256, 0, stream>>>(hhist, DHE, bsum, hoff, 0);
    k_bucket_p<<<(DP + 255) / 256, 256, 0, stream>>>(know_nodes, know_edges, hoff, hcur, pns, DP);
    k_hyper_agg<<<(DHE * 64 + 255) / 256, 256, 0, stream>>>(kg, pns, hoff, hhist, efeat);
    k_sdeg<<<(DP + 255) / 256, 256, 0, stream>>>(know_nodes, slot_k, sdeg, DP);
    k_match<<<(DP + 255) / 256, 256, 0, stream>>>(know_nodes, know_edges, slot_k, mcnt, mhe, msl, DP);
    k_accmatch<<<256, 256, 0, stream>>>(efeat, mhe, msl, mcnt, sacc);
    k_mfma_gemm<<<64, 256, 0, stream>>>(sacc, know_theta, know_bias, sdeg, slotout, 4096, 0);
    k_rel_gather<<<(DB * DLR * 32 + 255) / 256, 256, 0, stream>>>(slotout, slot_k, know_rel_idx,
                                                                  related, 64);

    // ---------------- context + MHA
    k_gather_rows<<<(DB * DLC * 128 + 255) / 256, 256, 0, stream>>>(kg, context_idx, ctx, DB * DLC);
    k_mfma_gemm<<<(DB * DLC + 63) / 64, 256, 0, stream>>>(ctx, in_proj_w, in_proj_b, nullptr,
                                                          qb, DB * DLC, 1);
    k_mfma_gemm<<<(DB * 128 + 63) / 64, 256, 0, stream>>>(related, in_proj_w + DD * DD,
                                                          in_proj_b + DD, nullptr, kb, DB * 128, 1);
    k_mfma_gemm<<<(DB * 128 + 63) / 64, 256, 0, stream>>>(related, in_proj_w + 2 * DD * DD,
                                                          in_proj_b + 2 * DD, nullptr, vb, DB * 128, 1);
    k_mha<<<DB * DNH, 256, 0, stream>>>(qb, kb, vb, obuf);
    k_mfma_gemm<<<(DB * DLC + 63) / 64, 256, 0, stream>>>(obuf, out_proj_w, out_proj_b, nullptr,
                                                          attrel, DB * DLC, 1);

    // ---------------- pooling + score
    k_selfattn<32><<<DB, 128, 0, stream>>>(attrel, attn_his_a, attn_his_b, his);
    k_build_ucat<<<(DB * 33 * 128 + 255) / 256, 256, 0, stream>>>(ctx, his, ucat);
    k_selfattn<33><<<DB, 128, 0, stream>>>(ucat, attn_a, attn_b, userb);
    k_score_mfma<<<gemmN, 256, 0, stream>>>(kg, userb, rec_bias, out);
}

// Round 5
// 1246.554 us; speedup vs baseline: 2.4366x; 1.0646x over previous
//
#include <hip/hip_runtime.h>
#include <hip/hip_bf16.h>

#define DN 100000     // N entities
#define DD 128        // D
#define DR 12         // R relations
#define DNB 8         // bases
#define DE 1000000    // edges
#define DP 400000     // hyperedge incidences
#define DHE 20000     // hyperedges
#define DHE2 40000    // both sides combined
#define DB 64         // batch
#define DLR 64
#define DLC 32
#define DNH 8
#define DHD 16
#define NRBINS (DR * DN)   // 1.2M
#define SCAN_CHUNK 1024
#define MCAP 65536

typedef unsigned short ushortT;
typedef unsigned int uintT;
typedef __attribute__((ext_vector_type(8))) short s8v;
typedef __attribute__((ext_vector_type(4))) float f4v;

#define APAD 136   // 64 rows of K=128 bf16, stride 272B
#define BPAD 40    // 128 rows of K=32 bf16, stride 80B

__device__ __forceinline__ ushortT rneb(float v) {
    uintT b = __float_as_uint(v);
    return (ushortT)((b + 0x7FFFu + ((b >> 16) & 1u)) >> 16);
}
__device__ __forceinline__ float b2f(ushortT h) {
    return __uint_as_float(((uintT)h) << 16);
}

__device__ __forceinline__ void split_store8(ushortT* hbase, ushortT* lbase, const float* v)
{
    ushortT h[8], l[8];
    #pragma unroll
    for (int j = 0; j < 8; ++j) {
        h[j] = rneb(v[j]);
        l[j] = rneb(v[j] - b2f(h[j]));
    }
    uint4 hv = make_uint4((uintT)h[0] | ((uintT)h[1] << 16), (uintT)h[2] | ((uintT)h[3] << 16),
                          (uintT)h[4] | ((uintT)h[5] << 16), (uintT)h[6] | ((uintT)h[7] << 16));
    uint4 lv = make_uint4((uintT)l[0] | ((uintT)l[1] << 16), (uintT)l[2] | ((uintT)l[3] << 16),
                          (uintT)l[4] | ((uintT)l[5] << 16), (uintT)l[6] | ((uintT)l[7] << 16));
    *(uint4*)hbase = hv;
    *(uint4*)lbase = lv;
}

// ---------------------------------------------------------------- MFMA GEMM (split-bf16, ~fp32 accuracy)
__global__ __launch_bounds__(256) void k_mfma_gemm(
    const float* __restrict__ A, const float* __restrict__ W,
    const float* __restrict__ bias, const float* __restrict__ rs,
    float* __restrict__ C, int M, int trans)
{
    __shared__ __align__(16) ushortT Ah[64 * APAD], Al[64 * APAD];
    __shared__ __align__(16) ushortT Bh[128 * BPAD], Bl[128 * BPAD];
    int tid = threadIdx.x;
    int row0 = blockIdx.x * 64;
    {
        int row = tid >> 2, c0 = (tid & 3) * 32;
        int gr = row0 + row;
        const float* ar = A + (size_t)gr * 128 + c0;
        float sc = 1.0f;
        if (rs && gr < M) { float d = rs[gr]; sc = (d > 0.f) ? 1.0f / d : 0.f; }
        #pragma unroll
        for (int g = 0; g < 4; ++g) {
            float v[8] = {};
            if (gr < M) {
                float4 u0 = *(const float4*)(ar + g * 8);
                float4 u1 = *(const float4*)(ar + g * 8 + 4);
                v[0]=u0.x*sc; v[1]=u0.y*sc; v[2]=u0.z*sc; v[3]=u0.w*sc;
                v[4]=u1.x*sc; v[5]=u1.y*sc; v[6]=u1.z*sc; v[7]=u1.w*sc;
            }
            split_store8(&Ah[row * APAD + c0 + g * 8], &Al[row * APAD + c0 + g * 8], v);
        }
    }
    f4v acc[8] = {};
    int w = tid >> 6, lane = tid & 63, m = lane & 15, quad = lane >> 4;
    for (int kc = 0; kc < 4; ++kc) {
        __syncthreads();
        #pragma unroll
        for (int t2 = 0; t2 < 2; ++t2) {
            int task = tid + t2 * 256;
            int n = task & 127, kg = task >> 7;
            float v[8];
            if (!trans) {
                #pragma unroll
                for (int j = 0; j < 8; ++j)
                    v[j] = W[(size_t)(kc * 32 + kg * 8 + j) * 128 + n];
            } else {
                const float* wr = W + (size_t)n * 128 + kc * 32 + kg * 8;
                float4 u0 = *(const float4*)wr, u1 = *(const float4*)(wr + 4);
                v[0]=u0.x; v[1]=u0.y; v[2]=u0.z; v[3]=u0.w;
                v[4]=u1.x; v[5]=u1.y; v[6]=u1.z; v[7]=u1.w;
            }
            split_store8(&Bh[n * BPAD + kg * 8], &Bl[n * BPAD + kg * 8], v);
        }
        __syncthreads();
        s8v ah = *(const s8v*)&Ah[(w * 16 + m) * APAD + kc * 32 + quad * 8];
        s8v al = *(const s8v*)&Al[(w * 16 + m) * APAD + kc * 32 + quad * 8];
        #pragma unroll
        for (int nt = 0; nt < 8; ++nt) {
            s8v bh = *(const s8v*)&Bh[(nt * 16 + m) * BPAD + quad * 8];
            s8v bl = *(const s8v*)&Bl[(nt * 16 + m) * BPAD + quad * 8];
            acc[nt] = __builtin_amdgcn_mfma_f32_16x16x32_bf16(ah, bh, acc[nt], 0, 0, 0);
            acc[nt] = __builtin_amdgcn_mfma_f32_16x16x32_bf16(al, bh, acc[nt], 0, 0, 0);
            acc[nt] = __builtin_amdgcn_mfma_f32_16x16x32_bf16(ah, bl, acc[nt], 0, 0, 0);
        }
    }
    float bv[8];
    #pragma unroll
    for (int nt = 0; nt < 8; ++nt) bv[nt] = bias ? bias[nt * 16 + m] : 0.f;
    #pragma unroll
    for (int rr = 0; rr < 4; ++rr) {
        int gr = row0 + w * 16 + quad * 4 + rr;
        if (gr < M) {
            #pragma unroll
            for (int nt = 0; nt < 8; ++nt)
                C[(size_t)gr * 128 + nt * 16 + m] = acc[nt][rr] + bv[nt];
        }
    }
}

// ---------------------------------------------------------------- RGCN fused segment-mean @ w[r] -> kg += (MFMA)
__global__ __launch_bounds__(256) void k_mfma_rgcn(
    const float* __restrict__ x, const float* __restrict__ wmat,
    const int* __restrict__ seglist, const int* __restrict__ soff,
    const int* __restrict__ slen, const int* __restrict__ ssrc,
    const int* __restrict__ stypebase, float* __restrict__ kg, int r)
{
    __shared__ __align__(16) ushortT Ah[64 * APAD], Al[64 * APAD];
    __shared__ __align__(16) ushortT Bh[128 * BPAD], Bl[128 * BPAD];
    int s0 = stypebase[r], s1 = stypebase[r + 1];
    int base = s0 + blockIdx.x * 64;
    if (base >= s1) return;
    int nrow = min(64, s1 - base);
    int tid = threadIdx.x;
    {
        int row = tid >> 2, c0 = (tid & 3) * 32;
        float a[32] = {};
        if (row < nrow) {
            int key = seglist[base + row];
            int st = soff[key], len = slen[key];
            for (int i = 0; i < len; ++i) {
                const float* xr = x + (size_t)ssrc[st + i] * 128 + c0;
                #pragma unroll
                for (int j = 0; j < 8; ++j) {
                    float4 v = *(const float4*)(xr + j * 4);
                    a[j*4+0] += v.x; a[j*4+1] += v.y; a[j*4+2] += v.z; a[j*4+3] += v.w;
                }
            }
            float inv = 1.0f / (float)max(len, 1);
            #pragma unroll
            for (int j = 0; j < 32; ++j) a[j] *= inv;
        }
        #pragma unroll
        for (int g = 0; g < 4; ++g)
            split_store8(&Ah[row * APAD + c0 + g * 8], &Al[row * APAD + c0 + g * 8], a + g * 8);
    }
    f4v acc[8] = {};
    int w = tid >> 6, lane = tid & 63, m = lane & 15, quad = lane >> 4;
    for (int kc = 0; kc < 4; ++kc) {
        __syncthreads();
        #pragma unroll
        for (int t2 = 0; t2 < 2; ++t2) {
            int task = tid + t2 * 256;
            int n = task & 127, kg2 = task >> 7;
            float v[8];
            #pragma unroll
            for (int j = 0; j < 8; ++j)
                v[j] = wmat[(size_t)(kc * 32 + kg2 * 8 + j) * 128 + n];
            split_store8(&Bh[n * BPAD + kg2 * 8], &Bl[n * BPAD + kg2 * 8], v);
        }
        __syncthreads();
        s8v ah = *(const s8v*)&Ah[(w * 16 + m) * APAD + kc * 32 + quad * 8];
        s8v al = *(const s8v*)&Al[(w * 16 + m) * APAD + kc * 32 + quad * 8];
        #pragma unroll
        for (int nt = 0; nt < 8; ++nt) {
            s8v bh = *(const s8v*)&Bh[(nt * 16 + m) * BPAD + quad * 8];
            s8v bl = *(const s8v*)&Bl[(nt * 16 + m) * BPAD + quad * 8];
            acc[nt] = __builtin_amdgcn_mfma_f32_16x16x32_bf16(ah, bh, acc[nt], 0, 0, 0);
            acc[nt] = __builtin_amdgcn_mfma_f32_16x16x32_bf16(al, bh, acc[nt], 0, 0, 0);
            acc[nt] = __builtin_amdgcn_mfma_f32_16x16x32_bf16(ah, bl, acc[nt], 0, 0, 0);
        }
    }
    #pragma unroll
    for (int rr = 0; rr < 4; ++rr) {
        int rt = w * 16 + quad * 4 + rr;
        if (rt < nrow) {
            int dst = seglist[base + rt] - r * DN;
            float* kr = kg + (size_t)dst * 128 + m;
            #pragma unroll
            for (int nt = 0; nt < 8; ++nt)
                kr[nt * 16] += acc[nt][rr];
        }
    }
}

// ---------------------------------------------------------------- scoring (MFMA)
__global__ __launch_bounds__(256) void k_score_mfma(
    const float* __restrict__ kg, const float* __restrict__ user,
    const float* __restrict__ rb, float* __restrict__ out)
{
    __shared__ __align__(16) ushortT Ah[64 * APAD], Al[64 * APAD];
    __shared__ __align__(16) ushortT Bh[64 * APAD], Bl[64 * APAD];
    int tid = threadIdx.x;
    int n0 = blockIdx.x * 64;
    {
        int row = tid >> 2, c0 = (tid & 3) * 32;
        int gr = n0 + row;
        const float* ar = kg + (size_t)gr * 128 + c0;
        const float* ur = user + (size_t)row * 128 + c0;
        #pragma unroll
        for (int g = 0; g < 4; ++g) {
            float v[8] = {};
            if (gr < DN) {
                float4 u0 = *(const float4*)(ar + g * 8);
                float4 u1 = *(const float4*)(ar + g * 8 + 4);
                v[0]=u0.x; v[1]=u0.y; v[2]=u0.z; v[3]=u0.w;
                v[4]=u1.x; v[5]=u1.y; v[6]=u1.z; v[7]=u1.w;
            }
            split_store8(&Ah[row * APAD + c0 + g * 8], &Al[row * APAD + c0 + g * 8], v);
            float u[8];
            float4 w0 = *(const float4*)(ur + g * 8);
            float4 w1 = *(const float4*)(ur + g * 8 + 4);
            u[0]=w0.x; u[1]=w0.y; u[2]=w0.z; u[3]=w0.w;
            u[4]=w1.x; u[5]=w1.y; u[6]=w1.z; u[7]=w1.w;
            split_store8(&Bh[row * APAD + c0 + g * 8], &Bl[row * APAD + c0 + g * 8], u);
        }
    }
    __syncthreads();
    f4v acc[4] = {};
    int w = tid >> 6, lane = tid & 63, m = lane & 15, quad = lane >> 4;
    #pragma unroll
    for (int kc = 0; kc < 4; ++kc) {
        s8v ah = *(const s8v*)&Ah[(w * 16 + m) * APAD + kc * 32 + quad * 8];
        s8v al = *(const s8v*)&Al[(w * 16 + m) * APAD + kc * 32 + quad * 8];
        #pragma unroll
        for (int nt = 0; nt < 4; ++nt) {
            s8v bh = *(const s8v*)&Bh[(nt * 16 + m) * APAD + kc * 32 + quad * 8];
            s8v bl = *(const s8v*)&Bl[(nt * 16 + m) * APAD + kc * 32 + quad * 8];
            acc[nt] = __builtin_amdgcn_mfma_f32_16x16x32_bf16(ah, bh, acc[nt], 0, 0, 0);
            acc[nt] = __builtin_amdgcn_mfma_f32_16x16x32_bf16(al, bh, acc[nt], 0, 0, 0);
            acc[nt] = __builtin_amdgcn_mfma_f32_16x16x32_bf16(ah, bl, acc[nt], 0, 0, 0);
        }
    }
    int n = n0 + w * 16 + quad * 4;
    if (n < DN) {
        float4 rbv = *(const float4*)&rb[n];
        #pragma unroll
        for (int nt = 0; nt < 4; ++nt) {
            int b = nt * 16 + m;
            float4 o = make_float4(acc[nt][0] + rbv.x, acc[nt][1] + rbv.y,
                                   acc[nt][2] + rbv.z, acc[nt][3] + rbv.w);
            *(float4*)&out[(size_t)b * DN + n] = o;
        }
    }
}

// ---------------------------------------------------------------- scans (single-mode, for hyper)
__global__ void k_scan_pass1(const int* __restrict__ in, int n, int* __restrict__ bsum)
{
    __shared__ int red[256];
    int b = blockIdx.x, t = threadIdx.x;
    int i0 = b * SCAN_CHUNK + t * 4;
    int s = 0;
    #pragma unroll
    for (int j = 0; j < 4; ++j) {
        int i = i0 + j;
        if (i < n) s += in[i];
    }
    red[t] = s;
    __syncthreads();
    for (int o = 128; o > 0; o >>= 1) {
        if (t < o) red[t] += red[t + o];
        __syncthreads();
    }
    if (t == 0) bsum[b] = red[0];
}

__global__ __launch_bounds__(256) void k_scan_pass2p(int* bsum, int nb, int* total)
{
    __shared__ int lds[256];
    __shared__ int carry;
    int t = threadIdx.x;
    if (t == 0) carry = 0;
    __syncthreads();
    for (int c0 = 0; c0 < nb; c0 += 256) {
        int i = c0 + t;
        int v = (i < nb) ? bsum[i] : 0;
        lds[t] = v;
        __syncthreads();
        for (int o = 1; o < 256; o <<= 1) {
            int add = (t >= o) ? lds[t - o] : 0;
            __syncthreads();
            lds[t] += add;
            __syncthreads();
        }
        int myc = carry;
        if (i < nb) bsum[i] = lds[t] - v + myc;
        int tot = lds[255];
        __syncthreads();
        if (t == 0) carry = myc + tot;
        __syncthreads();
    }
    if (total && t == 0) *total = carry;
}

__global__ void k_scan_pass3(const int* __restrict__ in, int n, const int* __restrict__ bsum,
                             int* __restrict__ out)
{
    __shared__ int lds[256];
    int b = blockIdx.x, t = threadIdx.x;
    int i0 = b * SCAN_CHUNK + t * 4;
    int v[4]; int s = 0;
    #pragma unroll
    for (int j = 0; j < 4; ++j) {
        int i = i0 + j;
        int x = 0;
        if (i < n) x = in[i];
        v[j] = x; s += x;
    }
    lds[t] = s;
    __syncthreads();
    for (int o = 1; o < 256; o <<= 1) {
        int add = (t >= o) ? lds[t - o] : 0;
        __syncthreads();
        lds[t] += add;
        __syncthreads();
    }
    int run = lds[t] - s + bsum[b];
    #pragma unroll
    for (int j = 0; j < 4; ++j) {
        int i = i0 + j;
        if (i < n) { out[i] = run; run += v[j]; }
    }
}

// ---------------------------------------------------------------- dual scan (value + predicate), for RGCN
__global__ void k_scan2_pass1(const int* __restrict__ in, int n, int* bV, int* bP)
{
    __shared__ int redV[256], redP[256];
    int b = blockIdx.x, t = threadIdx.x;
    int i0 = b * SCAN_CHUNK + t * 4;
    int sv = 0, sp = 0;
    #pragma unroll
    for (int j = 0; j < 4; ++j) {
        int i = i0 + j;
        if (i < n) { int v = in[i]; sv += v; sp += (v > 0); }
    }
    redV[t] = sv; redP[t] = sp;
    __syncthreads();
    for (int o = 128; o > 0; o >>= 1) {
        if (t < o) { redV[t] += redV[t + o]; redP[t] += redP[t + o]; }
        __syncthreads();
    }
    if (t == 0) { bV[b] = redV[0]; bP[b] = redP[0]; }
}

__global__ __launch_bounds__(256) void k_scan2_pass2(int* bV, int* bP, int nb, int* totalP)
{
    __shared__ int lds[256];
    __shared__ int carry;
    int t = threadIdx.x;
    #pragma unroll 1
    for (int which = 0; which < 2; ++which) {
        int* bsum = which ? bP : bV;
        __syncthreads();
        if (t == 0) carry = 0;
        __syncthreads();
        for (int c0 = 0; c0 < nb; c0 += 256) {
            int i = c0 + t;
            int v = (i < nb) ? bsum[i] : 0;
            lds[t] = v;
            __syncthreads();
            for (int o = 1; o < 256; o <<= 1) {
                int add = (t >= o) ? lds[t - o] : 0;
                __syncthreads();
                lds[t] += add;
                __syncthreads();
            }
            int myc = carry;
            if (i < nb) bsum[i] = lds[t] - v + myc;
            int tot = lds[255];
            __syncthreads();
            if (t == 0) carry = myc + tot;
            __syncthreads();
        }
        if (which == 1 && totalP && t == 0) *totalP = carry;
    }
}

__global__ void k_scan2_pass3(const int* __restrict__ in, int n,
                              const int* __restrict__ bV, const int* __restrict__ bP,
                              int* __restrict__ outV, int* __restrict__ outP)
{
    __shared__ int ldsV[256], ldsP[256];
    int b = blockIdx.x, t = threadIdx.x;
    int i0 = b * SCAN_CHUNK + t * 4;
    int v[4]; int sv = 0, sp = 0;
    #pragma unroll
    for (int j = 0; j < 4; ++j) {
        int i = i0 + j;
        int x = 0;
        if (i < n) x = in[i];
        v[j] = x; sv += x; sp += (x > 0);
    }
    ldsV[t] = sv; ldsP[t] = sp;
    __syncthreads();
    for (int o = 1; o < 256; o <<= 1) {
        int addV = (t >= o) ? ldsV[t - o] : 0;
        int addP = (t >= o) ? ldsP[t - o] : 0;
        __syncthreads();
        ldsV[t] += addV; ldsP[t] += addP;
        __syncthreads();
    }
    int runV = ldsV[t] - sv + bV[b];
    int runP = ldsP[t] - sp + bP[b];
    #pragma unroll
    for (int j = 0; j < 4; ++j) {
        int i = i0 + j;
        if (i < n) {
            outV[i] = runV; outP[i] = runP;
            runV += v[j]; runP += (v[j] > 0);
        }
    }
}

// ---------------------------------------------------------------- RGCN sort
__global__ void k_hist_rgcn(const int* __restrict__ dst, const int* __restrict__ et,
                            int* hist, int E)
{
    int i = blockIdx.x * blockDim.x + threadIdx.x;
    if (i < E) atomicAdd(&hist[(size_t)et[i] * DN + dst[i]], 1);
}

__global__ void k_seglist(const int* __restrict__ hist, const int* __restrict__ segpos,
                          int* __restrict__ seglist, int n)
{
    int i = blockIdx.x * blockDim.x + threadIdx.x;
    if (i < n && hist[i] > 0) seglist[segpos[i]] = i;
}

__global__ void k_stypebase(const int* __restrict__ segpos, int* stypebase)
{
    int t = threadIdx.x;
    if (t < DR) stypebase[t] = segpos[(size_t)t * DN];
}

__global__ void k_bucket_rgcn(const int* __restrict__ src, const int* __restrict__ dst,
                              const int* __restrict__ et, const int* __restrict__ off,
                              int* cur, int* ssrc, int E)
{
    int i = blockIdx.x * blockDim.x + threadIdx.x;
    if (i >= E) return;
    int key = et[i] * DN + dst[i];
    int pos = off[key] + atomicAdd(&cur[key], 1);
    ssrc[pos] = src[i];
}

__global__ void k_wcomp(const float* __restrict__ comp, const float* __restrict__ bases,
                        float* __restrict__ w_all)
{
    int i = blockIdx.x * blockDim.x + threadIdx.x;
    if (i >= DR * DD * DD) return;
    int r = i / (DD * DD), io = i % (DD * DD);
    float s = 0.f;
    #pragma unroll
    for (int b = 0; b < DNB; ++b) s += comp[r * DNB + b] * bases[(size_t)b * DD * DD + io];
    w_all[i] = s;
}

// ---------------------------------------------------------------- hypergraph (both sides combined, 40000 bins)
__global__ void k_hist_p2(const int* __restrict__ se, const int* __restrict__ ke, int* hist)
{
    int i = blockIdx.x * blockDim.x + threadIdx.x;
    if (i < DP) atomicAdd(&hist[se[i]], 1);
    else if (i < 2 * DP) atomicAdd(&hist[DHE + ke[i - DP]], 1);
}

__global__ void k_bucket_p2(const int* __restrict__ sn, const int* __restrict__ se,
                            const int* __restrict__ kn, const int* __restrict__ ke,
                            const int* __restrict__ off, int* cur, int* pns)
{
    int i = blockIdx.x * blockDim.x + threadIdx.x;
    if (i >= 2 * DP) return;
    int e, node;
    if (i < DP) { e = se[i]; node = sn[i]; }
    else { e = DHE + ke[i - DP]; node = kn[i - DP]; }
    int pos = off[e] + atomicAdd(&cur[e], 1);
    pns[pos] = node;
}

// one wave per hyperedge (global 0..40000): efeat[he] = mean of kg[node]
__global__ void k_hyper_agg(const float* __restrict__ xsrc, const int* __restrict__ pns,
                            const int* __restrict__ hoff, const int* __restrict__ hcnt,
                            float* __restrict__ efeat)
{
    int lane = threadIdx.x & 63;
    int he = (blockIdx.x * blockDim.x + threadIdx.x) >> 6;
    if (he >= DHE2) return;
    int st = hoff[he], len = hcnt[he];
    float2 acc = make_float2(0.f, 0.f);
    for (int c = 0; c < len; c += 64) {
        int m = min(64, len - c);
        int nid = (c + lane < len) ? pns[st + c + lane] : 0;
        for (int j = 0; j < m; ++j) {
            int node = __shfl(nid, j);
            float2 v = *(const float2*)&xsrc[(size_t)node * 128 + lane * 2];
            acc.x += v.x; acc.y += v.y;
        }
    }
    float inv = (len > 0) ? 1.0f / (float)len : 0.f;
    acc.x *= inv; acc.y *= inv;
    *(float2*)&efeat[(size_t)he * 128 + lane * 2] = acc;
}

__global__ void k_slot_assign2(const int* __restrict__ sidx, const int* __restrict__ kidx,
                               int* slot_s, int* slot_k, int* scnt)
{
    int i = blockIdx.x * blockDim.x + threadIdx.x;
    if (i < DB * DLR) {
        int node = sidx[i];
        if (atomicCAS(&slot_s[node], -1, -2) == -1) slot_s[node] = atomicAdd(&scnt[0], 1);
    } else if (i < 2 * DB * DLR) {
        int node = kidx[i - DB * DLR];
        if (atomicCAS(&slot_k[node], -1, -2) == -1) slot_k[node] = atomicAdd(&scnt[1], 1);
    }
}

// fused sdeg + match with block-aggregated compaction (one global atomic per block)
__global__ __launch_bounds__(256) void k_sdeg_match(
    const int* __restrict__ nodes, const int* __restrict__ he, const int* __restrict__ slot,
    float* sdeg, int* mcnt, int* mhe, int* msl, int heBase)
{
    __shared__ int lcnt, lbase;
    if (threadIdx.x == 0) lcnt = 0;
    __syncthreads();
    int i = blockIdx.x * 256 + threadIdx.x;
    int s = -1, lidx = 0;
    if (i < DP) {
        s = slot[nodes[i]];
        if (s >= 0) {
            atomicAdd(&sdeg[s], 1.0f);
            lidx = atomicAdd(&lcnt, 1);
        }
    }
    __syncthreads();
    if (threadIdx.x == 0) lbase = (lcnt > 0) ? atomicAdd(mcnt, lcnt) : 0;
    __syncthreads();
    if (s >= 0) {
        int idx = lbase + lidx;
        if (idx < MCAP) { mhe[idx] = heBase + he[i]; msl[idx] = s; }
    }
}

__global__ void k_accmatch(const float* __restrict__ efeat, const int* __restrict__ mhe,
                           const int* __restrict__ msl, const int* __restrict__ mcnt,
                           float* sacc)
{
    int lane = threadIdx.x & 63;
    int w = (blockIdx.x * blockDim.x + threadIdx.x) >> 6;
    int nw = (gridDim.x * blockDim.x) >> 6;
    int M = min(*mcnt, MCAP);
    for (int i = w; i < M; i += nw) {
        float2 v = *(const float2*)&efeat[(size_t)mhe[i] * 128 + lane * 2];
        atomicAdd(&sacc[(size_t)msl[i] * 128 + lane * 2],     v.x);
        atomicAdd(&sacc[(size_t)msl[i] * 128 + lane * 2 + 1], v.y);
    }
}

__global__ void k_rel_gather(const float* __restrict__ slotout, const int* __restrict__ slot,
                             const int* __restrict__ rel_idx, float* __restrict__ related,
                             int colOff)
{
    int gid = blockIdx.x * blockDim.x + threadIdx.x;
    int i = gid >> 5, c = gid & 31;
    if (i >= DB * DLR) return;
    int s = slot[rel_idx[i]];
    int b = i / DLR, l = i % DLR;
    ((float4*)&related[((size_t)b * 128 + colOff + l) * 128])[c] =
        ((const float4*)&slotout[(size_t)s * 128])[c];
}

// ---------------------------------------------------------------- gathers / misc
__global__ void k_gather_rows(const float* __restrict__ src, const int* __restrict__ idx,
                              float* dst, int nRows)
{
    int i = blockIdx.x * blockDim.x + threadIdx.x;
    if (i >= nRows * 128) return;
    int row = i >> 7, d = i & 127;
    dst[i] = src[(size_t)idx[row] * 128 + d];
}

// ---------------------------------------------------------------- MHA: one block per (b,h)
__global__ __launch_bounds__(256) void k_mha(const float* __restrict__ qb,
                                             const float* __restrict__ kb,
                                             const float* __restrict__ vb,
                                             float* __restrict__ ob)
{
    int b = blockIdx.x >> 3, h = blockIdx.x & 7;
    __shared__ float Ks[128][16], Vs[128][16], Qs[32][16];
    int tid = threadIdx.x;
    for (int i = tid; i < 128 * 16; i += 256) {
        int j = i >> 4, d = i & 15;
        Ks[j][d] = kb[((size_t)b * 128 + j) * 128 + h * 16 + d];
        Vs[j][d] = vb[((size_t)b * 128 + j) * 128 + h * 16 + d];
    }
    for (int i = tid; i < 32 * 16; i += 256) {
        int q = i >> 4, d = i & 15;
        Qs[q][d] = qb[((size_t)b * 32 + q) * 128 + h * 16 + d] * 0.25f;
    }
    __syncthreads();
    int q = tid >> 3;
    int jg = tid & 7;
    float lg[16];
    float m = -1e30f;
    #pragma unroll
    for (int jj = 0; jj < 16; ++jj) {
        int j = jg * 16 + jj;
        float s = 0.f;
        #pragma unroll
        for (int d = 0; d < 16; ++d) s += Qs[q][d] * Ks[j][d];
        lg[jj] = s;
        m = fmaxf(m, s);
    }
    #pragma unroll
    for (int o = 1; o < 8; o <<= 1) m = fmaxf(m, __shfl_xor(m, o));
    float sum = 0.f;
    float acc[16] = {};
    #pragma unroll
    for (int jj = 0; jj < 16; ++jj) {
        float p = __expf(lg[jj] - m);
        sum += p;
        int j = jg * 16 + jj;
        #pragma unroll
        for (int d = 0; d < 16; ++d) acc[d] += p * Vs[j][d];
    }
    #pragma unroll
    for (int o = 1; o < 8; o <<= 1) {
        sum += __shfl_xor(sum, o);
        #pragma unroll
        for (int d = 0; d < 16; ++d) acc[d] += __shfl_xor(acc[d], o);
    }
    if (jg == 0) {
        float inv = 1.0f / sum;
        #pragma unroll
        for (int d = 0; d < 16; ++d)
            ob[((size_t)b * 32 + q) * 128 + h * 16 + d] = acc[d] * inv;
    }
}

// ---------------------------------------------------------------- tanh-attention pooling
__global__ __launch_bounds__(128) void k_selfattn32(const float* __restrict__ h,
                                                    const float* __restrict__ a,
                                                    const float* __restrict__ bvec,
                                                    float* __restrict__ out)
{
    const int L = 32;
    __shared__ float As[64 * 128];
    __shared__ float Hs[33 * 128];
    __shared__ float Ts[33];
    __shared__ float Ws[33];
    int b = blockIdx.x, tid = threadIdx.x;
    const float* hb = h + (size_t)b * L * 128;
    for (int i = tid; i < L * 32; i += 128) ((float4*)Hs)[i] = ((const float4*)hb)[i];
    float sacc[L];
    #pragma unroll
    for (int l = 0; l < L; ++l) sacc[l] = 0.f;
    for (int kc = 0; kc < 2; ++kc) {
        __syncthreads();
        for (int i = tid; i < 64 * 32; i += 128)
            ((float4*)As)[i] = ((const float4*)(a + kc * 64 * 128))[i];
        __syncthreads();
        #pragma unroll
        for (int l = 0; l < L; ++l) {
            float s = 0.f;
            for (int k = 0; k < 64; ++k) s += Hs[l * 128 + kc * 64 + k] * As[k * 128 + tid];
            sacc[l] += s;
        }
    }
    float bv = bvec[tid];
    __syncthreads();
    #pragma unroll
    for (int l = 0; l < L; ++l) As[l * 128 + tid] = tanhf(sacc[l]) * bv;
    __syncthreads();
    if (tid < L) {
        float e = 0.f;
        for (int d = 0; d < 128; ++d) e += As[tid * 128 + d];
        Ts[tid] = e;
    }
    __syncthreads();
    if (tid == 0) {
        float m = -1e30f;
        for (int l = 0; l < L; ++l) m = fmaxf(m, Ts[l]);
        float s = 0.f;
        for (int l = 0; l < L; ++l) { float w = __expf(Ts[l] - m); Ws[l] = w; s += w; }
        float inv = 1.0f / s;
        for (int l = 0; l < L; ++l) Ws[l] *= inv;
    }
    __syncthreads();
    float o = 0.f;
    #pragma unroll
    for (int l = 0; l < L; ++l) o += Ws[l] * Hs[l * 128 + tid];
    out[(size_t)b * 128 + tid] = o;
}

// L=33 variant reading ctx rows 0..31 and his as row 32 (ucat fused away)
__global__ __launch_bounds__(128) void k_selfattn_cat(const float* __restrict__ ctx,
                                                      const float* __restrict__ his,
                                                      const float* __restrict__ a,
                                                      const float* __restrict__ bvec,
                                                      float* __restrict__ out)
{
    const int L = 33;
    __shared__ float As[64 * 128];
    __shared__ float Hs[33 * 128];
    __shared__ float Ts[33];
    __shared__ float Ws[33];
    int b = blockIdx.x, tid = threadIdx.x;
    for (int i = tid; i < L * 32; i += 128) {
        int row = i >> 5, c = i & 31;
        float4 v = (row < 32) ? ((const float4*)(ctx + ((size_t)b * 32 + row) * 128))[c]
                              : ((const float4*)(his + (size_t)b * 128))[c];
        ((float4*)Hs)[i] = v;
    }
    float sacc[L];
    #pragma unroll
    for (int l = 0; l < L; ++l) sacc[l] = 0.f;
    for (int kc = 0; kc < 2; ++kc) {
        __syncthreads();
        for (int i = tid; i < 64 * 32; i += 128)
            ((float4*)As)[i] = ((const float4*)(a + kc * 64 * 128))[i];
        __syncthreads();
        #pragma unroll
        for (int l = 0; l < L; ++l) {
            float s = 0.f;
            for (int k = 0; k < 64; ++k) s += Hs[l * 128 + kc * 64 + k] * As[k * 128 + tid];
            sacc[l] += s;
        }
    }
    float bv = bvec[tid];
    __syncthreads();
    #pragma unroll
    for (int l = 0; l < L; ++l) As[l * 128 + tid] = tanhf(sacc[l]) * bv;
    __syncthreads();
    if (tid < L) {
        float e = 0.f;
        for (int d = 0; d < 128; ++d) e += As[tid * 128 + d];
        Ts[tid] = e;
    }
    __syncthreads();
    if (tid == 0) {
        float m = -1e30f;
        for (int l = 0; l < L; ++l) m = fmaxf(m, Ts[l]);
        float s = 0.f;
        for (int l = 0; l < L; ++l) { float w = __expf(Ts[l] - m); Ws[l] = w; s += w; }
        float inv = 1.0f / s;
        for (int l = 0; l < L; ++l) Ws[l] *= inv;
    }
    __syncthreads();
    float o = 0.f;
    #pragma unroll
    for (int l = 0; l < L; ++l) o += Ws[l] * Hs[l * 128 + tid];
    out[(size_t)b * 128 + tid] = o;
}

// ---------------------------------------------------------------- launch
extern "C" void kernel_launch(void* const* d_in, const int* in_sizes, int n_in,
                              void* d_out, int out_size, void* d_ws, size_t ws_size,
                              hipStream_t stream)
{
    const float* emb        = (const float*)d_in[0];
    const float* bases      = (const float*)d_in[1];
    const float* comp       = (const float*)d_in[2];
    const float* root       = (const float*)d_in[3];
    const float* rgcn_bias  = (const float*)d_in[4];
    const float* sess_theta = (const float*)d_in[5];
    const float* sess_bias  = (const float*)d_in[6];
    const float* know_theta = (const float*)d_in[7];
    const float* know_bias  = (const float*)d_in[8];
    const float* in_proj_w  = (const float*)d_in[9];
    const float* in_proj_b  = (const float*)d_in[10];
    const float* out_proj_w = (const float*)d_in[11];
    const float* out_proj_b = (const float*)d_in[12];
    const float* attn_his_a = (const float*)d_in[13];
    const float* attn_his_b = (const float*)d_in[14];
    const float* attn_a     = (const float*)d_in[15];
    const float* attn_b     = (const float*)d_in[16];
    const float* rec_bias   = (const float*)d_in[17];
    const int* edge_src     = (const int*)d_in[18];
    const int* edge_dst     = (const int*)d_in[19];
    const int* edge_type    = (const int*)d_in[20];
    const int* sess_nodes   = (const int*)d_in[21];
    const int* sess_edges   = (const int*)d_in[22];
    const int* know_nodes   = (const int*)d_in[23];
    const int* know_edges   = (const int*)d_in[24];
    const int* sess_rel_idx = (const int*)d_in[25];
    const int* know_rel_idx = (const int*)d_in[26];
    const int* context_idx  = (const int*)d_in[27];
    float* out = (float*)d_out;

    float* wsf = (float*)d_ws;
    size_t off = 0;
    auto alloc = [&](size_t n) { size_t r = off; off += (n + 255) & ~(size_t)255; return r; };
    float* kg      = wsf + alloc(12800000);          // N*D
    float* tmp     = wsf + alloc(12800000);          // RGCN sort arena + efeat tail
    float* w_all   = wsf + alloc(196608);
    int*   bsumV   = (int*)(wsf + alloc(2048));
    int*   bsumP   = (int*)(wsf + alloc(2048));
    int*   stybase = (int*)(wsf + alloc(16));
    // ---- contiguous zero block (one memset) ----
    size_t zstart = off;
    int*   hhist   = (int*)(wsf + alloc(DHE2));
    int*   hcur    = (int*)(wsf + alloc(DHE2));
    int*   mcnt    = (int*)(wsf + alloc(16));        // [0]=sess, [1]=know
    int*   scnt    = (int*)(wsf + alloc(16));
    float* sdeg_s  = wsf + alloc(4096);
    float* sdeg_k  = wsf + alloc(4096);
    float* sacc_s  = wsf + alloc(524288);
    float* sacc_k  = wsf + alloc(524288);
    size_t zend = off;
    // ---- contiguous 0xFF block (one memset) ----
    size_t fstart = off;
    int*   slot_s  = (int*)(wsf + alloc(100000));
    int*   slot_k  = (int*)(wsf + alloc(100000));
    size_t fend = off;
    int*   hoff    = (int*)(wsf + alloc(DHE2));
    int*   pns     = (int*)(wsf + alloc(2 * DP));
    int*   mhe_s   = (int*)(wsf + alloc(MCAP));
    int*   msl_s   = (int*)(wsf + alloc(MCAP));
    int*   mhe_k   = (int*)(wsf + alloc(MCAP));
    int*   msl_k   = (int*)(wsf + alloc(MCAP));
    float* slotout = wsf + alloc(524288);
    float* related = wsf + alloc(1048576);
    float* ctx     = wsf + alloc(262144);
    float* qb      = wsf + alloc(262144);
    float* kb      = wsf + alloc(1048576);
    float* vb      = wsf + alloc(1048576);
    float* obuf    = wsf + alloc(262144);
    float* attrel  = wsf + alloc(262144);
    float* his     = wsf + alloc(8192);
    float* userb   = wsf + alloc(8192);
    (void)ws_size; (void)in_sizes; (void)n_in; (void)out_size;

    // RGCN sort arena inside tmp; efeat (40000*128 = 5.12M) in the tail
    int*   hist    = (int*)tmp;                 // 1.2M
    int*   rcur    = (int*)tmp + 1200000;       // 1.2M (bucket cursor, pre-zeroed with hist)
    int*   soff    = (int*)tmp + 2400000;       // 1.2M
    int*   segpos  = (int*)tmp + 3600000;       // 1.2M
    int*   seglist = (int*)tmp + 4800000;       // 1.2M
    int*   ssrc    = (int*)tmp + 6000000;       // 1.0M
    float* efeat   = tmp + 7000000;             // 5.12M (used only after RGCN finishes)

    const int nbR = (NRBINS + SCAN_CHUNK - 1) / SCAN_CHUNK;   // 1172
    const int nbH = (DHE2 + SCAN_CHUNK - 1) / SCAN_CHUNK;     // 40

    // ---------------- upfront memsets (3 total)
    hipMemsetAsync(wsf + zstart, 0, (zend - zstart) * 4, stream);
    hipMemsetAsync(wsf + fstart, 0xFF, (fend - fstart) * 4, stream);
    hipMemsetAsync(hist, 0, 2400000 * 4, stream);   // hist + rcur

    k_slot_assign2<<<32, 256, 0, stream>>>(sess_rel_idx, know_rel_idx, slot_s, slot_k, scnt);

    // ---------------- RGCN: sort edges by (type, dst)
    k_hist_rgcn<<<(DE + 255) / 256, 256, 0, stream>>>(edge_dst, edge_type, hist, DE);
    k_scan2_pass1<<<nbR, 256, 0, stream>>>(hist, NRBINS, bsumV, bsumP);
    k_scan2_pass2<<<1, 256, 0, stream>>>(bsumV, bsumP, nbR, stybase + DR);
    k_scan2_pass3<<<nbR, 256, 0, stream>>>(hist, NRBINS, bsumV, bsumP, soff, segpos);
    k_stypebase<<<1, 64, 0, stream>>>(segpos, stybase);
    k_seglist<<<(NRBINS + 255) / 256, 256, 0, stream>>>(hist, segpos, seglist, NRBINS);
    k_bucket_rgcn<<<(DE + 255) / 256, 256, 0, stream>>>(edge_src, edge_dst, edge_type,
                                                        soff, rcur, ssrc, DE);
    k_wcomp<<<(DR * DD * DD + 255) / 256, 256, 0, stream>>>(comp, bases, w_all);

    int gemmN = (DN + 63) / 64;
    k_mfma_gemm<<<gemmN, 256, 0, stream>>>(emb, root, rgcn_bias, nullptr, kg, DN, 0);
    for (int r = 0; r < DR; ++r)
        k_mfma_rgcn<<<gemmN, 256, 0, stream>>>(emb, w_all + (size_t)r * DD * DD,
                                               seglist, soff, hist, ssrc, stybase, kg, r);

    // ---------------- hypergraph (both sides as one 40000-edge problem)
    k_hist_p2<<<(2 * DP + 255) / 256, 256, 0, stream>>>(sess_edges, know_edges, hhist);
    k_scan_pass1<<<nbH, 256, 0, stream>>>(hhist, DHE2, bsumV);
    k_scan_pass2p<<<1, 256, 0, stream>>>(bsumV, nbH, nullptr);
    k_scan_pass3<<<nbH, 256, 0, stream>>>(hhist, DHE2, bsumV, hoff);
    k_bucket_p2<<<(2 * DP + 255) / 256, 256, 0, stream>>>(sess_nodes, sess_edges,
                                                          know_nodes, know_edges,
                                                          hoff, hcur, pns);
    k_hyper_agg<<<(DHE2 * 64 + 255) / 256, 256, 0, stream>>>(kg, pns, hoff, hhist, efeat);

    k_sdeg_match<<<(DP + 255) / 256, 256, 0, stream>>>(sess_nodes, sess_edges, slot_s,
                                                       sdeg_s, mcnt, mhe_s, msl_s, 0);
    k_sdeg_match<<<(DP + 255) / 256, 256, 0, stream>>>(know_nodes, know_edges, slot_k,
                                                       sdeg_k, mcnt + 1, mhe_k, msl_k, DHE);
    k_accmatch<<<256, 256, 0, stream>>>(efeat, mhe_s, msl_s, mcnt, sacc_s);
    k_accmatch<<<256, 256, 0, stream>>>(efeat, mhe_k, msl_k, mcnt + 1, sacc_k);

    k_mfma_gemm<<<64, 256, 0, stream>>>(sacc_s, sess_theta, sess_bias, sdeg_s, slotout, 4096, 0);
    k_rel_gather<<<(DB * DLR * 32 + 255) / 256, 256, 0, stream>>>(slotout, slot_s, sess_rel_idx,
                                                                  related, 0);
    k_mfma_gemm<<<64, 256, 0, stream>>>(sacc_k, know_theta, know_bias, sdeg_k, slotout, 4096, 0);
    k_rel_gather<<<(DB * DLR * 32 + 255) / 256, 256, 0, stream>>>(slotout, slot_k, know_rel_idx,
                                                                  related, 64);

    // ---------------- context + MHA
    k_gather_rows<<<(DB * DLC * 128 + 255) / 256, 256, 0, stream>>>(kg, context_idx, ctx, DB * DLC);
    k_mfma_gemm<<<(DB * DLC + 63) / 64, 256, 0, stream>>>(ctx, in_proj_w, in_proj_b, nullptr,
                                                          qb, DB * DLC, 1);
    k_mfma_gemm<<<(DB * 128 + 63) / 64, 256, 0, stream>>>(related, in_proj_w + DD * DD,
                                                          in_proj_b + DD, nullptr, kb, DB * 128, 1);
    k_mfma_gemm<<<(DB * 128 + 63) / 64, 256, 0, stream>>>(related, in_proj_w + 2 * DD * DD,
                                                          in_proj_b + 2 * DD, nullptr, vb, DB * 128, 1);
    k_mha<<<DB * DNH, 256, 0, stream>>>(qb, kb, vb, obuf);
    k_mfma_gemm<<<(DB * DLC + 63) / 64, 256, 0, stream>>>(obuf, out_proj_w, out_proj_b, nullptr,
                                                          attrel, DB * DLC, 1);

    // ---------------- pooling + score
    k_selfattn32<<<DB, 128, 0, stream>>>(attrel, attn_his_a, attn_his_b, his);
    k_selfattn_cat<<<DB, 128, 0, stream>>>(ctx, his, attn_a, attn_b, userb);
    k_score_mfma<<<gemmN, 256, 0, stream>>>(kg, userb, rec_bias, out);
}

// Round 6
// 1104.921 us; speedup vs baseline: 2.7489x; 1.1282x over previous
//
#include <hip/hip_runtime.h>
#include <hip/hip_bf16.h>

#define DN 100000     // N entities
#define DD 128        // D
#define DR 12         // R relations
#define DNB 8         // bases
#define DE 1000000    // edges
#define DP 400000     // hyperedge incidences
#define DHE 20000     // hyperedges
#define DHE2 40000    // both sides combined
#define DB 64         // batch
#define DLR 64
#define DLC 32
#define DNH 8
#define DHD 16
#define NRBINS (DR * DN)   // 1.2M
#define SCAN_CHUNK 1024
#define MCAP 65536

typedef unsigned short ushortT;
typedef unsigned int uintT;
typedef __attribute__((ext_vector_type(8))) short s8v;
typedef __attribute__((ext_vector_type(4))) float f4v;

#define APAD 136   // 64 rows of K=128 bf16, stride 272B
#define BPAD 40    // 128 rows of K=32 bf16, stride 80B

__device__ __forceinline__ ushortT rneb(float v) {
    uintT b = __float_as_uint(v);
    return (ushortT)((b + 0x7FFFu + ((b >> 16) & 1u)) >> 16);
}
__device__ __forceinline__ float b2f(ushortT h) {
    return __uint_as_float(((uintT)h) << 16);
}

__device__ __forceinline__ void split_store8(ushortT* hbase, ushortT* lbase, const float* v)
{
    ushortT h[8], l[8];
    #pragma unroll
    for (int j = 0; j < 8; ++j) {
        h[j] = rneb(v[j]);
        l[j] = rneb(v[j] - b2f(h[j]));
    }
    uint4 hv = make_uint4((uintT)h[0] | ((uintT)h[1] << 16), (uintT)h[2] | ((uintT)h[3] << 16),
                          (uintT)h[4] | ((uintT)h[5] << 16), (uintT)h[6] | ((uintT)h[7] << 16));
    uint4 lv = make_uint4((uintT)l[0] | ((uintT)l[1] << 16), (uintT)l[2] | ((uintT)l[3] << 16),
                          (uintT)l[4] | ((uintT)l[5] << 16), (uintT)l[6] | ((uintT)l[7] << 16));
    *(uint4*)hbase = hv;
    *(uint4*)lbase = lv;
}

// ---------------------------------------------------------------- MFMA GEMM (split-bf16, ~fp32 accuracy)
__global__ __launch_bounds__(256) void k_mfma_gemm(
    const float* __restrict__ A, const float* __restrict__ W,
    const float* __restrict__ bias, const float* __restrict__ rs,
    float* __restrict__ C, int M, int trans)
{
    __shared__ __align__(16) ushortT Ah[64 * APAD], Al[64 * APAD];
    __shared__ __align__(16) ushortT Bh[128 * BPAD], Bl[128 * BPAD];
    int tid = threadIdx.x;
    int row0 = blockIdx.x * 64;
    {
        int row = tid >> 2, c0 = (tid & 3) * 32;
        int gr = row0 + row;
        const float* ar = A + (size_t)gr * 128 + c0;
        float sc = 1.0f;
        if (rs && gr < M) { float d = rs[gr]; sc = (d > 0.f) ? 1.0f / d : 0.f; }
        #pragma unroll
        for (int g = 0; g < 4; ++g) {
            float v[8] = {};
            if (gr < M) {
                float4 u0 = *(const float4*)(ar + g * 8);
                float4 u1 = *(const float4*)(ar + g * 8 + 4);
                v[0]=u0.x*sc; v[1]=u0.y*sc; v[2]=u0.z*sc; v[3]=u0.w*sc;
                v[4]=u1.x*sc; v[5]=u1.y*sc; v[6]=u1.z*sc; v[7]=u1.w*sc;
            }
            split_store8(&Ah[row * APAD + c0 + g * 8], &Al[row * APAD + c0 + g * 8], v);
        }
    }
    f4v acc[8] = {};
    int w = tid >> 6, lane = tid & 63, m = lane & 15, quad = lane >> 4;
    for (int kc = 0; kc < 4; ++kc) {
        __syncthreads();
        #pragma unroll
        for (int t2 = 0; t2 < 2; ++t2) {
            int task = tid + t2 * 256;
            int n = task & 127, kg = task >> 7;
            float v[8];
            if (!trans) {
                #pragma unroll
                for (int j = 0; j < 8; ++j)
                    v[j] = W[(size_t)(kc * 32 + kg * 8 + j) * 128 + n];
            } else {
                const float* wr = W + (size_t)n * 128 + kc * 32 + kg * 8;
                float4 u0 = *(const float4*)wr, u1 = *(const float4*)(wr + 4);
                v[0]=u0.x; v[1]=u0.y; v[2]=u0.z; v[3]=u0.w;
                v[4]=u1.x; v[5]=u1.y; v[6]=u1.z; v[7]=u1.w;
            }
            split_store8(&Bh[n * BPAD + kg * 8], &Bl[n * BPAD + kg * 8], v);
        }
        __syncthreads();
        s8v ah = *(const s8v*)&Ah[(w * 16 + m) * APAD + kc * 32 + quad * 8];
        s8v al = *(const s8v*)&Al[(w * 16 + m) * APAD + kc * 32 + quad * 8];
        #pragma unroll
        for (int nt = 0; nt < 8; ++nt) {
            s8v bh = *(const s8v*)&Bh[(nt * 16 + m) * BPAD + quad * 8];
            s8v bl = *(const s8v*)&Bl[(nt * 16 + m) * BPAD + quad * 8];
            acc[nt] = __builtin_amdgcn_mfma_f32_16x16x32_bf16(ah, bh, acc[nt], 0, 0, 0);
            acc[nt] = __builtin_amdgcn_mfma_f32_16x16x32_bf16(al, bh, acc[nt], 0, 0, 0);
            acc[nt] = __builtin_amdgcn_mfma_f32_16x16x32_bf16(ah, bl, acc[nt], 0, 0, 0);
        }
    }
    float bv[8];
    #pragma unroll
    for (int nt = 0; nt < 8; ++nt) bv[nt] = bias ? bias[nt * 16 + m] : 0.f;
    #pragma unroll
    for (int rr = 0; rr < 4; ++rr) {
        int gr = row0 + w * 16 + quad * 4 + rr;
        if (gr < M) {
            #pragma unroll
            for (int nt = 0; nt < 8; ++nt)
                C[(size_t)gr * 128 + nt * 16 + m] = acc[nt][rr] + bv[nt];
        }
    }
}

// ---------------------------------------------------------------- fused e[row] = tanh(A@W)[row,:] . bvec  (MFMA)
__global__ __launch_bounds__(256) void k_mfma_tanh_dot(
    const float* __restrict__ A, const float* __restrict__ W,
    const float* __restrict__ bvec, float* __restrict__ e, int M)
{
    __shared__ __align__(16) ushortT Ah[64 * APAD], Al[64 * APAD];
    __shared__ __align__(16) ushortT Bh[128 * BPAD], Bl[128 * BPAD];
    int tid = threadIdx.x;
    int row0 = blockIdx.x * 64;
    {
        int row = tid >> 2, c0 = (tid & 3) * 32;
        int gr = row0 + row;
        const float* ar = A + (size_t)gr * 128 + c0;
        #pragma unroll
        for (int g = 0; g < 4; ++g) {
            float v[8] = {};
            if (gr < M) {
                float4 u0 = *(const float4*)(ar + g * 8);
                float4 u1 = *(const float4*)(ar + g * 8 + 4);
                v[0]=u0.x; v[1]=u0.y; v[2]=u0.z; v[3]=u0.w;
                v[4]=u1.x; v[5]=u1.y; v[6]=u1.z; v[7]=u1.w;
            }
            split_store8(&Ah[row * APAD + c0 + g * 8], &Al[row * APAD + c0 + g * 8], v);
        }
    }
    f4v acc[8] = {};
    int w = tid >> 6, lane = tid & 63, m = lane & 15, quad = lane >> 4;
    for (int kc = 0; kc < 4; ++kc) {
        __syncthreads();
        #pragma unroll
        for (int t2 = 0; t2 < 2; ++t2) {
            int task = tid + t2 * 256;
            int n = task & 127, kg = task >> 7;
            float v[8];
            #pragma unroll
            for (int j = 0; j < 8; ++j)
                v[j] = W[(size_t)(kc * 32 + kg * 8 + j) * 128 + n];
            split_store8(&Bh[n * BPAD + kg * 8], &Bl[n * BPAD + kg * 8], v);
        }
        __syncthreads();
        s8v ah = *(const s8v*)&Ah[(w * 16 + m) * APAD + kc * 32 + quad * 8];
        s8v al = *(const s8v*)&Al[(w * 16 + m) * APAD + kc * 32 + quad * 8];
        #pragma unroll
        for (int nt = 0; nt < 8; ++nt) {
            s8v bh = *(const s8v*)&Bh[(nt * 16 + m) * BPAD + quad * 8];
            s8v bl = *(const s8v*)&Bl[(nt * 16 + m) * BPAD + quad * 8];
            acc[nt] = __builtin_amdgcn_mfma_f32_16x16x32_bf16(ah, bh, acc[nt], 0, 0, 0);
            acc[nt] = __builtin_amdgcn_mfma_f32_16x16x32_bf16(al, bh, acc[nt], 0, 0, 0);
            acc[nt] = __builtin_amdgcn_mfma_f32_16x16x32_bf16(ah, bl, acc[nt], 0, 0, 0);
        }
    }
    // epilogue: p[rr] = sum_nt tanh(acc[nt][rr]) * bvec[nt*16+m]; reduce over 16 m-lanes
    float bv[8];
    #pragma unroll
    for (int nt = 0; nt < 8; ++nt) bv[nt] = bvec[nt * 16 + m];
    #pragma unroll
    for (int rr = 0; rr < 4; ++rr) {
        float p = 0.f;
        #pragma unroll
        for (int nt = 0; nt < 8; ++nt) p += tanhf(acc[nt][rr]) * bv[nt];
        #pragma unroll
        for (int o = 1; o < 16; o <<= 1) p += __shfl_xor(p, o);
        int gr = row0 + w * 16 + quad * 4 + rr;
        if (m == 0 && gr < M) e[gr] = p;
    }
}

// ---------------------------------------------------------------- softmax(e) weighted sum of h rows
template <int L>
__global__ __launch_bounds__(128) void k_pool_apply(const float* __restrict__ h,
                                                    const float* __restrict__ e,
                                                    float* __restrict__ out)
{
    __shared__ float es[L];
    int b = blockIdx.x, tid = threadIdx.x;
    if (tid < L) es[tid] = e[b * L + tid];
    __syncthreads();
    float mx = -1e30f;
    #pragma unroll
    for (int l = 0; l < L; ++l) mx = fmaxf(mx, es[l]);
    float wgt[L];
    float sum = 0.f;
    #pragma unroll
    for (int l = 0; l < L; ++l) { wgt[l] = __expf(es[l] - mx); sum += wgt[l]; }
    float inv = 1.0f / sum;
    float o = 0.f;
    #pragma unroll
    for (int l = 0; l < L; ++l) o += wgt[l] * h[((size_t)b * L + l) * 128 + tid];
    out[(size_t)b * 128 + tid] = o * inv;
}

__global__ void k_build_ucat(const float* __restrict__ ctx, const float* __restrict__ his,
                             float* ucat)
{
    int i = blockIdx.x * blockDim.x + threadIdx.x;
    if (i >= DB * 33 * 128) return;
    int d = i & 127, l = (i >> 7) % 33, b = i / (33 * 128);
    ucat[i] = (l < 32) ? ctx[((size_t)b * 32 + l) * 128 + d] : his[(size_t)b * 128 + d];
}

// ---------------------------------------------------------------- RGCN fused segment-mean @ w[r] -> kg += (MFMA)
__global__ __launch_bounds__(256) void k_mfma_rgcn(
    const float* __restrict__ x, const float* __restrict__ wmat,
    const int* __restrict__ seglist, const int* __restrict__ soff,
    const int* __restrict__ slen, const int* __restrict__ ssrc,
    const int* __restrict__ stypebase, float* __restrict__ kg, int r)
{
    __shared__ __align__(16) ushortT Ah[64 * APAD], Al[64 * APAD];
    __shared__ __align__(16) ushortT Bh[128 * BPAD], Bl[128 * BPAD];
    int s0 = stypebase[r], s1 = stypebase[r + 1];
    int base = s0 + blockIdx.x * 64;
    if (base >= s1) return;
    int nrow = min(64, s1 - base);
    int tid = threadIdx.x;
    {
        int row = tid >> 2, c0 = (tid & 3) * 32;
        float a[32] = {};
        if (row < nrow) {
            int key = seglist[base + row];
            int st = soff[key], len = slen[key];
            for (int i = 0; i < len; ++i) {
                const float* xr = x + (size_t)ssrc[st + i] * 128 + c0;
                #pragma unroll
                for (int j = 0; j < 8; ++j) {
                    float4 v = *(const float4*)(xr + j * 4);
                    a[j*4+0] += v.x; a[j*4+1] += v.y; a[j*4+2] += v.z; a[j*4+3] += v.w;
                }
            }
            float inv = 1.0f / (float)max(len, 1);
            #pragma unroll
            for (int j = 0; j < 32; ++j) a[j] *= inv;
        }
        #pragma unroll
        for (int g = 0; g < 4; ++g)
            split_store8(&Ah[row * APAD + c0 + g * 8], &Al[row * APAD + c0 + g * 8], a + g * 8);
    }
    f4v acc[8] = {};
    int w = tid >> 6, lane = tid & 63, m = lane & 15, quad = lane >> 4;
    for (int kc = 0; kc < 4; ++kc) {
        __syncthreads();
        #pragma unroll
        for (int t2 = 0; t2 < 2; ++t2) {
            int task = tid + t2 * 256;
            int n = task & 127, kg2 = task >> 7;
            float v[8];
            #pragma unroll
            for (int j = 0; j < 8; ++j)
                v[j] = wmat[(size_t)(kc * 32 + kg2 * 8 + j) * 128 + n];
            split_store8(&Bh[n * BPAD + kg2 * 8], &Bl[n * BPAD + kg2 * 8], v);
        }
        __syncthreads();
        s8v ah = *(const s8v*)&Ah[(w * 16 + m) * APAD + kc * 32 + quad * 8];
        s8v al = *(const s8v*)&Al[(w * 16 + m) * APAD + kc * 32 + quad * 8];
        #pragma unroll
        for (int nt = 0; nt < 8; ++nt) {
            s8v bh = *(const s8v*)&Bh[(nt * 16 + m) * BPAD + quad * 8];
            s8v bl = *(const s8v*)&Bl[(nt * 16 + m) * BPAD + quad * 8];
            acc[nt] = __builtin_amdgcn_mfma_f32_16x16x32_bf16(ah, bh, acc[nt], 0, 0, 0);
            acc[nt] = __builtin_amdgcn_mfma_f32_16x16x32_bf16(al, bh, acc[nt], 0, 0, 0);
            acc[nt] = __builtin_amdgcn_mfma_f32_16x16x32_bf16(ah, bl, acc[nt], 0, 0, 0);
        }
    }
    #pragma unroll
    for (int rr = 0; rr < 4; ++rr) {
        int rt = w * 16 + quad * 4 + rr;
        if (rt < nrow) {
            int dst = seglist[base + rt] - r * DN;
            float* kr = kg + (size_t)dst * 128 + m;
            #pragma unroll
            for (int nt = 0; nt < 8; ++nt)
                kr[nt * 16] += acc[nt][rr];
        }
    }
}

// ---------------------------------------------------------------- scoring (MFMA)
__global__ __launch_bounds__(256) void k_score_mfma(
    const float* __restrict__ kg, const float* __restrict__ user,
    const float* __restrict__ rb, float* __restrict__ out)
{
    __shared__ __align__(16) ushortT Ah[64 * APAD], Al[64 * APAD];
    __shared__ __align__(16) ushortT Bh[64 * APAD], Bl[64 * APAD];
    int tid = threadIdx.x;
    int n0 = blockIdx.x * 64;
    {
        int row = tid >> 2, c0 = (tid & 3) * 32;
        int gr = n0 + row;
        const float* ar = kg + (size_t)gr * 128 + c0;
        const float* ur = user + (size_t)row * 128 + c0;
        #pragma unroll
        for (int g = 0; g < 4; ++g) {
            float v[8] = {};
            if (gr < DN) {
                float4 u0 = *(const float4*)(ar + g * 8);
                float4 u1 = *(const float4*)(ar + g * 8 + 4);
                v[0]=u0.x; v[1]=u0.y; v[2]=u0.z; v[3]=u0.w;
                v[4]=u1.x; v[5]=u1.y; v[6]=u1.z; v[7]=u1.w;
            }
            split_store8(&Ah[row * APAD + c0 + g * 8], &Al[row * APAD + c0 + g * 8], v);
            float u[8];
            float4 w0 = *(const float4*)(ur + g * 8);
            float4 w1 = *(const float4*)(ur + g * 8 + 4);
            u[0]=w0.x; u[1]=w0.y; u[2]=w0.z; u[3]=w0.w;
            u[4]=w1.x; u[5]=w1.y; u[6]=w1.z; u[7]=w1.w;
            split_store8(&Bh[row * APAD + c0 + g * 8], &Bl[row * APAD + c0 + g * 8], u);
        }
    }
    __syncthreads();
    f4v acc[4] = {};
    int w = tid >> 6, lane = tid & 63, m = lane & 15, quad = lane >> 4;
    #pragma unroll
    for (int kc = 0; kc < 4; ++kc) {
        s8v ah = *(const s8v*)&Ah[(w * 16 + m) * APAD + kc * 32 + quad * 8];
        s8v al = *(const s8v*)&Al[(w * 16 + m) * APAD + kc * 32 + quad * 8];
        #pragma unroll
        for (int nt = 0; nt < 4; ++nt) {
            s8v bh = *(const s8v*)&Bh[(nt * 16 + m) * APAD + kc * 32 + quad * 8];
            s8v bl = *(const s8v*)&Bl[(nt * 16 + m) * APAD + kc * 32 + quad * 8];
            acc[nt] = __builtin_amdgcn_mfma_f32_16x16x32_bf16(ah, bh, acc[nt], 0, 0, 0);
            acc[nt] = __builtin_amdgcn_mfma_f32_16x16x32_bf16(al, bh, acc[nt], 0, 0, 0);
            acc[nt] = __builtin_amdgcn_mfma_f32_16x16x32_bf16(ah, bl, acc[nt], 0, 0, 0);
        }
    }
    int n = n0 + w * 16 + quad * 4;
    if (n < DN) {
        float4 rbv = *(const float4*)&rb[n];
        #pragma unroll
        for (int nt = 0; nt < 4; ++nt) {
            int b = nt * 16 + m;
            float4 o = make_float4(acc[nt][0] + rbv.x, acc[nt][1] + rbv.y,
                                   acc[nt][2] + rbv.z, acc[nt][3] + rbv.w);
            *(float4*)&out[(size_t)b * DN + n] = o;
        }
    }
}

// ---------------------------------------------------------------- scans (single-mode, for hyper)
__global__ void k_scan_pass1(const int* __restrict__ in, int n, int* __restrict__ bsum)
{
    __shared__ int red[256];
    int b = blockIdx.x, t = threadIdx.x;
    int i0 = b * SCAN_CHUNK + t * 4;
    int s = 0;
    #pragma unroll
    for (int j = 0; j < 4; ++j) {
        int i = i0 + j;
        if (i < n) s += in[i];
    }
    red[t] = s;
    __syncthreads();
    for (int o = 128; o > 0; o >>= 1) {
        if (t < o) red[t] += red[t + o];
        __syncthreads();
    }
    if (t == 0) bsum[b] = red[0];
}

__global__ __launch_bounds__(256) void k_scan_pass2p(int* bsum, int nb, int* total)
{
    __shared__ int lds[256];
    __shared__ int carry;
    int t = threadIdx.x;
    if (t == 0) carry = 0;
    __syncthreads();
    for (int c0 = 0; c0 < nb; c0 += 256) {
        int i = c0 + t;
        int v = (i < nb) ? bsum[i] : 0;
        lds[t] = v;
        __syncthreads();
        for (int o = 1; o < 256; o <<= 1) {
            int add = (t >= o) ? lds[t - o] : 0;
            __syncthreads();
            lds[t] += add;
            __syncthreads();
        }
        int myc = carry;
        if (i < nb) bsum[i] = lds[t] - v + myc;
        int tot = lds[255];
        __syncthreads();
        if (t == 0) carry = myc + tot;
        __syncthreads();
    }
    if (total && t == 0) *total = carry;
}

__global__ void k_scan_pass3(const int* __restrict__ in, int n, const int* __restrict__ bsum,
                             int* __restrict__ out)
{
    __shared__ int lds[256];
    int b = blockIdx.x, t = threadIdx.x;
    int i0 = b * SCAN_CHUNK + t * 4;
    int v[4]; int s = 0;
    #pragma unroll
    for (int j = 0; j < 4; ++j) {
        int i = i0 + j;
        int x = 0;
        if (i < n) x = in[i];
        v[j] = x; s += x;
    }
    lds[t] = s;
    __syncthreads();
    for (int o = 1; o < 256; o <<= 1) {
        int add = (t >= o) ? lds[t - o] : 0;
        __syncthreads();
        lds[t] += add;
        __syncthreads();
    }
    int run = lds[t] - s + bsum[b];
    #pragma unroll
    for (int j = 0; j < 4; ++j) {
        int i = i0 + j;
        if (i < n) { out[i] = run; run += v[j]; }
    }
}

// ---------------------------------------------------------------- dual scan (value + predicate), for RGCN
__global__ void k_scan2_pass1(const int* __restrict__ in, int n, int* bV, int* bP)
{
    __shared__ int redV[256], redP[256];
    int b = blockIdx.x, t = threadIdx.x;
    int i0 = b * SCAN_CHUNK + t * 4;
    int sv = 0, sp = 0;
    #pragma unroll
    for (int j = 0; j < 4; ++j) {
        int i = i0 + j;
        if (i < n) { int v = in[i]; sv += v; sp += (v > 0); }
    }
    redV[t] = sv; redP[t] = sp;
    __syncthreads();
    for (int o = 128; o > 0; o >>= 1) {
        if (t < o) { redV[t] += redV[t + o]; redP[t] += redP[t + o]; }
        __syncthreads();
    }
    if (t == 0) { bV[b] = redV[0]; bP[b] = redP[0]; }
}

__global__ __launch_bounds__(256) void k_scan2_pass2(int* bV, int* bP, int nb, int* totalP)
{
    __shared__ int lds[256];
    __shared__ int carry;
    int t = threadIdx.x;
    #pragma unroll 1
    for (int which = 0; which < 2; ++which) {
        int* bsum = which ? bP : bV;
        __syncthreads();
        if (t == 0) carry = 0;
        __syncthreads();
        for (int c0 = 0; c0 < nb; c0 += 256) {
            int i = c0 + t;
            int v = (i < nb) ? bsum[i] : 0;
            lds[t] = v;
            __syncthreads();
            for (int o = 1; o < 256; o <<= 1) {
                int add = (t >= o) ? lds[t - o] : 0;
                __syncthreads();
                lds[t] += add;
                __syncthreads();
            }
            int myc = carry;
            if (i < nb) bsum[i] = lds[t] - v + myc;
            int tot = lds[255];
            __syncthreads();
            if (t == 0) carry = myc + tot;
            __syncthreads();
        }
        if (which == 1 && totalP && t == 0) *totalP = carry;
    }
}

__global__ void k_scan2_pass3(const int* __restrict__ in, int n,
                              const int* __restrict__ bV, const int* __restrict__ bP,
                              int* __restrict__ outV, int* __restrict__ outP)
{
    __shared__ int ldsV[256], ldsP[256];
    int b = blockIdx.x, t = threadIdx.x;
    int i0 = b * SCAN_CHUNK + t * 4;
    int v[4]; int sv = 0, sp = 0;
    #pragma unroll
    for (int j = 0; j < 4; ++j) {
        int i = i0 + j;
        int x = 0;
        if (i < n) x = in[i];
        v[j] = x; sv += x; sp += (x > 0);
    }
    ldsV[t] = sv; ldsP[t] = sp;
    __syncthreads();
    for (int o = 1; o < 256; o <<= 1) {
        int addV = (t >= o) ? ldsV[t - o] : 0;
        int addP = (t >= o) ? ldsP[t - o] : 0;
        __syncthreads();
        ldsV[t] += addV; ldsP[t] += addP;
        __syncthreads();
    }
    int runV = ldsV[t] - sv + bV[b];
    int runP = ldsP[t] - sp + bP[b];
    #pragma unroll
    for (int j = 0; j < 4; ++j) {
        int i = i0 + j;
        if (i < n) {
            outV[i] = runV; outP[i] = runP;
            runV += v[j]; runP += (v[j] > 0);
        }
    }
}

// ---------------------------------------------------------------- RGCN sort
__global__ void k_hist_rgcn(const int* __restrict__ dst, const int* __restrict__ et,
                            int* hist, int E)
{
    int i = blockIdx.x * blockDim.x + threadIdx.x;
    if (i < E) atomicAdd(&hist[(size_t)et[i] * DN + dst[i]], 1);
}

__global__ void k_seglist(const int* __restrict__ hist, const int* __restrict__ segpos,
                          int* __restrict__ seglist, int n)
{
    int i = blockIdx.x * blockDim.x + threadIdx.x;
    if (i < n && hist[i] > 0) seglist[segpos[i]] = i;
}

__global__ void k_stypebase(const int* __restrict__ segpos, int* stypebase)
{
    int t = threadIdx.x;
    if (t < DR) stypebase[t] = segpos[(size_t)t * DN];
}

__global__ void k_bucket_rgcn(const int* __restrict__ src, const int* __restrict__ dst,
                              const int* __restrict__ et, const int* __restrict__ off,
                              int* cur, int* ssrc, int E)
{
    int i = blockIdx.x * blockDim.x + threadIdx.x;
    if (i >= E) return;
    int key = et[i] * DN + dst[i];
    int pos = off[key] + atomicAdd(&cur[key], 1);
    ssrc[pos] = src[i];
}

__global__ void k_wcomp(const float* __restrict__ comp, const float* __restrict__ bases,
                        float* __restrict__ w_all)
{
    int i = blockIdx.x * blockDim.x + threadIdx.x;
    if (i >= DR * DD * DD) return;
    int r = i / (DD * DD), io = i % (DD * DD);
    float s = 0.f;
    #pragma unroll
    for (int b = 0; b < DNB; ++b) s += comp[r * DNB + b] * bases[(size_t)b * DD * DD + io];
    w_all[i] = s;
}

// ---------------------------------------------------------------- hypergraph (both sides combined, 40000 bins)
__global__ void k_hist_p2(const int* __restrict__ se, const int* __restrict__ ke, int* hist)
{
    int i = blockIdx.x * blockDim.x + threadIdx.x;
    if (i < DP) atomicAdd(&hist[se[i]], 1);
    else if (i < 2 * DP) atomicAdd(&hist[DHE + ke[i - DP]], 1);
}

__global__ void k_bucket_p2(const int* __restrict__ sn, const int* __restrict__ se,
                            const int* __restrict__ kn, const int* __restrict__ ke,
                            const int* __restrict__ off, int* cur, int* pns)
{
    int i = blockIdx.x * blockDim.x + threadIdx.x;
    if (i >= 2 * DP) return;
    int e, node;
    if (i < DP) { e = se[i]; node = sn[i]; }
    else { e = DHE + ke[i - DP]; node = kn[i - DP]; }
    int pos = off[e] + atomicAdd(&cur[e], 1);
    pns[pos] = node;
}

// one wave per hyperedge (global 0..40000): efeat[he] = mean of kg[node]
__global__ void k_hyper_agg(const float* __restrict__ xsrc, const int* __restrict__ pns,
                            const int* __restrict__ hoff, const int* __restrict__ hcnt,
                            float* __restrict__ efeat)
{
    int lane = threadIdx.x & 63;
    int he = (blockIdx.x * blockDim.x + threadIdx.x) >> 6;
    if (he >= DHE2) return;
    int st = hoff[he], len = hcnt[he];
    float2 acc = make_float2(0.f, 0.f);
    for (int c = 0; c < len; c += 64) {
        int m = min(64, len - c);
        int nid = (c + lane < len) ? pns[st + c + lane] : 0;
        for (int j = 0; j < m; ++j) {
            int node = __shfl(nid, j);
            float2 v = *(const float2*)&xsrc[(size_t)node * 128 + lane * 2];
            acc.x += v.x; acc.y += v.y;
        }
    }
    float inv = (len > 0) ? 1.0f / (float)len : 0.f;
    acc.x *= inv; acc.y *= inv;
    *(float2*)&efeat[(size_t)he * 128 + lane * 2] = acc;
}

__global__ void k_slot_assign2(const int* __restrict__ sidx, const int* __restrict__ kidx,
                               int* slot_s, int* slot_k, int* scnt)
{
    int i = blockIdx.x * blockDim.x + threadIdx.x;
    if (i < DB * DLR) {
        int node = sidx[i];
        if (atomicCAS(&slot_s[node], -1, -2) == -1) slot_s[node] = atomicAdd(&scnt[0], 1);
    } else if (i < 2 * DB * DLR) {
        int node = kidx[i - DB * DLR];
        if (atomicCAS(&slot_k[node], -1, -2) == -1) slot_k[node] = atomicAdd(&scnt[1], 1);
    }
}

// fused sdeg + match with block-aggregated compaction (one global atomic per block)
__global__ __launch_bounds__(256) void k_sdeg_match(
    const int* __restrict__ nodes, const int* __restrict__ he, const int* __restrict__ slot,
    float* sdeg, int* mcnt, int* mhe, int* msl, int heBase)
{
    __shared__ int lcnt, lbase;
    if (threadIdx.x == 0) lcnt = 0;
    __syncthreads();
    int i = blockIdx.x * 256 + threadIdx.x;
    int s = -1, lidx = 0;
    if (i < DP) {
        s = slot[nodes[i]];
        if (s >= 0) {
            atomicAdd(&sdeg[s], 1.0f);
            lidx = atomicAdd(&lcnt, 1);
        }
    }
    __syncthreads();
    if (threadIdx.x == 0) lbase = (lcnt > 0) ? atomicAdd(mcnt, lcnt) : 0;
    __syncthreads();
    if (s >= 0) {
        int idx = lbase + lidx;
        if (idx < MCAP) { mhe[idx] = heBase + he[i]; msl[idx] = s; }
    }
}

__global__ void k_accmatch(const float* __restrict__ efeat, const int* __restrict__ mhe,
                           const int* __restrict__ msl, const int* __restrict__ mcnt,
                           float* sacc)
{
    int lane = threadIdx.x & 63;
    int w = (blockIdx.x * blockDim.x + threadIdx.x) >> 6;
    int nw = (gridDim.x * blockDim.x) >> 6;
    int M = min(*mcnt, MCAP);
    for (int i = w; i < M; i += nw) {
        float2 v = *(const float2*)&efeat[(size_t)mhe[i] * 128 + lane * 2];
        atomicAdd(&sacc[(size_t)msl[i] * 128 + lane * 2],     v.x);
        atomicAdd(&sacc[(size_t)msl[i] * 128 + lane * 2 + 1], v.y);
    }
}

__global__ void k_rel_gather(const float* __restrict__ slotout, const int* __restrict__ slot,
                             const int* __restrict__ rel_idx, float* __restrict__ related,
                             int colOff)
{
    int gid = blockIdx.x * blockDim.x + threadIdx.x;
    int i = gid >> 5, c = gid & 31;
    if (i >= DB * DLR) return;
    int s = slot[rel_idx[i]];
    int b = i / DLR, l = i % DLR;
    ((float4*)&related[((size_t)b * 128 + colOff + l) * 128])[c] =
        ((const float4*)&slotout[(size_t)s * 128])[c];
}

// ---------------------------------------------------------------- gathers / misc
__global__ void k_gather_rows(const float* __restrict__ src, const int* __restrict__ idx,
                              float* dst, int nRows)
{
    int i = blockIdx.x * blockDim.x + threadIdx.x;
    if (i >= nRows * 128) return;
    int row = i >> 7, d = i & 127;
    dst[i] = src[(size_t)idx[row] * 128 + d];
}

// ---------------------------------------------------------------- MHA: one block per (b,h)
__global__ __launch_bounds__(256) void k_mha(const float* __restrict__ qb,
                                             const float* __restrict__ kb,
                                             const float* __restrict__ vb,
                                             float* __restrict__ ob)
{
    int b = blockIdx.x >> 3, h = blockIdx.x & 7;
    __shared__ float Ks[128][16], Vs[128][16], Qs[32][16];
    int tid = threadIdx.x;
    for (int i = tid; i < 128 * 16; i += 256) {
        int j = i >> 4, d = i & 15;
        Ks[j][d] = kb[((size_t)b * 128 + j) * 128 + h * 16 + d];
        Vs[j][d] = vb[((size_t)b * 128 + j) * 128 + h * 16 + d];
    }
    for (int i = tid; i < 32 * 16; i += 256) {
        int q = i >> 4, d = i & 15;
        Qs[q][d] = qb[((size_t)b * 32 + q) * 128 + h * 16 + d] * 0.25f;
    }
    __syncthreads();
    int q = tid >> 3;
    int jg = tid & 7;
    float lg[16];
    float m = -1e30f;
    #pragma unroll
    for (int jj = 0; jj < 16; ++jj) {
        int j = jg * 16 + jj;
        float s = 0.f;
        #pragma unroll
        for (int d = 0; d < 16; ++d) s += Qs[q][d] * Ks[j][d];
        lg[jj] = s;
        m = fmaxf(m, s);
    }
    #pragma unroll
    for (int o = 1; o < 8; o <<= 1) m = fmaxf(m, __shfl_xor(m, o));
    float sum = 0.f;
    float acc[16] = {};
    #pragma unroll
    for (int jj = 0; jj < 16; ++jj) {
        float p = __expf(lg[jj] - m);
        sum += p;
        int j = jg * 16 + jj;
        #pragma unroll
        for (int d = 0; d < 16; ++d) acc[d] += p * Vs[j][d];
    }
    #pragma unroll
    for (int o = 1; o < 8; o <<= 1) {
        sum += __shfl_xor(sum, o);
        #pragma unroll
        for (int d = 0; d < 16; ++d) acc[d] += __shfl_xor(acc[d], o);
    }
    if (jg == 0) {
        float inv = 1.0f / sum;
        #pragma unroll
        for (int d = 0; d < 16; ++d)
            ob[((size_t)b * 32 + q) * 128 + h * 16 + d] = acc[d] * inv;
    }
}

// ---------------------------------------------------------------- launch
extern "C" void kernel_launch(void* const* d_in, const int* in_sizes, int n_in,
                              void* d_out, int out_size, void* d_ws, size_t ws_size,
                              hipStream_t stream)
{
    const float* emb        = (const float*)d_in[0];
    const float* bases      = (const float*)d_in[1];
    const float* comp       = (const float*)d_in[2];
    const float* root       = (const float*)d_in[3];
    const float* rgcn_bias  = (const float*)d_in[4];
    const float* sess_theta = (const float*)d_in[5];
    const float* sess_bias  = (const float*)d_in[6];
    const float* know_theta = (const float*)d_in[7];
    const float* know_bias  = (const float*)d_in[8];
    const float* in_proj_w  = (const float*)d_in[9];
    const float* in_proj_b  = (const float*)d_in[10];
    const float* out_proj_w = (const float*)d_in[11];
    const float* out_proj_b = (const float*)d_in[12];
    const float* attn_his_a = (const float*)d_in[13];
    const float* attn_his_b = (const float*)d_in[14];
    const float* attn_a     = (const float*)d_in[15];
    const float* attn_b     = (const float*)d_in[16];
    const float* rec_bias   = (const float*)d_in[17];
    const int* edge_src     = (const int*)d_in[18];
    const int* edge_dst     = (const int*)d_in[19];
    const int* edge_type    = (const int*)d_in[20];
    const int* sess_nodes   = (const int*)d_in[21];
    const int* sess_edges   = (const int*)d_in[22];
    const int* know_nodes   = (const int*)d_in[23];
    const int* know_edges   = (const int*)d_in[24];
    const int* sess_rel_idx = (const int*)d_in[25];
    const int* know_rel_idx = (const int*)d_in[26];
    const int* context_idx  = (const int*)d_in[27];
    float* out = (float*)d_out;

    float* wsf = (float*)d_ws;
    size_t off = 0;
    auto alloc = [&](size_t n) { size_t r = off; off += (n + 255) & ~(size_t)255; return r; };
    float* kg      = wsf + alloc(12800000);          // N*D
    float* tmp     = wsf + alloc(12800000);          // RGCN sort arena + efeat tail
    float* w_all   = wsf + alloc(196608);
    int*   bsumV   = (int*)(wsf + alloc(2048));
    int*   bsumP   = (int*)(wsf + alloc(2048));
    int*   stybase = (int*)(wsf + alloc(16));
    // ---- contiguous zero block (one memset) ----
    size_t zstart = off;
    int*   hhist   = (int*)(wsf + alloc(DHE2));
    int*   hcur    = (int*)(wsf + alloc(DHE2));
    int*   mcnt    = (int*)(wsf + alloc(16));        // [0]=sess, [1]=know
    int*   scnt    = (int*)(wsf + alloc(16));
    float* sdeg_s  = wsf + alloc(4096);
    float* sdeg_k  = wsf + alloc(4096);
    float* sacc_s  = wsf + alloc(524288);
    float* sacc_k  = wsf + alloc(524288);
    size_t zend = off;
    // ---- contiguous 0xFF block (one memset) ----
    size_t fstart = off;
    int*   slot_s  = (int*)(wsf + alloc(100000));
    int*   slot_k  = (int*)(wsf + alloc(100000));
    size_t fend = off;
    int*   hoff    = (int*)(wsf + alloc(DHE2));
    int*   pns     = (int*)(wsf + alloc(2 * DP));
    int*   mhe_s   = (int*)(wsf + alloc(MCAP));
    int*   msl_s   = (int*)(wsf + alloc(MCAP));
    int*   mhe_k   = (int*)(wsf + alloc(MCAP));
    int*   msl_k   = (int*)(wsf + alloc(MCAP));
    float* slotout = wsf + alloc(524288);
    float* related = wsf + alloc(1048576);
    float* ctx     = wsf + alloc(262144);
    float* qb      = wsf + alloc(262144);
    float* kb      = wsf + alloc(1048576);
    float* vb      = wsf + alloc(1048576);
    float* obuf    = wsf + alloc(262144);
    float* attrel  = wsf + alloc(262144);
    float* his     = wsf + alloc(8192);
    float* ucat    = wsf + alloc(270336);
    float* userb   = wsf + alloc(8192);
    float* e1      = wsf + alloc(2048);
    float* e2      = wsf + alloc(2112);
    (void)ws_size; (void)in_sizes; (void)n_in; (void)out_size;

    // RGCN sort arena inside tmp; efeat (40000*128 = 5.12M) in the tail
    int*   hist    = (int*)tmp;                 // 1.2M
    int*   rcur    = (int*)tmp + 1200000;       // 1.2M (bucket cursor, pre-zeroed with hist)
    int*   soff    = (int*)tmp + 2400000;       // 1.2M
    int*   segpos  = (int*)tmp + 3600000;       // 1.2M
    int*   seglist = (int*)tmp + 4800000;       // 1.2M
    int*   ssrc    = (int*)tmp + 6000000;       // 1.0M
    float* efeat   = tmp + 7000000;             // 5.12M (used only after RGCN finishes)

    const int nbR = (NRBINS + SCAN_CHUNK - 1) / SCAN_CHUNK;   // 1172
    const int nbH = (DHE2 + SCAN_CHUNK - 1) / SCAN_CHUNK;     // 40

    // ---------------- upfront memsets (3 total)
    hipMemsetAsync(wsf + zstart, 0, (zend - zstart) * 4, stream);
    hipMemsetAsync(wsf + fstart, 0xFF, (fend - fstart) * 4, stream);
    hipMemsetAsync(hist, 0, 2400000 * 4, stream);   // hist + rcur

    k_slot_assign2<<<32, 256, 0, stream>>>(sess_rel_idx, know_rel_idx, slot_s, slot_k, scnt);

    // ---------------- RGCN: sort edges by (type, dst)
    k_hist_rgcn<<<(DE + 255) / 256, 256, 0, stream>>>(edge_dst, edge_type, hist, DE);
    k_scan2_pass1<<<nbR, 256, 0, stream>>>(hist, NRBINS, bsumV, bsumP);
    k_scan2_pass2<<<1, 256, 0, stream>>>(bsumV, bsumP, nbR, stybase + DR);
    k_scan2_pass3<<<nbR, 256, 0, stream>>>(hist, NRBINS, bsumV, bsumP, soff, segpos);
    k_stypebase<<<1, 64, 0, stream>>>(segpos, stybase);
    k_seglist<<<(NRBINS + 255) / 256, 256, 0, stream>>>(hist, segpos, seglist, NRBINS);
    k_bucket_rgcn<<<(DE + 255) / 256, 256, 0, stream>>>(edge_src, edge_dst, edge_type,
                                                        soff, rcur, ssrc, DE);
    k_wcomp<<<(DR * DD * DD + 255) / 256, 256, 0, stream>>>(comp, bases, w_all);

    int gemmN = (DN + 63) / 64;
    k_mfma_gemm<<<gemmN, 256, 0, stream>>>(emb, root, rgcn_bias, nullptr, kg, DN, 0);
    for (int r = 0; r < DR; ++r)
        k_mfma_rgcn<<<gemmN, 256, 0, stream>>>(emb, w_all + (size_t)r * DD * DD,
                                               seglist, soff, hist, ssrc, stybase, kg, r);

    // ---------------- hypergraph (both sides as one 40000-edge problem)
    k_hist_p2<<<(2 * DP + 255) / 256, 256, 0, stream>>>(sess_edges, know_edges, hhist);
    k_scan_pass1<<<nbH, 256, 0, stream>>>(hhist, DHE2, bsumV);
    k_scan_pass2p<<<1, 256, 0, stream>>>(bsumV, nbH, nullptr);
    k_scan_pass3<<<nbH, 256, 0, stream>>>(hhist, DHE2, bsumV, hoff);
    k_bucket_p2<<<(2 * DP + 255) / 256, 256, 0, stream>>>(sess_nodes, sess_edges,
                                                          know_nodes, know_edges,
                                                          hoff, hcur, pns);
    k_hyper_agg<<<(DHE2 * 64 + 255) / 256, 256, 0, stream>>>(kg, pns, hoff, hhist, efeat);

    k_sdeg_match<<<(DP + 255) / 256, 256, 0, stream>>>(sess_nodes, sess_edges, slot_s,
                                                       sdeg_s, mcnt, mhe_s, msl_s, 0);
    k_sdeg_match<<<(DP + 255) / 256, 256, 0, stream>>>(know_nodes, know_edges, slot_k,
                                                       sdeg_k, mcnt + 1, mhe_k, msl_k, DHE);
    k_accmatch<<<256, 256, 0, stream>>>(efeat, mhe_s, msl_s, mcnt, sacc_s);
    k_accmatch<<<256, 256, 0, stream>>>(efeat, mhe_k, msl_k, mcnt + 1, sacc_k);

    k_mfma_gemm<<<64, 256, 0, stream>>>(sacc_s, sess_theta, sess_bias, sdeg_s, slotout, 4096, 0);
    k_rel_gather<<<(DB * DLR * 32 + 255) / 256, 256, 0, stream>>>(slotout, slot_s, sess_rel_idx,
                                                                  related, 0);
    k_mfma_gemm<<<64, 256, 0, stream>>>(sacc_k, know_theta, know_bias, sdeg_k, slotout, 4096, 0);
    k_rel_gather<<<(DB * DLR * 32 + 255) / 256, 256, 0, stream>>>(slotout, slot_k, know_rel_idx,
                                                                  related, 64);

    // ---------------- context + MHA
    k_gather_rows<<<(DB * DLC * 128 + 255) / 256, 256, 0, stream>>>(kg, context_idx, ctx, DB * DLC);
    k_mfma_gemm<<<(DB * DLC + 63) / 64, 256, 0, stream>>>(ctx, in_proj_w, in_proj_b, nullptr,
                                                          qb, DB * DLC, 1);
    k_mfma_gemm<<<(DB * 128 + 63) / 64, 256, 0, stream>>>(related, in_proj_w + DD * DD,
                                                          in_proj_b + DD, nullptr, kb, DB * 128, 1);
    k_mfma_gemm<<<(DB * 128 + 63) / 64, 256, 0, stream>>>(related, in_proj_w + 2 * DD * DD,
                                                          in_proj_b + 2 * DD, nullptr, vb, DB * 128, 1);
    k_mha<<<DB * DNH, 256, 0, stream>>>(qb, kb, vb, obuf);
    k_mfma_gemm<<<(DB * DLC + 63) / 64, 256, 0, stream>>>(obuf, out_proj_w, out_proj_b, nullptr,
                                                          attrel, DB * DLC, 1);

    // ---------------- pooling (GEMM-shaped) + score
    k_mfma_tanh_dot<<<(DB * DLC + 63) / 64, 256, 0, stream>>>(attrel, attn_his_a, attn_his_b,
                                                              e1, DB * DLC);
    k_pool_apply<32><<<DB, 128, 0, stream>>>(attrel, e1, his);
    k_build_ucat<<<(DB * 33 * 128 + 255) / 256, 256, 0, stream>>>(ctx, his, ucat);
    k_mfma_tanh_dot<<<(DB * 33 + 63) / 64, 256, 0, stream>>>(ucat, attn_a, attn_b,
                                                             e2, DB * 33);
    k_pool_apply<33><<<DB, 128, 0, stream>>>(ucat, e2, userb);
    k_score_mfma<<<gemmN, 256, 0, stream>>>(kg, userb, rec_bias, out);
}

// Round 7
// 1075.826 us; speedup vs baseline: 2.8232x; 1.0270x over previous
//
#include <hip/hip_runtime.h>
#include <hip/hip_bf16.h>

#define DN 100000     // N entities
#define DD 128        // D
#define DR 12         // R relations
#define DNB 8         // bases
#define DE 1000000    // edges
#define DP 400000     // hyperedge incidences
#define DHE 20000     // hyperedges
#define DHE2 40000    // both sides combined
#define DB 64         // batch
#define DLR 64
#define DLC 32
#define DNH 8
#define DHD 16
#define NRBINS (DR * DN)   // 1.2M
#define SCAN_CHUNK 1024
#define MCAP 65536

typedef unsigned short ushortT;
typedef unsigned int uintT;
typedef __attribute__((ext_vector_type(8))) short s8v;
typedef __attribute__((ext_vector_type(4))) float f4v;

#define APAD 136   // 64 rows of K=128 bf16, stride 272B
#define BPAD 40    // 128 rows of K=32 bf16, stride 80B

__device__ __forceinline__ ushortT rneb(float v) {
    uintT b = __float_as_uint(v);
    return (ushortT)((b + 0x7FFFu + ((b >> 16) & 1u)) >> 16);
}
__device__ __forceinline__ float b2f(ushortT h) {
    return __uint_as_float(((uintT)h) << 16);
}

__device__ __forceinline__ void split_store8(ushortT* hbase, ushortT* lbase, const float* v)
{
    ushortT h[8], l[8];
    #pragma unroll
    for (int j = 0; j < 8; ++j) {
        h[j] = rneb(v[j]);
        l[j] = rneb(v[j] - b2f(h[j]));
    }
    uint4 hv = make_uint4((uintT)h[0] | ((uintT)h[1] << 16), (uintT)h[2] | ((uintT)h[3] << 16),
                          (uintT)h[4] | ((uintT)h[5] << 16), (uintT)h[6] | ((uintT)h[7] << 16));
    uint4 lv = make_uint4((uintT)l[0] | ((uintT)l[1] << 16), (uintT)l[2] | ((uintT)l[3] << 16),
                          (uintT)l[4] | ((uintT)l[5] << 16), (uintT)l[6] | ((uintT)l[7] << 16));
    *(uint4*)hbase = hv;
    *(uint4*)lbase = lv;
}

// ---------------------------------------------------------------- MFMA GEMM (split-bf16, ~fp32 accuracy)
__global__ __launch_bounds__(256) void k_mfma_gemm(
    const float* __restrict__ A, const float* __restrict__ W,
    const float* __restrict__ bias, const float* __restrict__ rs,
    float* __restrict__ C, int M, int trans)
{
    __shared__ __align__(16) ushortT Ah[64 * APAD], Al[64 * APAD];
    __shared__ __align__(16) ushortT Bh[128 * BPAD], Bl[128 * BPAD];
    int tid = threadIdx.x;
    int row0 = blockIdx.x * 64;
    {
        int row = tid >> 2, c0 = (tid & 3) * 32;
        int gr = row0 + row;
        const float* ar = A + (size_t)gr * 128 + c0;
        float sc = 1.0f;
        if (rs && gr < M) { float d = rs[gr]; sc = (d > 0.f) ? 1.0f / d : 0.f; }
        #pragma unroll
        for (int g = 0; g < 4; ++g) {
            float v[8] = {};
            if (gr < M) {
                float4 u0 = *(const float4*)(ar + g * 8);
                float4 u1 = *(const float4*)(ar + g * 8 + 4);
                v[0]=u0.x*sc; v[1]=u0.y*sc; v[2]=u0.z*sc; v[3]=u0.w*sc;
                v[4]=u1.x*sc; v[5]=u1.y*sc; v[6]=u1.z*sc; v[7]=u1.w*sc;
            }
            split_store8(&Ah[row * APAD + c0 + g * 8], &Al[row * APAD + c0 + g * 8], v);
        }
    }
    f4v acc[8] = {};
    int w = tid >> 6, lane = tid & 63, m = lane & 15, quad = lane >> 4;
    for (int kc = 0; kc < 4; ++kc) {
        __syncthreads();
        #pragma unroll
        for (int t2 = 0; t2 < 2; ++t2) {
            int task = tid + t2 * 256;
            int n = task & 127, kg = task >> 7;
            float v[8];
            if (!trans) {
                #pragma unroll
                for (int j = 0; j < 8; ++j)
                    v[j] = W[(size_t)(kc * 32 + kg * 8 + j) * 128 + n];
            } else {
                const float* wr = W + (size_t)n * 128 + kc * 32 + kg * 8;
                float4 u0 = *(const float4*)wr, u1 = *(const float4*)(wr + 4);
                v[0]=u0.x; v[1]=u0.y; v[2]=u0.z; v[3]=u0.w;
                v[4]=u1.x; v[5]=u1.y; v[6]=u1.z; v[7]=u1.w;
            }
            split_store8(&Bh[n * BPAD + kg * 8], &Bl[n * BPAD + kg * 8], v);
        }
        __syncthreads();
        s8v ah = *(const s8v*)&Ah[(w * 16 + m) * APAD + kc * 32 + quad * 8];
        s8v al = *(const s8v*)&Al[(w * 16 + m) * APAD + kc * 32 + quad * 8];
        #pragma unroll
        for (int nt = 0; nt < 8; ++nt) {
            s8v bh = *(const s8v*)&Bh[(nt * 16 + m) * BPAD + quad * 8];
            s8v bl = *(const s8v*)&Bl[(nt * 16 + m) * BPAD + quad * 8];
            acc[nt] = __builtin_amdgcn_mfma_f32_16x16x32_bf16(ah, bh, acc[nt], 0, 0, 0);
            acc[nt] = __builtin_amdgcn_mfma_f32_16x16x32_bf16(al, bh, acc[nt], 0, 0, 0);
            acc[nt] = __builtin_amdgcn_mfma_f32_16x16x32_bf16(ah, bl, acc[nt], 0, 0, 0);
        }
    }
    float bv[8];
    #pragma unroll
    for (int nt = 0; nt < 8; ++nt) bv[nt] = bias ? bias[nt * 16 + m] : 0.f;
    #pragma unroll
    for (int rr = 0; rr < 4; ++rr) {
        int gr = row0 + w * 16 + quad * 4 + rr;
        if (gr < M) {
            #pragma unroll
            for (int nt = 0; nt < 8; ++nt)
                C[(size_t)gr * 128 + nt * 16 + m] = acc[nt][rr] + bv[nt];
        }
    }
}

// ---------------------------------------------------------------- fused e[row] = tanh(A@W)[row,:] . bvec  (MFMA)
__global__ __launch_bounds__(256) void k_mfma_tanh_dot(
    const float* __restrict__ A, const float* __restrict__ W,
    const float* __restrict__ bvec, float* __restrict__ e, int M)
{
    __shared__ __align__(16) ushortT Ah[64 * APAD], Al[64 * APAD];
    __shared__ __align__(16) ushortT Bh[128 * BPAD], Bl[128 * BPAD];
    int tid = threadIdx.x;
    int row0 = blockIdx.x * 64;
    {
        int row = tid >> 2, c0 = (tid & 3) * 32;
        int gr = row0 + row;
        const float* ar = A + (size_t)gr * 128 + c0;
        #pragma unroll
        for (int g = 0; g < 4; ++g) {
            float v[8] = {};
            if (gr < M) {
                float4 u0 = *(const float4*)(ar + g * 8);
                float4 u1 = *(const float4*)(ar + g * 8 + 4);
                v[0]=u0.x; v[1]=u0.y; v[2]=u0.z; v[3]=u0.w;
                v[4]=u1.x; v[5]=u1.y; v[6]=u1.z; v[7]=u1.w;
            }
            split_store8(&Ah[row * APAD + c0 + g * 8], &Al[row * APAD + c0 + g * 8], v);
        }
    }
    f4v acc[8] = {};
    int w = tid >> 6, lane = tid & 63, m = lane & 15, quad = lane >> 4;
    for (int kc = 0; kc < 4; ++kc) {
        __syncthreads();
        #pragma unroll
        for (int t2 = 0; t2 < 2; ++t2) {
            int task = tid + t2 * 256;
            int n = task & 127, kg = task >> 7;
            float v[8];
            #pragma unroll
            for (int j = 0; j < 8; ++j)
                v[j] = W[(size_t)(kc * 32 + kg * 8 + j) * 128 + n];
            split_store8(&Bh[n * BPAD + kg * 8], &Bl[n * BPAD + kg * 8], v);
        }
        __syncthreads();
        s8v ah = *(const s8v*)&Ah[(w * 16 + m) * APAD + kc * 32 + quad * 8];
        s8v al = *(const s8v*)&Al[(w * 16 + m) * APAD + kc * 32 + quad * 8];
        #pragma unroll
        for (int nt = 0; nt < 8; ++nt) {
            s8v bh = *(const s8v*)&Bh[(nt * 16 + m) * BPAD + quad * 8];
            s8v bl = *(const s8v*)&Bl[(nt * 16 + m) * BPAD + quad * 8];
            acc[nt] = __builtin_amdgcn_mfma_f32_16x16x32_bf16(ah, bh, acc[nt], 0, 0, 0);
            acc[nt] = __builtin_amdgcn_mfma_f32_16x16x32_bf16(al, bh, acc[nt], 0, 0, 0);
            acc[nt] = __builtin_amdgcn_mfma_f32_16x16x32_bf16(ah, bl, acc[nt], 0, 0, 0);
        }
    }
    float bv[8];
    #pragma unroll
    for (int nt = 0; nt < 8; ++nt) bv[nt] = bvec[nt * 16 + m];
    #pragma unroll
    for (int rr = 0; rr < 4; ++rr) {
        float p = 0.f;
        #pragma unroll
        for (int nt = 0; nt < 8; ++nt) p += tanhf(acc[nt][rr]) * bv[nt];
        #pragma unroll
        for (int o = 1; o < 16; o <<= 1) p += __shfl_xor(p, o);
        int gr = row0 + w * 16 + quad * 4 + rr;
        if (m == 0 && gr < M) e[gr] = p;
    }
}

// ---------------------------------------------------------------- softmax(e) weighted sum of h rows
template <int L>
__global__ __launch_bounds__(128) void k_pool_apply(const float* __restrict__ h,
                                                    const float* __restrict__ e,
                                                    float* __restrict__ out)
{
    __shared__ float es[L];
    int b = blockIdx.x, tid = threadIdx.x;
    if (tid < L) es[tid] = e[b * L + tid];
    __syncthreads();
    float mx = -1e30f;
    #pragma unroll
    for (int l = 0; l < L; ++l) mx = fmaxf(mx, es[l]);
    float wgt[L];
    float sum = 0.f;
    #pragma unroll
    for (int l = 0; l < L; ++l) { wgt[l] = __expf(es[l] - mx); sum += wgt[l]; }
    float inv = 1.0f / sum;
    float o = 0.f;
    #pragma unroll
    for (int l = 0; l < L; ++l) o += wgt[l] * h[((size_t)b * L + l) * 128 + tid];
    out[(size_t)b * 128 + tid] = o * inv;
}

__global__ void k_build_ucat(const float* __restrict__ ctx, const float* __restrict__ his,
                             float* ucat)
{
    int i = blockIdx.x * blockDim.x + threadIdx.x;
    if (i >= DB * 33 * 128) return;
    int d = i & 127, l = (i >> 7) % 33, b = i / (33 * 128);
    ucat[i] = (l < 32) ? ctx[((size_t)b * 32 + l) * 128 + d] : his[(size_t)b * 128 + d];
}

// ---------------------------------------------------------------- RGCN fused segment-mean @ w[r] -> kg += (MFMA)
__global__ __launch_bounds__(256) void k_mfma_rgcn(
    const float* __restrict__ x, const float* __restrict__ wmat,
    const int* __restrict__ seglist, const int* __restrict__ soff,
    const int* __restrict__ slen, const int* __restrict__ ssrc,
    const int* __restrict__ stypebase, float* __restrict__ kg, int r)
{
    __shared__ __align__(16) ushortT Ah[64 * APAD], Al[64 * APAD];
    __shared__ __align__(16) ushortT Bh[128 * BPAD], Bl[128 * BPAD];
    int s0 = stypebase[r], s1 = stypebase[r + 1];
    int base = s0 + blockIdx.x * 64;
    if (base >= s1) return;
    int nrow = min(64, s1 - base);
    int tid = threadIdx.x;
    {
        int row = tid >> 2, c0 = (tid & 3) * 32;
        float a[32] = {};
        if (row < nrow) {
            int key = seglist[base + row];
            int st = soff[key], len = slen[key];
            for (int i = 0; i < len; ++i) {
                const float* xr = x + (size_t)ssrc[st + i] * 128 + c0;
                #pragma unroll
                for (int j = 0; j < 8; ++j) {
                    float4 v = *(const float4*)(xr + j * 4);
                    a[j*4+0] += v.x; a[j*4+1] += v.y; a[j*4+2] += v.z; a[j*4+3] += v.w;
                }
            }
            float inv = 1.0f / (float)max(len, 1);
            #pragma unroll
            for (int j = 0; j < 32; ++j) a[j] *= inv;
        }
        #pragma unroll
        for (int g = 0; g < 4; ++g)
            split_store8(&Ah[row * APAD + c0 + g * 8], &Al[row * APAD + c0 + g * 8], a + g * 8);
    }
    f4v acc[8] = {};
    int w = tid >> 6, lane = tid & 63, m = lane & 15, quad = lane >> 4;
    for (int kc = 0; kc < 4; ++kc) {
        __syncthreads();
        #pragma unroll
        for (int t2 = 0; t2 < 2; ++t2) {
            int task = tid + t2 * 256;
            int n = task & 127, kg2 = task >> 7;
            float v[8];
            #pragma unroll
            for (int j = 0; j < 8; ++j)
                v[j] = wmat[(size_t)(kc * 32 + kg2 * 8 + j) * 128 + n];
            split_store8(&Bh[n * BPAD + kg2 * 8], &Bl[n * BPAD + kg2 * 8], v);
        }
        __syncthreads();
        s8v ah = *(const s8v*)&Ah[(w * 16 + m) * APAD + kc * 32 + quad * 8];
        s8v al = *(const s8v*)&Al[(w * 16 + m) * APAD + kc * 32 + quad * 8];
        #pragma unroll
        for (int nt = 0; nt < 8; ++nt) {
            s8v bh = *(const s8v*)&Bh[(nt * 16 + m) * BPAD + quad * 8];
            s8v bl = *(const s8v*)&Bl[(nt * 16 + m) * BPAD + quad * 8];
            acc[nt] = __builtin_amdgcn_mfma_f32_16x16x32_bf16(ah, bh, acc[nt], 0, 0, 0);
            acc[nt] = __builtin_amdgcn_mfma_f32_16x16x32_bf16(al, bh, acc[nt], 0, 0, 0);
            acc[nt] = __builtin_amdgcn_mfma_f32_16x16x32_bf16(ah, bl, acc[nt], 0, 0, 0);
        }
    }
    #pragma unroll
    for (int rr = 0; rr < 4; ++rr) {
        int rt = w * 16 + quad * 4 + rr;
        if (rt < nrow) {
            int dst = seglist[base + rt] - r * DN;
            float* kr = kg + (size_t)dst * 128 + m;
            #pragma unroll
            for (int nt = 0; nt < 8; ++nt)
                kr[nt * 16] += acc[nt][rr];
        }
    }
}

// ---------------------------------------------------------------- scoring (MFMA)
__global__ __launch_bounds__(256) void k_score_mfma(
    const float* __restrict__ kg, const float* __restrict__ user,
    const float* __restrict__ rb, float* __restrict__ out)
{
    __shared__ __align__(16) ushortT Ah[64 * APAD], Al[64 * APAD];
    __shared__ __align__(16) ushortT Bh[64 * APAD], Bl[64 * APAD];
    int tid = threadIdx.x;
    int n0 = blockIdx.x * 64;
    {
        int row = tid >> 2, c0 = (tid & 3) * 32;
        int gr = n0 + row;
        const float* ar = kg + (size_t)gr * 128 + c0;
        const float* ur = user + (size_t)row * 128 + c0;
        #pragma unroll
        for (int g = 0; g < 4; ++g) {
            float v[8] = {};
            if (gr < DN) {
                float4 u0 = *(const float4*)(ar + g * 8);
                float4 u1 = *(const float4*)(ar + g * 8 + 4);
                v[0]=u0.x; v[1]=u0.y; v[2]=u0.z; v[3]=u0.w;
                v[4]=u1.x; v[5]=u1.y; v[6]=u1.z; v[7]=u1.w;
            }
            split_store8(&Ah[row * APAD + c0 + g * 8], &Al[row * APAD + c0 + g * 8], v);
            float u[8];
            float4 w0 = *(const float4*)(ur + g * 8);
            float4 w1 = *(const float4*)(ur + g * 8 + 4);
            u[0]=w0.x; u[1]=w0.y; u[2]=w0.z; u[3]=w0.w;
            u[4]=w1.x; u[5]=w1.y; u[6]=w1.z; u[7]=w1.w;
            split_store8(&Bh[row * APAD + c0 + g * 8], &Bl[row * APAD + c0 + g * 8], u);
        }
    }
    __syncthreads();
    f4v acc[4] = {};
    int w = tid >> 6, lane = tid & 63, m = lane & 15, quad = lane >> 4;
    #pragma unroll
    for (int kc = 0; kc < 4; ++kc) {
        s8v ah = *(const s8v*)&Ah[(w * 16 + m) * APAD + kc * 32 + quad * 8];
        s8v al = *(const s8v*)&Al[(w * 16 + m) * APAD + kc * 32 + quad * 8];
        #pragma unroll
        for (int nt = 0; nt < 4; ++nt) {
            s8v bh = *(const s8v*)&Bh[(nt * 16 + m) * APAD + kc * 32 + quad * 8];
            s8v bl = *(const s8v*)&Bl[(nt * 16 + m) * APAD + kc * 32 + quad * 8];
            acc[nt] = __builtin_amdgcn_mfma_f32_16x16x32_bf16(ah, bh, acc[nt], 0, 0, 0);
            acc[nt] = __builtin_amdgcn_mfma_f32_16x16x32_bf16(al, bh, acc[nt], 0, 0, 0);
            acc[nt] = __builtin_amdgcn_mfma_f32_16x16x32_bf16(ah, bl, acc[nt], 0, 0, 0);
        }
    }
    int n = n0 + w * 16 + quad * 4;
    if (n < DN) {
        float4 rbv = *(const float4*)&rb[n];
        #pragma unroll
        for (int nt = 0; nt < 4; ++nt) {
            int b = nt * 16 + m;
            float4 o = make_float4(acc[nt][0] + rbv.x, acc[nt][1] + rbv.y,
                                   acc[nt][2] + rbv.z, acc[nt][3] + rbv.w);
            *(float4*)&out[(size_t)b * DN + n] = o;
        }
    }
}

// ---------------------------------------------------------------- scans (single-mode, for hyper)
__global__ void k_scan_pass1(const int* __restrict__ in, int n, int* __restrict__ bsum)
{
    __shared__ int red[256];
    int b = blockIdx.x, t = threadIdx.x;
    int i0 = b * SCAN_CHUNK + t * 4;
    int s = 0;
    #pragma unroll
    for (int j = 0; j < 4; ++j) {
        int i = i0 + j;
        if (i < n) s += in[i];
    }
    red[t] = s;
    __syncthreads();
    for (int o = 128; o > 0; o >>= 1) {
        if (t < o) red[t] += red[t + o];
        __syncthreads();
    }
    if (t == 0) bsum[b] = red[0];
}

__global__ __launch_bounds__(256) void k_scan_pass2p(int* bsum, int nb, int* total)
{
    __shared__ int lds[256];
    __shared__ int carry;
    int t = threadIdx.x;
    if (t == 0) carry = 0;
    __syncthreads();
    for (int c0 = 0; c0 < nb; c0 += 256) {
        int i = c0 + t;
        int v = (i < nb) ? bsum[i] : 0;
        lds[t] = v;
        __syncthreads();
        for (int o = 1; o < 256; o <<= 1) {
            int add = (t >= o) ? lds[t - o] : 0;
            __syncthreads();
            lds[t] += add;
            __syncthreads();
        }
        int myc = carry;
        if (i < nb) bsum[i] = lds[t] - v + myc;
        int tot = lds[255];
        __syncthreads();
        if (t == 0) carry = myc + tot;
        __syncthreads();
    }
    if (total && t == 0) *total = carry;
}

__global__ void k_scan_pass3(const int* __restrict__ in, int n, const int* __restrict__ bsum,
                             int* __restrict__ out)
{
    __shared__ int lds[256];
    int b = blockIdx.x, t = threadIdx.x;
    int i0 = b * SCAN_CHUNK + t * 4;
    int v[4]; int s = 0;
    #pragma unroll
    for (int j = 0; j < 4; ++j) {
        int i = i0 + j;
        int x = 0;
        if (i < n) x = in[i];
        v[j] = x; s += x;
    }
    lds[t] = s;
    __syncthreads();
    for (int o = 1; o < 256; o <<= 1) {
        int add = (t >= o) ? lds[t - o] : 0;
        __syncthreads();
        lds[t] += add;
        __syncthreads();
    }
    int run = lds[t] - s + bsum[b];
    #pragma unroll
    for (int j = 0; j < 4; ++j) {
        int i = i0 + j;
        if (i < n) { out[i] = run; run += v[j]; }
    }
}

// ---------------------------------------------------------------- dual scan (value + predicate), for RGCN
__global__ void k_scan2_pass1(const int* __restrict__ in, int n, int* bV, int* bP)
{
    __shared__ int redV[256], redP[256];
    int b = blockIdx.x, t = threadIdx.x;
    int i0 = b * SCAN_CHUNK + t * 4;
    int sv = 0, sp = 0;
    #pragma unroll
    for (int j = 0; j < 4; ++j) {
        int i = i0 + j;
        if (i < n) { int v = in[i]; sv += v; sp += (v > 0); }
    }
    redV[t] = sv; redP[t] = sp;
    __syncthreads();
    for (int o = 128; o > 0; o >>= 1) {
        if (t < o) { redV[t] += redV[t + o]; redP[t] += redP[t + o]; }
        __syncthreads();
    }
    if (t == 0) { bV[b] = redV[0]; bP[b] = redP[0]; }
}

__global__ __launch_bounds__(256) void k_scan2_pass2(int* bV, int* bP, int nb, int* totalP)
{
    __shared__ int lds[256];
    __shared__ int carry;
    int t = threadIdx.x;
    #pragma unroll 1
    for (int which = 0; which < 2; ++which) {
        int* bsum = which ? bP : bV;
        __syncthreads();
        if (t == 0) carry = 0;
        __syncthreads();
        for (int c0 = 0; c0 < nb; c0 += 256) {
            int i = c0 + t;
            int v = (i < nb) ? bsum[i] : 0;
            lds[t] = v;
            __syncthreads();
            for (int o = 1; o < 256; o <<= 1) {
                int add = (t >= o) ? lds[t - o] : 0;
                __syncthreads();
                lds[t] += add;
                __syncthreads();
            }
            int myc = carry;
            if (i < nb) bsum[i] = lds[t] - v + myc;
            int tot = lds[255];
            __syncthreads();
            if (t == 0) carry = myc + tot;
            __syncthreads();
        }
        if (which == 1 && totalP && t == 0) *totalP = carry;
    }
}

__global__ void k_scan2_pass3(const int* __restrict__ in, int n,
                              const int* __restrict__ bV, const int* __restrict__ bP,
                              int* __restrict__ outV, int* __restrict__ outP)
{
    __shared__ int ldsV[256], ldsP[256];
    int b = blockIdx.x, t = threadIdx.x;
    int i0 = b * SCAN_CHUNK + t * 4;
    int v[4]; int sv = 0, sp = 0;
    #pragma unroll
    for (int j = 0; j < 4; ++j) {
        int i = i0 + j;
        int x = 0;
        if (i < n) x = in[i];
        v[j] = x; sv += x; sp += (x > 0);
    }
    ldsV[t] = sv; ldsP[t] = sp;
    __syncthreads();
    for (int o = 1; o < 256; o <<= 1) {
        int addV = (t >= o) ? ldsV[t - o] : 0;
        int addP = (t >= o) ? ldsP[t - o] : 0;
        __syncthreads();
        ldsV[t] += addV; ldsP[t] += addP;
        __syncthreads();
    }
    int runV = ldsV[t] - sv + bV[b];
    int runP = ldsP[t] - sp + bP[b];
    #pragma unroll
    for (int j = 0; j < 4; ++j) {
        int i = i0 + j;
        if (i < n) {
            outV[i] = runV; outP[i] = runP;
            runV += v[j]; runP += (v[j] > 0);
        }
    }
}

// ---------------------------------------------------------------- RGCN sort
__global__ void k_hist_rgcn(const int* __restrict__ dst, const int* __restrict__ et,
                            int* hist, int E)
{
    int i = blockIdx.x * blockDim.x + threadIdx.x;
    if (i < E) atomicAdd(&hist[(size_t)et[i] * DN + dst[i]], 1);
}

__global__ void k_seglist(const int* __restrict__ hist, const int* __restrict__ segpos,
                          int* __restrict__ seglist, int n)
{
    int i = blockIdx.x * blockDim.x + threadIdx.x;
    if (i < n && hist[i] > 0) seglist[segpos[i]] = i;
}

__global__ void k_stypebase(const int* __restrict__ segpos, int* stypebase)
{
    int t = threadIdx.x;
    if (t < DR) stypebase[t] = segpos[(size_t)t * DN];
}

__global__ void k_bucket_rgcn(const int* __restrict__ src, const int* __restrict__ dst,
                              const int* __restrict__ et, const int* __restrict__ off,
                              int* cur, int* ssrc, int E)
{
    int i = blockIdx.x * blockDim.x + threadIdx.x;
    if (i >= E) return;
    int key = et[i] * DN + dst[i];
    int pos = off[key] + atomicAdd(&cur[key], 1);
    ssrc[pos] = src[i];
}

__global__ void k_wcomp(const float* __restrict__ comp, const float* __restrict__ bases,
                        float* __restrict__ w_all)
{
    int i = blockIdx.x * blockDim.x + threadIdx.x;
    if (i >= DR * DD * DD) return;
    int r = i / (DD * DD), io = i % (DD * DD);
    float s = 0.f;
    #pragma unroll
    for (int b = 0; b < DNB; ++b) s += comp[r * DNB + b] * bases[(size_t)b * DD * DD + io];
    w_all[i] = s;
}

// ---------------------------------------------------------------- hypergraph (both sides combined, 40000 bins)
__global__ void k_hist_p2(const int* __restrict__ se, const int* __restrict__ ke, int* hist)
{
    int i = blockIdx.x * blockDim.x + threadIdx.x;
    if (i < DP) atomicAdd(&hist[se[i]], 1);
    else if (i < 2 * DP) atomicAdd(&hist[DHE + ke[i - DP]], 1);
}

__global__ void k_bucket_p2(const int* __restrict__ sn, const int* __restrict__ se,
                            const int* __restrict__ kn, const int* __restrict__ ke,
                            const int* __restrict__ off, int* cur, int* pns)
{
    int i = blockIdx.x * blockDim.x + threadIdx.x;
    if (i >= 2 * DP) return;
    int e, node;
    if (i < DP) { e = se[i]; node = sn[i]; }
    else { e = DHE + ke[i - DP]; node = kn[i - DP]; }
    int pos = off[e] + atomicAdd(&cur[e], 1);
    pns[pos] = node;
}

// one wave per NEEDED hyperedge: efeat[he] = mean of kg[node]; half-wave float4 gather, 4 rows in flight
__global__ void k_hyper_agg(const float* __restrict__ xsrc, const int* __restrict__ pns,
                            const int* __restrict__ hoff, const int* __restrict__ hcnt,
                            const int* __restrict__ heneed, float* __restrict__ efeat)
{
    int lane = threadIdx.x & 63;
    int he = (blockIdx.x * blockDim.x + threadIdx.x) >> 6;
    if (he >= DHE2) return;
    if (!heneed[he]) return;
    int st = hoff[he], len = hcnt[he];
    int half = lane >> 5;
    int c16 = (lane & 31) * 4;
    float4 acc = make_float4(0.f, 0.f, 0.f, 0.f);
    int c = 0;
    for (; c + 4 <= len; c += 4) {
        int n0 = pns[st + c + half];
        int n1 = pns[st + c + 2 + half];
        float4 v0 = *(const float4*)&xsrc[(size_t)n0 * 128 + c16];
        float4 v1 = *(const float4*)&xsrc[(size_t)n1 * 128 + c16];
        acc.x += v0.x + v1.x; acc.y += v0.y + v1.y;
        acc.z += v0.z + v1.z; acc.w += v0.w + v1.w;
    }
    for (; c < len; c += 2) {
        int idx = c + half;
        if (idx < len) {
            int n = pns[st + idx];
            float4 v = *(const float4*)&xsrc[(size_t)n * 128 + c16];
            acc.x += v.x; acc.y += v.y; acc.z += v.z; acc.w += v.w;
        }
    }
    acc.x += __shfl_xor(acc.x, 32);
    acc.y += __shfl_xor(acc.y, 32);
    acc.z += __shfl_xor(acc.z, 32);
    acc.w += __shfl_xor(acc.w, 32);
    if (half == 0) {
        float inv = (len > 0) ? 1.0f / (float)len : 0.f;
        float4 o = make_float4(acc.x * inv, acc.y * inv, acc.z * inv, acc.w * inv);
        *(float4*)&efeat[(size_t)he * 128 + c16] = o;
    }
}

__global__ void k_slot_assign2(const int* __restrict__ sidx, const int* __restrict__ kidx,
                               int* slot_s, int* slot_k, int* scnt)
{
    int i = blockIdx.x * blockDim.x + threadIdx.x;
    if (i < DB * DLR) {
        int node = sidx[i];
        if (atomicCAS(&slot_s[node], -1, -2) == -1) slot_s[node] = atomicAdd(&scnt[0], 1);
    } else if (i < 2 * DB * DLR) {
        int node = kidx[i - DB * DLR];
        if (atomicCAS(&slot_k[node], -1, -2) == -1) slot_k[node] = atomicAdd(&scnt[1], 1);
    }
}

// fused sdeg + match + need-flag, block-aggregated compaction
__global__ __launch_bounds__(256) void k_sdeg_match(
    const int* __restrict__ nodes, const int* __restrict__ he, const int* __restrict__ slot,
    float* sdeg, int* mcnt, int* mhe, int* msl, int* heneed, int heBase)
{
    __shared__ int lcnt, lbase;
    if (threadIdx.x == 0) lcnt = 0;
    __syncthreads();
    int i = blockIdx.x * 256 + threadIdx.x;
    int s = -1, lidx = 0, h = 0;
    if (i < DP) {
        s = slot[nodes[i]];
        if (s >= 0) {
            h = heBase + he[i];
            heneed[h] = 1;
            atomicAdd(&sdeg[s], 1.0f);
            lidx = atomicAdd(&lcnt, 1);
        }
    }
    __syncthreads();
    if (threadIdx.x == 0) lbase = (lcnt > 0) ? atomicAdd(mcnt, lcnt) : 0;
    __syncthreads();
    if (s >= 0) {
        int idx = lbase + lidx;
        if (idx < MCAP) { mhe[idx] = h; msl[idx] = s; }
    }
}

// both sides in one launch
__global__ void k_accmatch2(const float* __restrict__ efeat,
                            const int* __restrict__ mhe_s, const int* __restrict__ msl_s,
                            const int* __restrict__ mhe_k, const int* __restrict__ msl_k,
                            const int* __restrict__ mcnt,
                            float* sacc_s, float* sacc_k)
{
    int lane = threadIdx.x & 63;
    int w = (blockIdx.x * blockDim.x + threadIdx.x) >> 6;
    int nw = (gridDim.x * blockDim.x) >> 6;
    int Ms = min(mcnt[0], MCAP), Mk = min(mcnt[1], MCAP);
    for (int i = w; i < Ms + Mk; i += nw) {
        bool sess = i < Ms;
        int he = sess ? mhe_s[i] : mhe_k[i - Ms];
        int sl = sess ? msl_s[i] : msl_k[i - Ms];
        float* sacc = sess ? sacc_s : sacc_k;
        float2 v = *(const float2*)&efeat[(size_t)he * 128 + lane * 2];
        atomicAdd(&sacc[(size_t)sl * 128 + lane * 2],     v.x);
        atomicAdd(&sacc[(size_t)sl * 128 + lane * 2 + 1], v.y);
    }
}

// both sides in one launch
__global__ void k_rel_gather2(const float* __restrict__ so_s, const float* __restrict__ so_k,
                              const int* __restrict__ slot_s, const int* __restrict__ slot_k,
                              const int* __restrict__ ridx_s, const int* __restrict__ ridx_k,
                              float* __restrict__ related)
{
    int gid = blockIdx.x * blockDim.x + threadIdx.x;
    int i = gid >> 5, c = gid & 31;
    if (i >= 2 * DB * DLR) return;
    bool sess = i < DB * DLR;
    int ii = sess ? i : i - DB * DLR;
    int s = sess ? slot_s[ridx_s[ii]] : slot_k[ridx_k[ii]];
    const float* so = sess ? so_s : so_k;
    int b = ii / DLR, l = ii % DLR;
    int colOff = sess ? 0 : 64;
    ((float4*)&related[((size_t)b * 128 + colOff + l) * 128])[c] =
        ((const float4*)&so[(size_t)s * 128])[c];
}

// ---------------------------------------------------------------- gathers / misc
__global__ void k_gather_rows(const float* __restrict__ src, const int* __restrict__ idx,
                              float* dst, int nRows)
{
    int i = blockIdx.x * blockDim.x + threadIdx.x;
    if (i >= nRows * 128) return;
    int row = i >> 7, d = i & 127;
    dst[i] = src[(size_t)idx[row] * 128 + d];
}

// ---------------------------------------------------------------- MHA: one block per (b,h)
__global__ __launch_bounds__(256) void k_mha(const float* __restrict__ qb,
                                             const float* __restrict__ kb,
                                             const float* __restrict__ vb,
                                             float* __restrict__ ob)
{
    int b = blockIdx.x >> 3, h = blockIdx.x & 7;
    __shared__ float Ks[128][16], Vs[128][16], Qs[32][16];
    int tid = threadIdx.x;
    for (int i = tid; i < 128 * 16; i += 256) {
        int j = i >> 4, d = i & 15;
        Ks[j][d] = kb[((size_t)b * 128 + j) * 128 + h * 16 + d];
        Vs[j][d] = vb[((size_t)b * 128 + j) * 128 + h * 16 + d];
    }
    for (int i = tid; i < 32 * 16; i += 256) {
        int q = i >> 4, d = i & 15;
        Qs[q][d] = qb[((size_t)b * 32 + q) * 128 + h * 16 + d] * 0.25f;
    }
    __syncthreads();
    int q = tid >> 3;
    int jg = tid & 7;
    float lg[16];
    float m = -1e30f;
    #pragma unroll
    for (int jj = 0; jj < 16; ++jj) {
        int j = jg * 16 + jj;
        float s = 0.f;
        #pragma unroll
        for (int d = 0; d < 16; ++d) s += Qs[q][d] * Ks[j][d];
        lg[jj] = s;
        m = fmaxf(m, s);
    }
    #pragma unroll
    for (int o = 1; o < 8; o <<= 1) m = fmaxf(m, __shfl_xor(m, o));
    float sum = 0.f;
    float acc[16] = {};
    #pragma unroll
    for (int jj = 0; jj < 16; ++jj) {
        float p = __expf(lg[jj] - m);
        sum += p;
        int j = jg * 16 + jj;
        #pragma unroll
        for (int d = 0; d < 16; ++d) acc[d] += p * Vs[j][d];
    }
    #pragma unroll
    for (int o = 1; o < 8; o <<= 1) {
        sum += __shfl_xor(sum, o);
        #pragma unroll
        for (int d = 0; d < 16; ++d) acc[d] += __shfl_xor(acc[d], o);
    }
    if (jg == 0) {
        float inv = 1.0f / sum;
        #pragma unroll
        for (int d = 0; d < 16; ++d)
            ob[((size_t)b * 32 + q) * 128 + h * 16 + d] = acc[d] * inv;
    }
}

// ---------------------------------------------------------------- launch
extern "C" void kernel_launch(void* const* d_in, const int* in_sizes, int n_in,
                              void* d_out, int out_size, void* d_ws, size_t ws_size,
                              hipStream_t stream)
{
    const float* emb        = (const float*)d_in[0];
    const float* bases      = (const float*)d_in[1];
    const float* comp       = (const float*)d_in[2];
    const float* root       = (const float*)d_in[3];
    const float* rgcn_bias  = (const float*)d_in[4];
    const float* sess_theta = (const float*)d_in[5];
    const float* sess_bias  = (const float*)d_in[6];
    const float* know_theta = (const float*)d_in[7];
    const float* know_bias  = (const float*)d_in[8];
    const float* in_proj_w  = (const float*)d_in[9];
    const float* in_proj_b  = (const float*)d_in[10];
    const float* out_proj_w = (const float*)d_in[11];
    const float* out_proj_b = (const float*)d_in[12];
    const float* attn_his_a = (const float*)d_in[13];
    const float* attn_his_b = (const float*)d_in[14];
    const float* attn_a     = (const float*)d_in[15];
    const float* attn_b     = (const float*)d_in[16];
    const float* rec_bias   = (const float*)d_in[17];
    const int* edge_src     = (const int*)d_in[18];
    const int* edge_dst     = (const int*)d_in[19];
    const int* edge_type    = (const int*)d_in[20];
    const int* sess_nodes   = (const int*)d_in[21];
    const int* sess_edges   = (const int*)d_in[22];
    const int* know_nodes   = (const int*)d_in[23];
    const int* know_edges   = (const int*)d_in[24];
    const int* sess_rel_idx = (const int*)d_in[25];
    const int* know_rel_idx = (const int*)d_in[26];
    const int* context_idx  = (const int*)d_in[27];
    float* out = (float*)d_out;

    float* wsf = (float*)d_ws;
    size_t off = 0;
    auto alloc = [&](size_t n) { size_t r = off; off += (n + 255) & ~(size_t)255; return r; };
    float* kg      = wsf + alloc(12800000);          // N*D
    float* tmp     = wsf + alloc(12800000);          // RGCN sort arena + efeat tail
    float* w_all   = wsf + alloc(196608);
    int*   bsumV   = (int*)(wsf + alloc(2048));
    int*   bsumP   = (int*)(wsf + alloc(2048));
    int*   stybase = (int*)(wsf + alloc(16));
    // ---- contiguous zero block (one memset) ----
    size_t zstart = off;
    int*   hhist   = (int*)(wsf + alloc(DHE2));
    int*   hcur    = (int*)(wsf + alloc(DHE2));
    int*   heneed  = (int*)(wsf + alloc(DHE2));
    int*   mcnt    = (int*)(wsf + alloc(16));        // [0]=sess, [1]=know
    int*   scnt    = (int*)(wsf + alloc(16));
    float* sdeg_s  = wsf + alloc(4096);
    float* sdeg_k  = wsf + alloc(4096);
    float* sacc_s  = wsf + alloc(524288);
    float* sacc_k  = wsf + alloc(524288);
    size_t zend = off;
    // ---- contiguous 0xFF block (one memset) ----
    size_t fstart = off;
    int*   slot_s  = (int*)(wsf + alloc(100000));
    int*   slot_k  = (int*)(wsf + alloc(100000));
    size_t fend = off;
    int*   hoff    = (int*)(wsf + alloc(DHE2));
    int*   pns     = (int*)(wsf + alloc(2 * DP));
    int*   mhe_s   = (int*)(wsf + alloc(MCAP));
    int*   msl_s   = (int*)(wsf + alloc(MCAP));
    int*   mhe_k   = (int*)(wsf + alloc(MCAP));
    int*   msl_k   = (int*)(wsf + alloc(MCAP));
    float* so_s    = wsf + alloc(524288);
    float* so_k    = wsf + alloc(524288);
    float* related = wsf + alloc(1048576);
    float* ctx     = wsf + alloc(262144);
    float* qb      = wsf + alloc(262144);
    float* kb      = wsf + alloc(1048576);
    float* vb      = wsf + alloc(1048576);
    float* obuf    = wsf + alloc(262144);
    float* attrel  = wsf + alloc(262144);
    float* his     = wsf + alloc(8192);
    float* ucat    = wsf + alloc(270336);
    float* userb   = wsf + alloc(8192);
    float* e1      = wsf + alloc(2048);
    float* e2      = wsf + alloc(2112);
    (void)ws_size; (void)in_sizes; (void)n_in; (void)out_size;

    // RGCN sort arena inside tmp; efeat (40000*128 = 5.12M) in the tail
    int*   hist    = (int*)tmp;                 // 1.2M
    int*   rcur    = (int*)tmp + 1200000;       // 1.2M (bucket cursor, pre-zeroed with hist)
    int*   soff    = (int*)tmp + 2400000;       // 1.2M
    int*   segpos  = (int*)tmp + 3600000;       // 1.2M
    int*   seglist = (int*)tmp + 4800000;       // 1.2M
    int*   ssrc    = (int*)tmp + 6000000;       // 1.0M
    float* efeat   = tmp + 7000000;             // 5.12M (used only after RGCN finishes)

    const int nbR = (NRBINS + SCAN_CHUNK - 1) / SCAN_CHUNK;   // 1172
    const int nbH = (DHE2 + SCAN_CHUNK - 1) / SCAN_CHUNK;     // 40

    // ---------------- upfront memsets (3 total)
    hipMemsetAsync(wsf + zstart, 0, (zend - zstart) * 4, stream);
    hipMemsetAsync(wsf + fstart, 0xFF, (fend - fstart) * 4, stream);
    hipMemsetAsync(hist, 0, 2400000 * 4, stream);   // hist + rcur

    k_slot_assign2<<<32, 256, 0, stream>>>(sess_rel_idx, know_rel_idx, slot_s, slot_k, scnt);
    // sdeg/match/need-flags early (only depend on slot arrays)
    k_sdeg_match<<<(DP + 255) / 256, 256, 0, stream>>>(sess_nodes, sess_edges, slot_s,
                                                       sdeg_s, mcnt, mhe_s, msl_s, heneed, 0);
    k_sdeg_match<<<(DP + 255) / 256, 256, 0, stream>>>(know_nodes, know_edges, slot_k,
                                                       sdeg_k, mcnt + 1, mhe_k, msl_k, heneed, DHE);

    // ---------------- RGCN: sort edges by (type, dst)
    k_hist_rgcn<<<(DE + 255) / 256, 256, 0, stream>>>(edge_dst, edge_type, hist, DE);
    k_scan2_pass1<<<nbR, 256, 0, stream>>>(hist, NRBINS, bsumV, bsumP);
    k_scan2_pass2<<<1, 256, 0, stream>>>(bsumV, bsumP, nbR, stybase + DR);
    k_scan2_pass3<<<nbR, 256, 0, stream>>>(hist, NRBINS, bsumV, bsumP, soff, segpos);
    k_stypebase<<<1, 64, 0, stream>>>(segpos, stybase);
    k_seglist<<<(NRBINS + 255) / 256, 256, 0, stream>>>(hist, segpos, seglist, NRBINS);
    k_bucket_rgcn<<<(DE + 255) / 256, 256, 0, stream>>>(edge_src, edge_dst, edge_type,
                                                        soff, rcur, ssrc, DE);
    k_wcomp<<<(DR * DD * DD + 255) / 256, 256, 0, stream>>>(comp, bases, w_all);

    int gemmN = (DN + 63) / 64;
    k_mfma_gemm<<<gemmN, 256, 0, stream>>>(emb, root, rgcn_bias, nullptr, kg, DN, 0);
    for (int r = 0; r < DR; ++r)
        k_mfma_rgcn<<<gemmN, 256, 0, stream>>>(emb, w_all + (size_t)r * DD * DD,
                                               seglist, soff, hist, ssrc, stybase, kg, r);

    // ---------------- hypergraph (both sides as one 40000-edge problem)
    k_hist_p2<<<(2 * DP + 255) / 256, 256, 0, stream>>>(sess_edges, know_edges, hhist);
    k_scan_pass1<<<nbH, 256, 0, stream>>>(hhist, DHE2, bsumV);
    k_scan_pass2p<<<1, 256, 0, stream>>>(bsumV, nbH, nullptr);
    k_scan_pass3<<<nbH, 256, 0, stream>>>(hhist, DHE2, bsumV, hoff);
    k_bucket_p2<<<(2 * DP + 255) / 256, 256, 0, stream>>>(sess_nodes, sess_edges,
                                                          know_nodes, know_edges,
                                                          hoff, hcur, pns);
    k_hyper_agg<<<(DHE2 * 64 + 255) / 256, 256, 0, stream>>>(kg, pns, hoff, hhist, heneed, efeat);
    k_accmatch2<<<256, 256, 0, stream>>>(efeat, mhe_s, msl_s, mhe_k, msl_k, mcnt, sacc_s, sacc_k);

    k_mfma_gemm<<<64, 256, 0, stream>>>(sacc_s, sess_theta, sess_bias, sdeg_s, so_s, 4096, 0);
    k_mfma_gemm<<<64, 256, 0, stream>>>(sacc_k, know_theta, know_bias, sdeg_k, so_k, 4096, 0);
    k_rel_gather2<<<(2 * DB * DLR * 32 + 255) / 256, 256, 0, stream>>>(
        so_s, so_k, slot_s, slot_k, sess_rel_idx, know_rel_idx, related);

    // ---------------- context + MHA
    k_gather_rows<<<(DB * DLC * 128 + 255) / 256, 256, 0, stream>>>(kg, context_idx, ctx, DB * DLC);
    k_mfma_gemm<<<(DB * DLC + 63) / 64, 256, 0, stream>>>(ctx, in_proj_w, in_proj_b, nullptr,
                                                          qb, DB * DLC, 1);
    k_mfma_gemm<<<(DB * 128 + 63) / 64, 256, 0, stream>>>(related, in_proj_w + DD * DD,
                                                          in_proj_b + DD, nullptr, kb, DB * 128, 1);
    k_mfma_gemm<<<(DB * 128 + 63) / 64, 256, 0, stream>>>(related, in_proj_w + 2 * DD * DD,
                                                          in_proj_b + 2 * DD, nullptr, vb, DB * 128, 1);
    k_mha<<<DB * DNH, 256, 0, stream>>>(qb, kb, vb, obuf);
    k_mfma_gemm<<<(DB * DLC + 63) / 64, 256, 0, stream>>>(obuf, out_proj_w, out_proj_b, nullptr,
                                                          attrel, DB * DLC, 1);

    // ---------------- pooling (GEMM-shaped) + score
    k_mfma_tanh_dot<<<(DB * DLC + 63) / 64, 256, 0, stream>>>(attrel, attn_his_a, attn_his_b,
                                                              e1, DB * DLC);
    k_pool_apply<32><<<DB, 128, 0, stream>>>(attrel, e1, his);
    k_build_ucat<<<(DB * 33 * 128 + 255) / 256, 256, 0, stream>>>(ctx, his, ucat);
    k_mfma_tanh_dot<<<(DB * 33 + 63) / 64, 256, 0, stream>>>(ucat, attn_a, attn_b,
                                                             e2, DB * 33);
    k_pool_apply<33><<<DB, 128, 0, stream>>>(ucat, e2, userb);
    k_score_mfma<<<gemmN, 256, 0, stream>>>(kg, userb, rec_bias, out);
}